// Round 4
// baseline (2524.298 us; speedup 1.0000x reference)
//
#include <hip/hip_runtime.h>
#include <math.h>

#define DEV __device__ __forceinline__

DEV float sigmoid_(float x){ return 1.f/(1.f+__expf(-x)); }
DEV float silu_(float x){ return x * sigmoid_(x); }
DEV float softplus_(float x){ return (x > 20.f) ? x : log1pf(__expf(x)); }
DEV float gelu_(float x){ return 0.5f*x*(1.f + erff(x*0.70710678118654752440f)); }

typedef __attribute__((ext_vector_type(8))) short short8v;
typedef __attribute__((ext_vector_type(4))) float floatx4;

// round-to-nearest-even bf16 split: returns hi or lo part as bf16 bits
DEV short bf_split(float x, bool want_lo){
  unsigned u = __float_as_uint(x);
  unsigned hb = (u + 0x7FFFu + ((u >> 16) & 1u)) >> 16;
  if (!want_lo) return (short)hb;
  float lo = x - __uint_as_float(hb << 16);
  unsigned ul = __float_as_uint(lo);
  return (short)((ul + 0x7FFFu + ((ul >> 16) & 1u)) >> 16);
}

// ============ MFMA GEMM with on-the-fly error-free triple split ============
// C[M x N] = act(A[M x K](fp32) @ W[N x K](fp32)^T + bias [+ R])
// Internally K3P = 3K (padded to %32). A parts [hi|hi|lo], W parts [hi|lo|hi]:
// computes hi*hi + hi*lo + lo*hi (drops lo*lo ~ 2^-16 relative).
// Requirements: M%128==0, N%128==0 (N may be padded: W rows >= realN read as 0,
// C cols >= NOUT not written).
template<int K, int K3P, int ACT, int RES, int BIAS>
__global__ __launch_bounds__(256)
void gemm3f_k(const float* __restrict__ A, int lda,
              const float* __restrict__ W, int ldw, int realN,
              const float* __restrict__ bias, const float* __restrict__ Rres,
              float* __restrict__ C, int ldc, int NOUT,
              int M, int N)
{
  __shared__ short As[128][40];
  __shared__ short Ws[128][40];
  const int bm = blockIdx.x << 7;
  const int bn = blockIdx.y << 7;
  const int tid = threadIdx.x;
  const int lane = tid & 63;
  const int wv = tid >> 6;
  const int wr = (wv >> 1) << 6;
  const int wc = (wv & 1) << 6;
  const int frow = lane & 15;
  const int fk   = lane >> 4;
  const int srow = tid >> 1;        // staging row (two threads per row)
  const int shalf = (tid & 1) << 4; // 0 / 16 bf16 columns

  floatx4 acc[4][4] = {};
  const float* gA = A + (size_t)(bm + srow)*lda;
  const bool wvalid = (bn + srow) < realN;
  const float* gW = W + (size_t)(bn + srow)*ldw;

  for (int k0 = 0; k0 < K3P; k0 += 32) {
    short av[16], wvv[16];
    if constexpr ((K % 32) == 0) {
      const int p = k0 / K;                 // part index, uniform over the tile
      const int c0 = k0 - p*K + shalf;      // fp32 column base (16B aligned)
      const bool loA = (p == 2), loW = (p == 1);
      #pragma unroll
      for (int q = 0; q < 4; ++q) {
        const float4 v = *(const float4*)(gA + c0 + q*4);
        av[q*4+0] = bf_split(v.x, loA);
        av[q*4+1] = bf_split(v.y, loA);
        av[q*4+2] = bf_split(v.z, loA);
        av[q*4+3] = bf_split(v.w, loA);
      }
      if (wvalid) {
        #pragma unroll
        for (int q = 0; q < 4; ++q) {
          const float4 v = *(const float4*)(gW + c0 + q*4);
          wvv[q*4+0] = bf_split(v.x, loW);
          wvv[q*4+1] = bf_split(v.y, loW);
          wvv[q*4+2] = bf_split(v.z, loW);
          wvv[q*4+3] = bf_split(v.w, loW);
        }
      } else {
        #pragma unroll
        for (int j = 0; j < 16; ++j) wvv[j] = 0;
      }
    } else {
      // general path (K not multiple of 32, e.g. K=48): per-element part calc
      #pragma unroll
      for (int j = 0; j < 16; ++j) {
        const int k3 = k0 + shalf + j;
        short sa = 0, sw = 0;
        if (k3 < 3*K) {
          const int p = k3 / K;
          const int c = k3 - p*K;
          sa = bf_split(gA[c], p == 2);
          if (wvalid) sw = bf_split(gW[c], p == 1);
        }
        av[j] = sa; wvv[j] = sw;
      }
    }
    __syncthreads();
    *(short8v*)&As[srow][shalf]     = *(short8v*)&av[0];
    *(short8v*)&As[srow][shalf + 8] = *(short8v*)&av[8];
    *(short8v*)&Ws[srow][shalf]     = *(short8v*)&wvv[0];
    *(short8v*)&Ws[srow][shalf + 8] = *(short8v*)&wvv[8];
    __syncthreads();
    short8v af[4], bfv[4];
    #pragma unroll
    for (int mf = 0; mf < 4; ++mf)
      af[mf] = *(const short8v*)&As[wr + mf*16 + frow][fk*8];
    #pragma unroll
    for (int nf = 0; nf < 4; ++nf)
      bfv[nf] = *(const short8v*)&Ws[wc + nf*16 + frow][fk*8];
    #pragma unroll
    for (int mf = 0; mf < 4; ++mf)
      #pragma unroll
      for (int nf = 0; nf < 4; ++nf)
        acc[mf][nf] = __builtin_amdgcn_mfma_f32_16x16x32_bf16(af[mf], bfv[nf], acc[mf][nf], 0, 0, 0);
  }

  #pragma unroll
  for (int mf = 0; mf < 4; ++mf) {
    #pragma unroll
    for (int nf = 0; nf < 4; ++nf) {
      const int col = bn + wc + nf*16 + (lane & 15);
      if (col >= NOUT) continue;
      #pragma unroll
      for (int r = 0; r < 4; ++r) {
        const int row = bm + wr + mf*16 + (lane >> 4)*4 + r;
        float v = acc[mf][nf][r];
        if (BIAS) v += bias[col];
        if (RES)  v += Rres[(size_t)row*ldc + col];
        if (ACT == 1) v = softplus_(v);
        C[(size_t)row*ldc + col] = v;
      }
    }
  }
}

// ---------------- patch conv: 16x16 stride-16 VALID conv, register-tiled ----------------
__global__ __launch_bounds__(256)
void patch_conv_k(const float* __restrict__ x, const float* __restrict__ w,
                  const float* __restrict__ bias, float* __restrict__ xp)
{
  const int bb = blockIdx.x >> 3;
  const int ph = blockIdx.x & 7;
  __shared__ float slab2[8*260];      // [pw][kh*16+kw] pad 4
  __shared__ float wsh[256*36];       // [pos][o] stride 36
  const int tid = threadIdx.x;
  const int og = tid & 7;
  const int pg = (tid >> 3) & 3;
  const int ks = tid >> 5;
  float acc[4][2] = {};
  for (int c = 0; c < 32; ++c) {
    const float4* src = (const float4*)(x + ((size_t)(bb*32 + c)*128 + ph*16)*128);
    for (int i = tid; i < 512; i += 256) {
      float4 v = src[i];
      const int r = i >> 5;
      const int c4 = (i & 31) << 2;
      *(float4*)&slab2[(c4 >> 4)*260 + r*16 + (c4 & 15)] = v;
    }
    for (int i = tid; i < 8192; i += 256) {
      const int o2 = i >> 8, pos = i & 255;
      wsh[pos*36 + o2] = w[((size_t)o2*32 + c)*256 + pos];
    }
    __syncthreads();
    #pragma unroll
    for (int khi = 0; khi < 2; ++khi) {
      const int kh = ks*2 + khi;
      #pragma unroll
      for (int kw4 = 0; kw4 < 16; kw4 += 4) {
        const float4 s0 = *(const float4*)&slab2[(pg*2+0)*260 + kh*16 + kw4];
        const float4 s1 = *(const float4*)&slab2[(pg*2+1)*260 + kh*16 + kw4];
        #pragma unroll
        for (int q = 0; q < 4; ++q) {
          const float4 wvq = *(const float4*)&wsh[(kh*16 + kw4 + q)*36 + og*4];
          const float sv0 = (&s0.x)[q], sv1 = (&s1.x)[q];
          acc[0][0] += wvq.x*sv0; acc[0][1] += wvq.x*sv1;
          acc[1][0] += wvq.y*sv0; acc[1][1] += wvq.y*sv1;
          acc[2][0] += wvq.z*sv0; acc[2][1] += wvq.z*sv1;
          acc[3][0] += wvq.w*sv0; acc[3][1] += wvq.w*sv1;
        }
      }
    }
    __syncthreads();
  }
  #pragma unroll
  for (int j = 0; j < 4; ++j)
    #pragma unroll
    for (int i = 0; i < 2; ++i)
      wsh[tid*8 + j*2 + i] = acc[j][i];
  __syncthreads();
  if (ks == 0) {
    const int pos = tid & 31;
    #pragma unroll
    for (int j = 0; j < 4; ++j) {
      const int o = og*4 + j;
      #pragma unroll
      for (int i = 0; i < 2; ++i) {
        float s = 0.f;
        #pragma unroll
        for (int k2 = 0; k2 < 8; ++k2) s += wsh[(k2*32 + pos)*8 + j*2 + i];
        xp[((size_t)bb*32 + o)*64 + ph*8 + pg*2 + i] = s + bias[o];
      }
    }
  }
}

// ---------------- fused: x_proj assemble + gelu fuse + concat + layernorm ----------------
__global__ __launch_bounds__(256)
void fuse_ln_k(const float* __restrict__ xpat, const float* __restrict__ xprojbuf,
               const float* __restrict__ xfeat, const float* __restrict__ lnw,
               const float* __restrict__ lnb, const float* __restrict__ focusp,
               float* __restrict__ cat)
{
  const int row = blockIdx.x;
  const int t = threadIdx.x;
  const float focus = focusp[0];
  const float xp = xpat[(size_t)row*256 + t];
  const float pr = (t < 128) ? xfeat[(size_t)row*1280 + t] : xprojbuf[(size_t)row*256 + t];
  const float xf = gelu_(focus*pr + (2.f - focus)*xp);
  float s  = xp + xf + pr;
  float sq = xp*xp + xf*xf + pr*pr;
  __shared__ float rs[4], rq[4];
  const int lane = t & 63, wv = t >> 6;
  #pragma unroll
  for (int off = 32; off > 0; off >>= 1) {
    s  += __shfl_down(s,  off, 64);
    sq += __shfl_down(sq, off, 64);
  }
  if (lane == 0) { rs[wv] = s; rq[wv] = sq; }
  __syncthreads();
  const float S = rs[0]+rs[1]+rs[2]+rs[3];
  const float Q = rq[0]+rq[1]+rq[2]+rq[3];
  const float mu = S * (1.f/768.f);
  const float var = Q*(1.f/768.f) - mu*mu;
  const float rstd = rsqrtf(var + 1e-5f);
  const size_t ob = (size_t)row*768;
  cat[ob +        t] = (xp - mu)*rstd*lnw[      t] + lnb[      t];
  cat[ob + 256 +  t] = (xf - mu)*rstd*lnw[256 + t] + lnb[256 + t];
  cat[ob + 512 +  t] = (pr - mu)*rstd*lnw[512 + t] + lnb[512 + t];
}

// ---------------- prep: duplicate + flip into the 64-sequence batches ----------------
__global__ void prep_m1_k(const float* __restrict__ cat, float* __restrict__ X)
{
  const int idx = blockIdx.x*256 + threadIdx.x;
  if (idx >= 64*32*768) return;
  const int d = idx % 768;
  const int sl = idx / 768;
  const int l = sl & 31;
  const int s = sl >> 5;
  const int b = s & 31;
  const int ll = (s < 32) ? l : 31 - l;
  X[idx] = cat[((size_t)b*32 + ll)*768 + d];
}
__global__ void prep_m2_k(const float* __restrict__ cat, float* __restrict__ X)
{
  const int idx = blockIdx.x*256 + threadIdx.x;
  if (idx >= 64*768*32) return;
  const int c = idx & 31;
  const int sj = idx >> 5;
  const int j = sj % 768;
  const int s = sj / 768;
  const int b = (s < 32) ? s : s - 32;
  const int jj = (s < 32) ? j : 767 - j;
  X[idx] = cat[((size_t)b*32 + c)*768 + jj];
}

// ---------------- depthwise causal conv (k=4) + silu ----------------
__global__ void dwconv_silu_k(const float* __restrict__ xz, int ldxz,
                              const float* __restrict__ w, const float* __restrict__ b,
                              float* __restrict__ xc, int di, int L, int total)
{
  const int idx = blockIdx.x*256 + threadIdx.x;
  if (idx >= total) return;
  const int d = idx % di;
  const int sl = idx / di;
  const int l = sl % L;
  float acc = b[d];
  const float* wd = w + d*4;
  #pragma unroll
  for (int k = 0; k < 4; ++k) {
    const int ll = l - 3 + k;
    if (ll >= 0) acc += xz[(size_t)(sl - 3 + k)*ldxz + d] * wd[k];
  }
  xc[idx] = silu_(acc);
}

// ---------------- m2 dt projection (K=2) + softplus, streaming ----------------
__global__ void dt2_k(const float* __restrict__ dbl, const float* __restrict__ dt_w,
                      const float* __restrict__ dt_b, float* __restrict__ delta)
{
  const int idx = blockIdx.x*256 + threadIdx.x;   // 49152*64
  if (idx >= 49152*64) return;
  const int d = idx & 63;
  const int r = idx >> 6;
  const float a0 = dbl[(size_t)r*34 + 0], a1 = dbl[(size_t)r*34 + 1];
  delta[idx] = softplus_(a0*dt_w[d*2] + a1*dt_w[d*2+1] + dt_b[d]);
}

// ---------------- m1 selective scan (L=32) ----------------
__global__ void scan_k(const float* __restrict__ delta, const float* __restrict__ xc,
                       const float* __restrict__ dbl, int lddbl, int droff,
                       const float* __restrict__ z, int ldz,
                       const float* __restrict__ A_log, const float* __restrict__ Dp,
                       float* __restrict__ Y, int di, int L, int total)
{
  const int idx = blockIdx.x*256 + threadIdx.x;
  if (idx >= total) return;
  const int d = idx % di;
  const int s = idx / di;
  float A[16], h[16];
  #pragma unroll
  for (int n = 0; n < 16; ++n) { A[n] = -__expf(A_log[d*16 + n]); h[n] = 0.f; }
  const float Dv = Dp[d];
  const size_t base = (size_t)s*L;
  for (int l = 0; l < L; ++l) {
    const size_t row = base + l;
    const float de  = delta[row*di + d];
    const float xcv = xc[row*di + d];
    const float du  = de * xcv;
    const float* bl = dbl + row*lddbl + droff;
    float y = 0.f;
    #pragma unroll
    for (int n = 0; n < 16; ++n) {
      const float dA = __expf(de * A[n]);
      h[n] = dA*h[n] + du*bl[n];
      y += h[n]*bl[16 + n];
    }
    const float zv = z[row*ldz + d];
    Y[row*di + d] = (y + xcv*Dv) * silu_(zv);
  }
}

// ---------------- m2 chunked scan: 12 chunks of 64 ----------------
#define NC2 12
#define LC2 64

__global__ __launch_bounds__(256)
void scan2_partA(const float* __restrict__ delta, const float* __restrict__ xc,
                 const float* __restrict__ dbl, const float* __restrict__ A_log,
                 float* __restrict__ Hend, unsigned short* __restrict__ sde_buf)
{
  const int t = blockIdx.x*256 + threadIdx.x;     // 64*NC2*64 = 49152
  if (t >= 64*64*NC2) return;
  const int d = t & 63;
  const int c = (t >> 6) % NC2;
  const int s = t / (64*NC2);
  float A[16], h[16];
  #pragma unroll
  for (int n = 0; n < 16; ++n) { A[n] = -__expf(A_log[d*16 + n]); h[n] = 0.f; }
  float sde = 0.f;
  const size_t row0 = (size_t)s*768 + c*LC2;
  for (int l = 0; l < LC2; ++l) {
    const size_t row = row0 + l;
    const float de  = delta[row*64 + d];
    const float xcv = xc[row*64 + d];
    const float du  = de * xcv;
    const float* bl = dbl + row*34 + 2;
    sde += de;
    #pragma unroll
    for (int n = 0; n < 16; ++n)
      h[n] = __expf(de*A[n])*h[n] + du*bl[n];
  }
  float* hp = Hend + (size_t)t*16;
  #pragma unroll
  for (int n = 0; n < 16; ++n) hp[n] = h[n];
  const unsigned u = __float_as_uint(sde);
  sde_buf[t] = (unsigned short)((u + 0x7FFFu + ((u >> 16) & 1u)) >> 16);
}

__global__ void scan2_carry(const float* __restrict__ A_log,
                            float* __restrict__ Hend, const unsigned short* __restrict__ sde_buf)
{
  const int t = blockIdx.x*256 + threadIdx.x;     // 4096
  if (t >= 4096) return;
  const int d = t & 63;
  const int s = t >> 6;
  float A[16], H[16];
  #pragma unroll
  for (int n = 0; n < 16; ++n) { A[n] = -__expf(A_log[d*16 + n]); H[n] = 0.f; }
  for (int c = 0; c < NC2; ++c) {
    const size_t off = ((size_t)(s*NC2 + c)*64 + d)*16;
    const float sde = __uint_as_float(((unsigned)sde_buf[(s*NC2 + c)*64 + d]) << 16);
    #pragma unroll
    for (int n = 0; n < 16; ++n) {
      const float he = Hend[off + n];
      Hend[off + n] = H[n];                       // becomes H_in for chunk c
      H[n] = __expf(sde*A[n])*H[n] + he;
    }
  }
}

__global__ __launch_bounds__(256)
void scan2_partC(const float* __restrict__ delta, const float* __restrict__ xc,
                 const float* __restrict__ dbl, const float* __restrict__ z,
                 const float* __restrict__ A_log, const float* __restrict__ Dp,
                 const float* __restrict__ Hin, float* __restrict__ Y)
{
  const int t = blockIdx.x*256 + threadIdx.x;
  if (t >= 64*64*NC2) return;
  const int d = t & 63;
  const int c = (t >> 6) % NC2;
  const int s = t / (64*NC2);
  float A[16], h[16];
  #pragma unroll
  for (int n = 0; n < 16; ++n) {
    A[n] = -__expf(A_log[d*16 + n]);
    h[n] = Hin[(size_t)t*16 + n];
  }
  const float Dv = Dp[d];
  const size_t row0 = (size_t)s*768 + c*LC2;
  for (int l = 0; l < LC2; ++l) {
    const size_t row = row0 + l;
    const float de  = delta[row*64 + d];
    const float xcv = xc[row*64 + d];
    const float du  = de * xcv;
    const float* bl = dbl + row*34 + 2;
    float y = 0.f;
    #pragma unroll
    for (int n = 0; n < 16; ++n) {
      const float dA = __expf(de*A[n]);
      h[n] = dA*h[n] + du*bl[n];
      y += h[n]*bl[16 + n];
    }
    const float zv = z[row*128 + d];
    Y[row*64 + d] = (y + xcv*Dv) * silu_(zv);
  }
}

// ---------------- combine + mean over l ----------------
__global__ __launch_bounds__(256)
void x3_k(const float* __restrict__ x1p, const float* __restrict__ x2p, float* __restrict__ x3)
{
  const int b = blockIdx.x;
  for (int j = threadIdx.x; j < 768; j += 256) {
    float s = 0.f;
    for (int i = 0; i < 32; ++i) {
      s += x1p[((size_t)b*32 + i)*768 + j] + x1p[((size_t)(b+32)*32 + i)*768 + j];
      s += x2p[((size_t)b*768 + j)*32 + i] + x2p[((size_t)(b+32)*768 + j)*32 + i];
    }
    x3[(size_t)b*768 + j] = s * (1.f/32.f);
  }
}

// ---------------- regression head ----------------
__global__ __launch_bounds__(512)
void head_k(const float* __restrict__ x3, const float* __restrict__ w1, const float* __restrict__ b1,
            const float* __restrict__ w2, const float* __restrict__ b2, float* __restrict__ out)
{
  const int b = blockIdx.x;
  const int t = threadIdx.x;
  __shared__ float xrow[768];
  for (int i = t; i < 768; i += 512) xrow[i] = x3[(size_t)b*768 + i];
  __syncthreads();
  float hv = 0.f;
  if (t < 384) {
    const float* wr = w1 + (size_t)t*768;
    float acc = b1[t];
    for (int d = 0; d < 768; ++d) acc += xrow[d]*wr[d];
    hv = acc * w2[t];
  }
  __shared__ float red[8];
  const int lane = t & 63, wv = t >> 6;
  #pragma unroll
  for (int off = 32; off > 0; off >>= 1) hv += __shfl_down(hv, off, 64);
  if (lane == 0) red[wv] = hv;
  __syncthreads();
  if (t == 0) {
    float s = b2[0];
    #pragma unroll
    for (int i = 0; i < 8; ++i) s += red[i];
    out[b] = s;
  }
}

extern "C" void kernel_launch(void* const* d_in, const int* in_sizes, int n_in,
                              void* d_out, int out_size, void* d_ws, size_t ws_size,
                              hipStream_t stream)
{
  (void)in_sizes; (void)n_in; (void)out_size;
  const float* x_cwt        = (const float*)d_in[0];
  const float* x_features   = (const float*)d_in[1];
  const float* patch_conv_w = (const float*)d_in[2];
  const float* patch_conv_b = (const float*)d_in[3];
  const float* patch_proj_w = (const float*)d_in[4];
  const float* patch_proj_b = (const float*)d_in[5];
  const float* feat_proj_w  = (const float*)d_in[6];
  const float* feat_proj_b  = (const float*)d_in[7];
  const float* ln_w         = (const float*)d_in[8];
  const float* ln_b         = (const float*)d_in[9];
  const float* focus        = (const float*)d_in[10];
  const float* reg_w1       = (const float*)d_in[11];
  const float* reg_b1       = (const float*)d_in[12];
  const float* reg_w2       = (const float*)d_in[13];
  const float* reg_b2       = (const float*)d_in[14];
  const float* m1w[9]; for (int i=0;i<9;i++) m1w[i] = (const float*)d_in[15+i];
  const float* m2w[9]; for (int i=0;i<9;i++) m2w[i] = (const float*)d_in[24+i];

  // ---- arena (floats), total 21,356,544 = 85.4 MB (within proven ws) ----
  float* p = (float*)d_ws;
  size_t need = 0;
  auto alloc = [&](size_t n){ float* r = p; p += n; need += n; return r; };
  float* cat    = alloc(786432);    // front: cat | m2 loop: Hend (exact fit)
  float* m1x    = alloc(1572864);   // (64,32,768)
  float* m2x    = alloc(1572864);   // (64,768,32)
  float* x3     = alloc(24576);     // m2 loop: sde (ushort, exact fit) | end: x3
  float* bxz    = alloc(6291456);   // m1 (2048,3072) / m2 (49152,128); front overlays
  float* bxc    = alloc(3145728);   // m1 (2048,1536) / m2 (49152,64)
  float* bdbl   = alloc(1671168);   // m1 (2048,80)   / m2 (49152,34)
  float* bdelta = alloc(3145728);   // m1 (2048,1536) / m2 (49152,64)
  float* by     = alloc(3145728);   // m1 (2048,1536) / m2 (49152,64)
  if (ws_size < need * sizeof(float)) return;
  // front-end overlays inside bxz (dead before m1 loop starts)
  float* xp_buf    = bxz;           // (32,32,64) = 65536
  float* x_patched = bxz + 65536;   // (1024,256) = 262144
  float* x_projb   = bxz + 327680;  // (1024,256) = 262144
  // m2 scan overlays
  float* sHend = cat;                        // 64*12*64*16 = 786432
  unsigned short* sSde = (unsigned short*)x3; // 49152 ushorts = 98304 B

  // ---- front-end ----
  patch_conv_k<<<256, 256, 0, stream>>>(x_cwt, patch_conv_w, patch_conv_b, xp_buf);
  // x_patched = xp_buf(1024x64) @ patch_proj_w(256x64)^T + b
  gemm3f_k<64,192,0,0,1><<<dim3(8,2), 256, 0, stream>>>(
      xp_buf, 64, patch_proj_w, 64, 256, patch_proj_b, nullptr,
      x_patched, 256, 256, 1024, 256);
  // x_projb[:,128:] = xfeat[:,256:](1024x1024) @ feat_proj_w(128x1024)^T + b
  gemm3f_k<1024,3072,0,0,1><<<dim3(8,1), 256, 0, stream>>>(
      x_features + 256, 1280, feat_proj_w, 1024, 128, feat_proj_b, nullptr,
      x_projb + 128, 256, 128, 1024, 128);
  fuse_ln_k<<<1024, 256, 0, stream>>>(x_patched, x_projb, x_features, ln_w, ln_b, focus, cat);
  prep_m1_k<<<6144, 256, 0, stream>>>(cat, m1x);

  // ---- m1: 2 layers on batched (64,32,768); di=1536, dr=48 ----
  for (int im = 0; im < 2; ++im) {
    const float* in_w   = m1w[0] + (size_t)im*3072*768;
    const float* conv_w = m1w[1] + (size_t)im*1536*4;
    const float* conv_b = m1w[2] + (size_t)im*1536;
    const float* xp_w   = m1w[3] + (size_t)im*80*1536;
    const float* dt_w   = m1w[4] + (size_t)im*1536*48;
    const float* dt_b   = m1w[5] + (size_t)im*1536;
    const float* A_log  = m1w[6] + (size_t)im*1536*16;
    const float* Dp     = m1w[7] + (size_t)im*1536;
    const float* out_w  = m1w[8] + (size_t)im*768*1536;
    gemm3f_k<768,2304,0,0,0><<<dim3(16,24), 256, 0, stream>>>(
        m1x, 768, in_w, 768, 3072, nullptr, nullptr, bxz, 3072, 3072, 2048, 3072);
    dwconv_silu_k<<<12288, 256, 0, stream>>>(bxz, 3072, conv_w, conv_b, bxc, 1536, 32, 2048*1536);
    gemm3f_k<1536,4608,0,0,0><<<dim3(16,1), 256, 0, stream>>>(
        bxc, 1536, xp_w, 1536, 80, nullptr, nullptr, bdbl, 80, 80, 2048, 128);
    gemm3f_k<48,160,1,0,1><<<dim3(16,12), 256, 0, stream>>>(
        bdbl, 80, dt_w, 48, 1536, dt_b, nullptr, bdelta, 1536, 1536, 2048, 1536);
    scan_k<<<384, 256, 0, stream>>>(bdelta, bxc, bdbl, 80, 48, bxz + 1536, 3072,
                                    A_log, Dp, by, 1536, 32, 98304);
    gemm3f_k<1536,4608,0,1,0><<<dim3(16,6), 256, 0, stream>>>(
        by, 1536, out_w, 1536, 768, nullptr, m1x, m1x, 768, 768, 2048, 768);
  }

  // ---- m2 prep (cat still alive; becomes Hend afterwards) ----
  prep_m2_k<<<6144, 256, 0, stream>>>(cat, m2x);

  // ---- m2: 2 layers on batched (64,768,32); di=64, dr=2 ----
  for (int im = 0; im < 2; ++im) {
    const float* in_w   = m2w[0] + (size_t)im*128*32;
    const float* conv_w = m2w[1] + (size_t)im*64*4;
    const float* conv_b = m2w[2] + (size_t)im*64;
    const float* xp_w   = m2w[3] + (size_t)im*34*64;
    const float* dt_w   = m2w[4] + (size_t)im*64*2;
    const float* dt_b   = m2w[5] + (size_t)im*64;
    const float* A_log  = m2w[6] + (size_t)im*64*16;
    const float* Dp     = m2w[7] + (size_t)im*64;
    const float* out_w  = m2w[8] + (size_t)im*32*64;
    gemm3f_k<32,96,0,0,0><<<dim3(384,1), 256, 0, stream>>>(
        m2x, 32, in_w, 32, 128, nullptr, nullptr, bxz, 128, 128, 49152, 128);
    dwconv_silu_k<<<12288, 256, 0, stream>>>(bxz, 128, conv_w, conv_b, bxc, 64, 768, 49152*64);
    gemm3f_k<64,192,0,0,0><<<dim3(384,1), 256, 0, stream>>>(
        bxc, 64, xp_w, 64, 34, nullptr, nullptr, bdbl, 34, 34, 49152, 128);
    dt2_k<<<12288, 256, 0, stream>>>(bdbl, dt_w, dt_b, bdelta);
    scan2_partA<<<192, 256, 0, stream>>>(bdelta, bxc, bdbl, A_log, sHend, sSde);
    scan2_carry<<<16, 256, 0, stream>>>(A_log, sHend, sSde);
    scan2_partC<<<192, 256, 0, stream>>>(bdelta, bxc, bdbl, bxz + 64, A_log, Dp, sHend, by);
    gemm3f_k<64,192,0,1,0><<<dim3(384,1), 256, 0, stream>>>(
        by, 64, out_w, 64, 32, nullptr, m2x, m2x, 32, 32, 49152, 128);
  }

  // ---- head ----
  x3_k<<<32, 256, 0, stream>>>(m1x, m2x, x3);
  head_k<<<32, 512, 0, stream>>>(x3, reg_w1, reg_b1, reg_w2, reg_b2, (float*)d_out);
}

// Round 5
// 1635.149 us; speedup vs baseline: 1.5438x; 1.5438x over previous
//
#include <hip/hip_runtime.h>
#include <math.h>

#define DEV __device__ __forceinline__

DEV float sigmoid_(float x){ return 1.f/(1.f+__expf(-x)); }
DEV float silu_(float x){ return x * sigmoid_(x); }
DEV float softplus_(float x){ return (x > 20.f) ? x : log1pf(__expf(x)); }
DEV float gelu_(float x){ return 0.5f*x*(1.f + erff(x*0.70710678118654752440f)); }

typedef __attribute__((ext_vector_type(8))) short short8v;
typedef __attribute__((ext_vector_type(4))) short short4v;
typedef __attribute__((ext_vector_type(4))) float floatx4;

// round-to-nearest-even bf16 split: returns hi or lo part as bf16 bits
DEV short bf_split(float x, bool want_lo){
  unsigned u = __float_as_uint(x);
  unsigned hb = (u + 0x7FFFu + ((u >> 16) & 1u)) >> 16;
  if (!want_lo) return (short)hb;
  float lo = x - __uint_as_float(hb << 16);
  unsigned ul = __float_as_uint(lo);
  return (short)((ul + 0x7FFFu + ((ul >> 16) & 1u)) >> 16);
}

// ---------------- fp32 GEMM (kept for m2's K<=64 streaming shapes) ----------------
template<int ACT, int RES>
__global__ __launch_bounds__(256)
void gemm_k(const float* __restrict__ A, int lda,
            const float* __restrict__ W,
            const float* __restrict__ bias,
            const float* __restrict__ Rres,
            float* __restrict__ C, int ldc,
            int M, int N, int K)
{
  __shared__ float As[16][68];
  __shared__ float Ws[16][68];
  const int bm = blockIdx.x << 6;
  const int bn = blockIdx.y << 6;
  const int tid = threadIdx.x;
  const int tm0 = (tid >> 4) << 2;
  const int tn0 = (tid & 15) << 2;
  const int r   = tid >> 2;
  const int kk4 = (tid & 3) << 2;
  float acc[4][4] = {};
  for (int k0 = 0; k0 < K; k0 += 16) {
    const int gk = k0 + kk4;
    float4 va = make_float4(0.f,0.f,0.f,0.f);
    const int gr = bm + r;
    if (gr < M && gk < K) va = *(const float4*)(A + (size_t)gr*lda + gk);
    As[kk4+0][r]=va.x; As[kk4+1][r]=va.y; As[kk4+2][r]=va.z; As[kk4+3][r]=va.w;
    float4 vw = make_float4(0.f,0.f,0.f,0.f);
    const int gc = bn + r;
    if (gc < N && gk < K) vw = *(const float4*)(W + (size_t)gc*K + gk);
    Ws[kk4+0][r]=vw.x; Ws[kk4+1][r]=vw.y; Ws[kk4+2][r]=vw.z; Ws[kk4+3][r]=vw.w;
    __syncthreads();
    #pragma unroll
    for (int kk = 0; kk < 16; ++kk) {
      const float a0=As[kk][tm0+0], a1=As[kk][tm0+1], a2=As[kk][tm0+2], a3=As[kk][tm0+3];
      const float w0=Ws[kk][tn0+0], w1=Ws[kk][tn0+1], w2=Ws[kk][tn0+2], w3=Ws[kk][tn0+3];
      acc[0][0]+=a0*w0; acc[0][1]+=a0*w1; acc[0][2]+=a0*w2; acc[0][3]+=a0*w3;
      acc[1][0]+=a1*w0; acc[1][1]+=a1*w1; acc[1][2]+=a1*w2; acc[1][3]+=a1*w3;
      acc[2][0]+=a2*w0; acc[2][1]+=a2*w1; acc[2][2]+=a2*w2; acc[2][3]+=a2*w3;
      acc[3][0]+=a3*w0; acc[3][1]+=a3*w1; acc[3][2]+=a3*w2; acc[3][3]+=a3*w3;
    }
    __syncthreads();
  }
  #pragma unroll
  for (int i=0;i<4;i++){
    const int row = bm + tm0 + i;
    if (row >= M) continue;
    #pragma unroll
    for (int j=0;j<4;j++){
      const int col = bn + tn0 + j;
      if (col >= N) continue;
      float v = acc[i][j];
      if (bias) v += bias[col];
      if (RES)  v += Rres[(size_t)row*ldc + col];
      if (ACT == 1) v = softplus_(v);
      C[(size_t)row*ldc + col] = v;
    }
  }
}

// ---------------- vectorized triple-split conversion (compile-time shapes) ----------------
// Y[Rpad x KP] bf16, row = [hi(C) | P2(C) | P3(C) | 0...]; MODEA=1: P2=hi,P3=lo; else P2=lo,P3=hi.
// Rows >= realR are zero.
template<int C, int KP, int MODEA>
__global__ void cvt3t_k(const float* __restrict__ X, int ldx, short* __restrict__ Y,
                        int realR, int total4)
{
  const int i4 = blockIdx.x*256 + threadIdx.x;
  if (i4 >= total4) return;
  const int idx = i4 << 2;
  const int c3 = idx % KP;
  const int r  = idx / KP;
  short4v out = {0,0,0,0};
  if (r < realR && c3 < 3*C) {
    const int part = c3 / C;
    const int c = c3 - part*C;
    const bool lo = MODEA ? (part == 2) : (part == 1);
    const float4 v = *(const float4*)(X + (size_t)r*ldx + c);
    out.x = bf_split(v.x, lo); out.y = bf_split(v.y, lo);
    out.z = bf_split(v.z, lo); out.w = bf_split(v.w, lo);
  }
  *(short4v*)(Y + (size_t)r*KP + c3) = out;
}

// ---------------- bf16 MFMA GEMM: C = act(A3 @ W3^T + bias [+ R]) ----------------
// A3: M x K3 bf16, W3: Npad x K3 bf16 (padded rows zero), C: M x NOUT fp32 (ldc).
// M%128==0, Npad%128==0, K3%32==0.
template<int ACT, int RES, int BIAS>
__global__ __launch_bounds__(256)
void gemm3b_k(const short* __restrict__ A3, const short* __restrict__ W3,
              const float* __restrict__ bias, const float* __restrict__ Rres,
              float* __restrict__ C, int ldc, int NOUT, int M, int N, int K3)
{
  __shared__ short As[128][40];
  __shared__ short Ws[128][40];
  const int bm = blockIdx.x << 7;
  const int bn = blockIdx.y << 7;
  const int tid = threadIdx.x;
  const int lane = tid & 63;
  const int wv = tid >> 6;
  const int wr = (wv >> 1) << 6;
  const int wc = (wv & 1) << 6;
  const int frow = lane & 15;
  const int fk   = lane >> 4;
  const int srow = tid >> 1;
  const int shalf = (tid & 1) << 4;

  floatx4 acc[4][4] = {};
  const short* gA = A3 + (size_t)(bm + srow)*K3 + shalf;
  const short* gW = W3 + (size_t)(bn + srow)*K3 + shalf;

  for (int k0 = 0; k0 < K3; k0 += 32) {
    short8v va0 = *(const short8v*)(gA + k0);
    short8v va1 = *(const short8v*)(gA + k0 + 8);
    short8v vw0 = *(const short8v*)(gW + k0);
    short8v vw1 = *(const short8v*)(gW + k0 + 8);
    __syncthreads();
    *(short8v*)&As[srow][shalf]     = va0;
    *(short8v*)&As[srow][shalf + 8] = va1;
    *(short8v*)&Ws[srow][shalf]     = vw0;
    *(short8v*)&Ws[srow][shalf + 8] = vw1;
    __syncthreads();
    short8v af[4], bfv[4];
    #pragma unroll
    for (int mf = 0; mf < 4; ++mf)
      af[mf] = *(const short8v*)&As[wr + mf*16 + frow][fk*8];
    #pragma unroll
    for (int nf = 0; nf < 4; ++nf)
      bfv[nf] = *(const short8v*)&Ws[wc + nf*16 + frow][fk*8];
    #pragma unroll
    for (int mf = 0; mf < 4; ++mf)
      #pragma unroll
      for (int nf = 0; nf < 4; ++nf)
        acc[mf][nf] = __builtin_amdgcn_mfma_f32_16x16x32_bf16(af[mf], bfv[nf], acc[mf][nf], 0, 0, 0);
  }

  #pragma unroll
  for (int mf = 0; mf < 4; ++mf) {
    #pragma unroll
    for (int nf = 0; nf < 4; ++nf) {
      const int col = bn + wc + nf*16 + (lane & 15);
      if (col >= NOUT) continue;
      #pragma unroll
      for (int r = 0; r < 4; ++r) {
        const int row = bm + wr + mf*16 + (lane >> 4)*4 + r;
        float v = acc[mf][nf][r];
        if (BIAS) v += bias[col];
        if (RES)  v += Rres[(size_t)row*ldc + col];
        if (ACT == 1) v = softplus_(v);
        C[(size_t)row*ldc + col] = v;
      }
    }
  }
}

// ---------------- patch conv as MFMA over im2col LDS tiles ----------------
// out[b, o, patch] = sum_{c,pos} x[b][c][patchpix(pos)] * w[o][c][pos]
// block = (bb, cs): cs = c-quarter (8 channels); partial[cs][b][o][patch]
__global__ __launch_bounds__(256)
void patch_mfma_k(const float* __restrict__ x, const float* __restrict__ w,
                  float* __restrict__ partial)
{
  const int bb = blockIdx.x >> 2;
  const int cs = blockIdx.x & 3;
  __shared__ short Ah[64][264], Al[64][264];
  __shared__ short Wh[32][264], Wl[32][264];
  const int tid = threadIdx.x;
  const int lane = tid & 63, wv = tid >> 6;
  const int frow = lane & 15, fk = lane >> 4;
  floatx4 acc[2] = {};
  for (int ci = 0; ci < 8; ++ci) {
    const int c = cs*8 + ci;
    __syncthreads();
    // stage x plane (128x128 contiguous) as im2col A[patch][pos], hi+lo
    const float4* xs = (const float4*)(x + ((size_t)bb*32 + c)*16384);
    #pragma unroll
    for (int q = 0; q < 16; ++q) {
      const int f4 = q*256 + tid;
      const float4 v = xs[f4];
      const int o4 = f4 << 2;
      const int h = o4 >> 7, ww = o4 & 127;
      const int patch = ((h >> 4) << 3) + (ww >> 4);
      const int pos = ((h & 15) << 4) + (ww & 15);
      short4v hv, lv;
      hv.x = bf_split(v.x,false); lv.x = bf_split(v.x,true);
      hv.y = bf_split(v.y,false); lv.y = bf_split(v.y,true);
      hv.z = bf_split(v.z,false); lv.z = bf_split(v.z,true);
      hv.w = bf_split(v.w,false); lv.w = bf_split(v.w,true);
      *(short4v*)&Ah[patch][pos] = hv;
      *(short4v*)&Al[patch][pos] = lv;
    }
    // stage weights for this channel: w[o][c][0..255]
    #pragma unroll
    for (int q = 0; q < 8; ++q) {
      const int f4 = q*256 + tid;
      const int o = f4 >> 6, pos = (f4 & 63) << 2;
      const float4 v = *(const float4*)(w + ((size_t)o*32 + c)*256 + pos);
      short4v hv, lv;
      hv.x = bf_split(v.x,false); lv.x = bf_split(v.x,true);
      hv.y = bf_split(v.y,false); lv.y = bf_split(v.y,true);
      hv.z = bf_split(v.z,false); lv.z = bf_split(v.z,true);
      hv.w = bf_split(v.w,false); lv.w = bf_split(v.w,true);
      *(short4v*)&Wh[o][pos] = hv;
      *(short4v*)&Wl[o][pos] = lv;
    }
    __syncthreads();
    // 3 part-passes: hi*hi + hi*lo + lo*hi
    #pragma unroll
    for (int part = 0; part < 3; ++part) {
      const short (*Asrc)[264] = (part == 2) ? Al : Ah;
      const short (*Wsrc)[264] = (part == 1) ? Wl : Wh;
      #pragma unroll
      for (int kc = 0; kc < 8; ++kc) {
        const short8v a  = *(const short8v*)&Asrc[wv*16 + frow][kc*32 + fk*8];
        const short8v b0 = *(const short8v*)&Wsrc[frow][kc*32 + fk*8];
        const short8v b1 = *(const short8v*)&Wsrc[16 + frow][kc*32 + fk*8];
        acc[0] = __builtin_amdgcn_mfma_f32_16x16x32_bf16(a, b0, acc[0], 0, 0, 0);
        acc[1] = __builtin_amdgcn_mfma_f32_16x16x32_bf16(a, b1, acc[1], 0, 0, 0);
      }
    }
  }
  #pragma unroll
  for (int nf = 0; nf < 2; ++nf) {
    const int o = nf*16 + (lane & 15);
    #pragma unroll
    for (int r = 0; r < 4; ++r) {
      const int patch = wv*16 + (lane >> 4)*4 + r;
      partial[(((size_t)cs*32 + bb)*32 + o)*64 + patch] = acc[nf][r];
    }
  }
}

__global__ void reduce_patch_k(const float* __restrict__ partial, const float* __restrict__ bias,
                               float* __restrict__ xp)
{
  const int idx = blockIdx.x*256 + threadIdx.x;   // 32*32*64
  if (idx >= 65536) return;
  const int o = (idx >> 6) & 31;
  float s = bias[o];
  #pragma unroll
  for (int cs = 0; cs < 4; ++cs) s += partial[(size_t)cs*65536 + idx];
  xp[idx] = s;
}

// ---------------- fused: x_proj assemble + gelu fuse + concat + layernorm ----------------
__global__ __launch_bounds__(256)
void fuse_ln_k(const float* __restrict__ xpat, const float* __restrict__ xprojbuf,
               const float* __restrict__ xfeat, const float* __restrict__ lnw,
               const float* __restrict__ lnb, const float* __restrict__ focusp,
               float* __restrict__ cat)
{
  const int row = blockIdx.x;
  const int t = threadIdx.x;
  const float focus = focusp[0];
  const float xp = xpat[(size_t)row*256 + t];
  const float pr = (t < 128) ? xfeat[(size_t)row*1280 + t] : xprojbuf[(size_t)row*256 + t];
  const float xf = gelu_(focus*pr + (2.f - focus)*xp);
  float s  = xp + xf + pr;
  float sq = xp*xp + xf*xf + pr*pr;
  __shared__ float rs[4], rq[4];
  const int lane = t & 63, wv = t >> 6;
  #pragma unroll
  for (int off = 32; off > 0; off >>= 1) {
    s  += __shfl_down(s,  off, 64);
    sq += __shfl_down(sq, off, 64);
  }
  if (lane == 0) { rs[wv] = s; rq[wv] = sq; }
  __syncthreads();
  const float S = rs[0]+rs[1]+rs[2]+rs[3];
  const float Q = rq[0]+rq[1]+rq[2]+rq[3];
  const float mu = S * (1.f/768.f);
  const float var = Q*(1.f/768.f) - mu*mu;
  const float rstd = rsqrtf(var + 1e-5f);
  const size_t ob = (size_t)row*768;
  cat[ob +        t] = (xp - mu)*rstd*lnw[      t] + lnb[      t];
  cat[ob + 256 +  t] = (xf - mu)*rstd*lnw[256 + t] + lnb[256 + t];
  cat[ob + 512 +  t] = (pr - mu)*rstd*lnw[512 + t] + lnb[512 + t];
}

// ---------------- prep: duplicate + flip ----------------
__global__ void prep_m1_k(const float* __restrict__ cat, float* __restrict__ X)
{
  const int idx = blockIdx.x*256 + threadIdx.x;
  if (idx >= 64*32*768) return;
  const int d = idx % 768;
  const int sl = idx / 768;
  const int l = sl & 31;
  const int s = sl >> 5;
  const int b = s & 31;
  const int ll = (s < 32) ? l : 31 - l;
  X[idx] = cat[((size_t)b*32 + ll)*768 + d];
}
__global__ void prep_m2_k(const float* __restrict__ cat, float* __restrict__ X)
{
  const int idx = blockIdx.x*256 + threadIdx.x;
  if (idx >= 64*768*32) return;
  const int c = idx & 31;
  const int sj = idx >> 5;
  const int j = sj % 768;
  const int s = sj / 768;
  const int b = (s < 32) ? s : s - 32;
  const int jj = (s < 32) ? j : 767 - j;
  X[idx] = cat[((size_t)b*32 + c)*768 + jj];
}

// ---------------- depthwise causal conv (k=4) + silu ----------------
__global__ void dwconv_silu_k(const float* __restrict__ xz, int ldxz,
                              const float* __restrict__ w, const float* __restrict__ b,
                              float* __restrict__ xc, int di, int L, int total)
{
  const int idx = blockIdx.x*256 + threadIdx.x;
  if (idx >= total) return;
  const int d = idx % di;
  const int sl = idx / di;
  const int l = sl % L;
  float acc = b[d];
  const float* wd = w + d*4;
  #pragma unroll
  for (int k = 0; k < 4; ++k) {
    const int ll = l - 3 + k;
    if (ll >= 0) acc += xz[(size_t)(sl - 3 + k)*ldxz + d] * wd[k];
  }
  xc[idx] = silu_(acc);
}

// ---------------- m2 dt projection (K=2) + softplus ----------------
__global__ void dt2_k(const float* __restrict__ dbl, const float* __restrict__ dt_w,
                      const float* __restrict__ dt_b, float* __restrict__ delta)
{
  const int idx = blockIdx.x*256 + threadIdx.x;
  if (idx >= 49152*64) return;
  const int d = idx & 63;
  const int r = idx >> 6;
  const float a0 = dbl[(size_t)r*34 + 0], a1 = dbl[(size_t)r*34 + 1];
  delta[idx] = softplus_(a0*dt_w[d*2] + a1*dt_w[d*2+1] + dt_b[d]);
}

// ---------------- m1 selective scan (L=32) ----------------
__global__ void scan_k(const float* __restrict__ delta, const float* __restrict__ xc,
                       const float* __restrict__ dbl, int lddbl, int droff,
                       const float* __restrict__ z, int ldz,
                       const float* __restrict__ A_log, const float* __restrict__ Dp,
                       float* __restrict__ Y, int di, int L, int total)
{
  const int idx = blockIdx.x*256 + threadIdx.x;
  if (idx >= total) return;
  const int d = idx % di;
  const int s = idx / di;
  float A[16], h[16];
  #pragma unroll
  for (int n = 0; n < 16; ++n) { A[n] = -__expf(A_log[d*16 + n]); h[n] = 0.f; }
  const float Dv = Dp[d];
  const size_t base = (size_t)s*L;
  for (int l = 0; l < L; ++l) {
    const size_t row = base + l;
    const float de  = delta[row*di + d];
    const float xcv = xc[row*di + d];
    const float du  = de * xcv;
    const float* bl = dbl + row*lddbl + droff;
    float y = 0.f;
    #pragma unroll
    for (int n = 0; n < 16; ++n) {
      const float dA = __expf(de * A[n]);
      h[n] = dA*h[n] + du*bl[n];
      y += h[n]*bl[16 + n];
    }
    const float zv = z[row*ldz + d];
    Y[row*di + d] = (y + xcv*Dv) * silu_(zv);
  }
}

// ---------------- m2 chunked scan: 12 chunks of 64 ----------------
#define NC2 12
#define LC2 64

__global__ __launch_bounds__(256)
void scan2_partA(const float* __restrict__ delta, const float* __restrict__ xc,
                 const float* __restrict__ dbl, const float* __restrict__ A_log,
                 float* __restrict__ Hend, unsigned short* __restrict__ sde_buf)
{
  const int t = blockIdx.x*256 + threadIdx.x;
  if (t >= 64*64*NC2) return;
  const int d = t & 63;
  const int c = (t >> 6) % NC2;
  const int s = t / (64*NC2);
  float A[16], h[16];
  #pragma unroll
  for (int n = 0; n < 16; ++n) { A[n] = -__expf(A_log[d*16 + n]); h[n] = 0.f; }
  float sde = 0.f;
  const size_t row0 = (size_t)s*768 + c*LC2;
  for (int l = 0; l < LC2; ++l) {
    const size_t row = row0 + l;
    const float de  = delta[row*64 + d];
    const float xcv = xc[row*64 + d];
    const float du  = de * xcv;
    const float* bl = dbl + row*34 + 2;
    sde += de;
    #pragma unroll
    for (int n = 0; n < 16; ++n)
      h[n] = __expf(de*A[n])*h[n] + du*bl[n];
  }
  float* hp = Hend + (size_t)t*16;
  #pragma unroll
  for (int n = 0; n < 16; ++n) hp[n] = h[n];
  const unsigned u = __float_as_uint(sde);
  sde_buf[t] = (unsigned short)((u + 0x7FFFu + ((u >> 16) & 1u)) >> 16);
}

__global__ void scan2_carry(const float* __restrict__ A_log,
                            float* __restrict__ Hend, const unsigned short* __restrict__ sde_buf)
{
  const int t = blockIdx.x*256 + threadIdx.x;
  if (t >= 4096) return;
  const int d = t & 63;
  const int s = t >> 6;
  float A[16], H[16];
  #pragma unroll
  for (int n = 0; n < 16; ++n) { A[n] = -__expf(A_log[d*16 + n]); H[n] = 0.f; }
  for (int c = 0; c < NC2; ++c) {
    const size_t off = ((size_t)(s*NC2 + c)*64 + d)*16;
    const float sde = __uint_as_float(((unsigned)sde_buf[(s*NC2 + c)*64 + d]) << 16);
    #pragma unroll
    for (int n = 0; n < 16; ++n) {
      const float he = Hend[off + n];
      Hend[off + n] = H[n];
      H[n] = __expf(sde*A[n])*H[n] + he;
    }
  }
}

__global__ __launch_bounds__(256)
void scan2_partC(const float* __restrict__ delta, const float* __restrict__ xc,
                 const float* __restrict__ dbl, const float* __restrict__ z,
                 const float* __restrict__ A_log, const float* __restrict__ Dp,
                 const float* __restrict__ Hin, float* __restrict__ Y)
{
  const int t = blockIdx.x*256 + threadIdx.x;
  if (t >= 64*64*NC2) return;
  const int d = t & 63;
  const int c = (t >> 6) % NC2;
  const int s = t / (64*NC2);
  float A[16], h[16];
  #pragma unroll
  for (int n = 0; n < 16; ++n) {
    A[n] = -__expf(A_log[d*16 + n]);
    h[n] = Hin[(size_t)t*16 + n];
  }
  const float Dv = Dp[d];
  const size_t row0 = (size_t)s*768 + c*LC2;
  for (int l = 0; l < LC2; ++l) {
    const size_t row = row0 + l;
    const float de  = delta[row*64 + d];
    const float xcv = xc[row*64 + d];
    const float du  = de * xcv;
    const float* bl = dbl + row*34 + 2;
    float y = 0.f;
    #pragma unroll
    for (int n = 0; n < 16; ++n) {
      const float dA = __expf(de*A[n]);
      h[n] = dA*h[n] + du*bl[n];
      y += h[n]*bl[16 + n];
    }
    const float zv = z[row*128 + d];
    Y[row*64 + d] = (y + xcv*Dv) * silu_(zv);
  }
}

// ---------------- combine + mean over l ----------------
__global__ __launch_bounds__(256)
void x3_k(const float* __restrict__ x1p, const float* __restrict__ x2p, float* __restrict__ x3)
{
  const int b = blockIdx.x;
  for (int j = threadIdx.x; j < 768; j += 256) {
    float s = 0.f;
    for (int i = 0; i < 32; ++i) {
      s += x1p[((size_t)b*32 + i)*768 + j] + x1p[((size_t)(b+32)*32 + i)*768 + j];
      s += x2p[((size_t)b*768 + j)*32 + i] + x2p[((size_t)(b+32)*768 + j)*32 + i];
    }
    x3[(size_t)b*768 + j] = s * (1.f/32.f);
  }
}

// ---------------- regression head ----------------
__global__ __launch_bounds__(512)
void head_k(const float* __restrict__ x3, const float* __restrict__ w1, const float* __restrict__ b1,
            const float* __restrict__ w2, const float* __restrict__ b2, float* __restrict__ out)
{
  const int b = blockIdx.x;
  const int t = threadIdx.x;
  __shared__ float xrow[768];
  for (int i = t; i < 768; i += 512) xrow[i] = x3[(size_t)b*768 + i];
  __syncthreads();
  float hv = 0.f;
  if (t < 384) {
    const float* wr = w1 + (size_t)t*768;
    float acc = b1[t];
    for (int d = 0; d < 768; ++d) acc += xrow[d]*wr[d];
    hv = acc * w2[t];
  }
  __shared__ float red[8];
  const int lane = t & 63, wv = t >> 6;
  #pragma unroll
  for (int off = 32; off > 0; off >>= 1) hv += __shfl_down(hv, off, 64);
  if (lane == 0) red[wv] = hv;
  __syncthreads();
  if (t == 0) {
    float s = b2[0];
    #pragma unroll
    for (int i = 0; i < 8; ++i) s += red[i];
    out[b] = s;
  }
}

extern "C" void kernel_launch(void* const* d_in, const int* in_sizes, int n_in,
                              void* d_out, int out_size, void* d_ws, size_t ws_size,
                              hipStream_t stream)
{
  (void)in_sizes; (void)n_in; (void)out_size;
  const float* x_cwt        = (const float*)d_in[0];
  const float* x_features   = (const float*)d_in[1];
  const float* patch_conv_w = (const float*)d_in[2];
  const float* patch_conv_b = (const float*)d_in[3];
  const float* patch_proj_w = (const float*)d_in[4];
  const float* patch_proj_b = (const float*)d_in[5];
  const float* feat_proj_w  = (const float*)d_in[6];
  const float* feat_proj_b  = (const float*)d_in[7];
  const float* ln_w         = (const float*)d_in[8];
  const float* ln_b         = (const float*)d_in[9];
  const float* focus        = (const float*)d_in[10];
  const float* reg_w1       = (const float*)d_in[11];
  const float* reg_b1       = (const float*)d_in[12];
  const float* reg_w2       = (const float*)d_in[13];
  const float* reg_b2       = (const float*)d_in[14];
  const float* m1w[9]; for (int i=0;i<9;i++) m1w[i] = (const float*)d_in[15+i];
  const float* m2w[9]; for (int i=0;i<9;i++) m2w[i] = (const float*)d_in[24+i];

  // ---- arena (floats) ----
  float* p = (float*)d_ws;
  size_t need = 0;
  auto alloc = [&](size_t n){ float* r = p; p += n; need += n; return r; };
  float* cat    = alloc(786432);    // front: cat | m2 loop: Hend
  float* m1x    = alloc(1572864);
  float* m2x    = alloc(1572864);
  float* x3     = alloc(24576);     // m2 loop: sde | end: x3
  float* bxz    = alloc(6291456);
  float* bxc    = alloc(3145728);
  float* bdbl   = alloc(1671168);
  float* bdelta = alloc(3145728);
  float* by     = alloc(3145728);
  if (ws_size < need * sizeof(float)) return;

  // front-end overlays (inside bxz / bxc / by — all dead before first use elsewhere)
  float* xp_buf    = bxz;             // 65,536
  float* x_patched = bxz + 65536;     // 262,144
  float* x_projb   = bxz + 327680;    // 262,144
  float* pc_part   = bxz + 589824;    // 262,144 (patch-conv partials)
  short* A3f = (short*)bxc;                    // 1024x3072 sh = 1,572,864 fl
  short* W3f = (short*)(bxc + 1600000);        // 128x3072 sh = 196,608 fl
  short* A3p = (short*)(bxc + 1900000);        // 1024x192 sh = 98,304 fl
  short* W3p = (short*)(bxc + 2100000);        // 256x192 sh = 24,576 fl
  // m1 overlays (liveness traced per step)
  short* A3i  = (short*)bxc;                   // 2048x2304 sh = 2,359,296 fl (<=bxc)
  short* W3i  = (short*)bdelta;                // 3072x2304 sh = 3,538,944 fl (bdelta+by head)
  short* A3x  = (short*)bdelta;                // 2048x4608 sh = 4,718,592 fl (bdelta + by[0..1.57M])
  short* W3x  = (short*)(by + 1600000);        // 128x4608 sh = 294,912 fl
  short* A3dt = (short*)(by + 1900000);        // 2048x160 sh = 163,840 fl
  short* W3dt = (short*)(by + 2100000);        // 1536x160 sh = 122,880 fl
  short* A3o  = (short*)bxz;                   // 2048x4608 sh = 4,718,592 fl (xz/z dead after scan)
  short* W3o  = (short*)bxc;                   // 768x4608 sh = 1,769,472 fl (xc dead after scan)
  // m2 scan overlays
  float* sHend = cat;
  unsigned short* sSde = (unsigned short*)x3;

  // ---- front-end ----
  patch_mfma_k<<<128, 256, 0, stream>>>(x_cwt, patch_conv_w, pc_part);
  reduce_patch_k<<<256, 256, 0, stream>>>(pc_part, patch_conv_b, xp_buf);
  // patch_proj: (1024x64)@(256x64)^T + b
  cvt3t_k<64,192,1><<<192, 256, 0, stream>>>(xp_buf, 64, A3p, 1024, 49152);
  cvt3t_k<64,192,0><<<48, 256, 0, stream>>>(patch_proj_w, 64, W3p, 256, 12288);
  gemm3b_k<0,0,1><<<dim3(8,2), 256, 0, stream>>>(A3p, W3p, patch_proj_b, nullptr,
                                                 x_patched, 256, 256, 1024, 256, 192);
  // feat_proj: (1024x1024)@(128x1024)^T + b -> x_projb[:,128:]
  cvt3t_k<1024,3072,1><<<3072, 256, 0, stream>>>(x_features + 256, 1280, A3f, 1024, 786432);
  cvt3t_k<1024,3072,0><<<384, 256, 0, stream>>>(feat_proj_w, 1024, W3f, 128, 98304);
  gemm3b_k<0,0,1><<<dim3(8,1), 256, 0, stream>>>(A3f, W3f, feat_proj_b, nullptr,
                                                 x_projb + 128, 256, 128, 1024, 128, 3072);
  fuse_ln_k<<<1024, 256, 0, stream>>>(x_patched, x_projb, x_features, ln_w, ln_b, focus, cat);
  prep_m1_k<<<6144, 256, 0, stream>>>(cat, m1x);

  // ---- m1: 2 layers on batched (64,32,768); di=1536, dr=48 ----
  for (int im = 0; im < 2; ++im) {
    const float* in_w   = m1w[0] + (size_t)im*3072*768;
    const float* conv_w = m1w[1] + (size_t)im*1536*4;
    const float* conv_b = m1w[2] + (size_t)im*1536;
    const float* xp_w   = m1w[3] + (size_t)im*80*1536;
    const float* dt_w   = m1w[4] + (size_t)im*1536*48;
    const float* dt_b   = m1w[5] + (size_t)im*1536;
    const float* A_log  = m1w[6] + (size_t)im*1536*16;
    const float* Dp     = m1w[7] + (size_t)im*1536;
    const float* out_w  = m1w[8] + (size_t)im*768*1536;
    // in-proj (A3i@bxc, W3i@bdelta; bxc/bdbl/bdelta/by dead here)
    cvt3t_k<768,2304,1><<<4608, 256, 0, stream>>>(m1x, 768, A3i, 2048, 1179648);
    cvt3t_k<768,2304,0><<<6912, 256, 0, stream>>>(in_w, 768, W3i, 3072, 1769472);
    gemm3b_k<0,0,0><<<dim3(16,24), 256, 0, stream>>>(A3i, W3i, nullptr, nullptr,
                                                     bxz, 3072, 3072, 2048, 3072, 2304);
    dwconv_silu_k<<<12288, 256, 0, stream>>>(bxz, 3072, conv_w, conv_b, bxc, 1536, 32, 2048*1536);
    // xp: (2048x1536)@(80->128 x1536)^T -> bdbl (ldc 80)
    cvt3t_k<1536,4608,1><<<9216, 256, 0, stream>>>(bxc, 1536, A3x, 2048, 2359296);
    cvt3t_k<1536,4608,0><<<576, 256, 0, stream>>>(xp_w, 1536, W3x, 80, 147456);
    gemm3b_k<0,0,0><<<dim3(16,1), 256, 0, stream>>>(A3x, W3x, nullptr, nullptr,
                                                    bdbl, 80, 80, 2048, 128, 4608);
    // dt: (2048x48)@(1536x48)^T + b, softplus -> bdelta (overwrites A3x head — dead)
    cvt3t_k<48,160,1><<<320, 256, 0, stream>>>(bdbl, 80, A3dt, 2048, 81920);
    cvt3t_k<48,160,0><<<240, 256, 0, stream>>>(dt_w, 48, W3dt, 1536, 61440);
    gemm3b_k<1,0,1><<<dim3(16,12), 256, 0, stream>>>(A3dt, W3dt, dt_b, nullptr,
                                                     bdelta, 1536, 1536, 2048, 1536, 160);
    scan_k<<<384, 256, 0, stream>>>(bdelta, bxc, bdbl, 80, 48, bxz + 1536, 3072,
                                    A_log, Dp, by, 1536, 32, 98304);
    // out-proj (A3o@bxz: z dead; W3o@bxc: xc dead) + residual
    cvt3t_k<1536,4608,1><<<9216, 256, 0, stream>>>(by, 1536, A3o, 2048, 2359296);
    cvt3t_k<1536,4608,0><<<3456, 256, 0, stream>>>(out_w, 1536, W3o, 768, 884736);
    gemm3b_k<0,1,0><<<dim3(16,6), 256, 0, stream>>>(A3o, W3o, nullptr, m1x,
                                                    m1x, 768, 768, 2048, 768, 4608);
  }

  // ---- m2 prep (cat still alive; becomes Hend afterwards) ----
  prep_m2_k<<<6144, 256, 0, stream>>>(cat, m2x);

  // ---- m2: 2 layers on batched (64,768,32); di=64, dr=2 ----
  for (int im = 0; im < 2; ++im) {
    const float* in_w   = m2w[0] + (size_t)im*128*32;
    const float* conv_w = m2w[1] + (size_t)im*64*4;
    const float* conv_b = m2w[2] + (size_t)im*64;
    const float* xp_w   = m2w[3] + (size_t)im*34*64;
    const float* dt_w   = m2w[4] + (size_t)im*64*2;
    const float* dt_b   = m2w[5] + (size_t)im*64;
    const float* A_log  = m2w[6] + (size_t)im*64*16;
    const float* Dp     = m2w[7] + (size_t)im*64;
    const float* out_w  = m2w[8] + (size_t)im*32*64;
    gemm_k<0,0><<<dim3(768,2), 256, 0, stream>>>(m2x, 32, in_w, nullptr, nullptr,
                                                 bxz, 128, 49152, 128, 32);
    dwconv_silu_k<<<12288, 256, 0, stream>>>(bxz, 128, conv_w, conv_b, bxc, 64, 768, 49152*64);
    gemm_k<0,0><<<dim3(768,1), 256, 0, stream>>>(bxc, 64, xp_w, nullptr, nullptr,
                                                 bdbl, 34, 49152, 34, 64);
    dt2_k<<<12288, 256, 0, stream>>>(bdbl, dt_w, dt_b, bdelta);
    scan2_partA<<<192, 256, 0, stream>>>(bdelta, bxc, bdbl, A_log, sHend, sSde);
    scan2_carry<<<16, 256, 0, stream>>>(A_log, sHend, sSde);
    scan2_partC<<<192, 256, 0, stream>>>(bdelta, bxc, bdbl, bxz + 64, A_log, Dp, sHend, by);
    gemm_k<0,1><<<dim3(768,1), 256, 0, stream>>>(by, 64, out_w, nullptr, m2x,
                                                 m2x, 32, 49152, 32, 64);
  }

  // ---- head ----
  x3_k<<<32, 256, 0, stream>>>(m1x, m2x, x3);
  head_k<<<32, 512, 0, stream>>>(x3, reg_w1, reg_b1, reg_w2, reg_b2, (float*)d_out);
}

// Round 6
// 1021.486 us; speedup vs baseline: 2.4712x; 1.6008x over previous
//
#include <hip/hip_runtime.h>
#include <math.h>

#define DEV __device__ __forceinline__

DEV float sigmoid_(float x){ return 1.f/(1.f+__expf(-x)); }
DEV float silu_(float x){ return x * sigmoid_(x); }
DEV float softplus_(float x){ return (x > 20.f) ? x : log1pf(__expf(x)); }
DEV float gelu_(float x){ return 0.5f*x*(1.f + erff(x*0.70710678118654752440f)); }

typedef __attribute__((ext_vector_type(8))) short short8v;
typedef __attribute__((ext_vector_type(4))) short short4v;
typedef __attribute__((ext_vector_type(4))) float floatx4;

// round-to-nearest-even bf16 split: returns hi or lo part as bf16 bits
DEV short bf_split(float x, bool want_lo){
  unsigned u = __float_as_uint(x);
  unsigned hb = (u + 0x7FFFu + ((u >> 16) & 1u)) >> 16;
  if (!want_lo) return (short)hb;
  float lo = x - __uint_as_float(hb << 16);
  unsigned ul = __float_as_uint(lo);
  return (short)((ul + 0x7FFFu + ((ul >> 16) & 1u)) >> 16);
}

// ---------------- fp32 GEMM (kept for m2's K<=64 streaming shapes) ----------------
template<int ACT, int RES>
__global__ __launch_bounds__(256)
void gemm_k(const float* __restrict__ A, int lda,
            const float* __restrict__ W,
            const float* __restrict__ bias,
            const float* __restrict__ Rres,
            float* __restrict__ C, int ldc,
            int M, int N, int K)
{
  __shared__ float As[16][68];
  __shared__ float Ws[16][68];
  const int bm = blockIdx.x << 6;
  const int bn = blockIdx.y << 6;
  const int tid = threadIdx.x;
  const int tm0 = (tid >> 4) << 2;
  const int tn0 = (tid & 15) << 2;
  const int r   = tid >> 2;
  const int kk4 = (tid & 3) << 2;
  float acc[4][4] = {};
  for (int k0 = 0; k0 < K; k0 += 16) {
    const int gk = k0 + kk4;
    float4 va = make_float4(0.f,0.f,0.f,0.f);
    const int gr = bm + r;
    if (gr < M && gk < K) va = *(const float4*)(A + (size_t)gr*lda + gk);
    As[kk4+0][r]=va.x; As[kk4+1][r]=va.y; As[kk4+2][r]=va.z; As[kk4+3][r]=va.w;
    float4 vw = make_float4(0.f,0.f,0.f,0.f);
    const int gc = bn + r;
    if (gc < N && gk < K) vw = *(const float4*)(W + (size_t)gc*K + gk);
    Ws[kk4+0][r]=vw.x; Ws[kk4+1][r]=vw.y; Ws[kk4+2][r]=vw.z; Ws[kk4+3][r]=vw.w;
    __syncthreads();
    #pragma unroll
    for (int kk = 0; kk < 16; ++kk) {
      const float a0=As[kk][tm0+0], a1=As[kk][tm0+1], a2=As[kk][tm0+2], a3=As[kk][tm0+3];
      const float w0=Ws[kk][tn0+0], w1=Ws[kk][tn0+1], w2=Ws[kk][tn0+2], w3=Ws[kk][tn0+3];
      acc[0][0]+=a0*w0; acc[0][1]+=a0*w1; acc[0][2]+=a0*w2; acc[0][3]+=a0*w3;
      acc[1][0]+=a1*w0; acc[1][1]+=a1*w1; acc[1][2]+=a1*w2; acc[1][3]+=a1*w3;
      acc[2][0]+=a2*w0; acc[2][1]+=a2*w1; acc[2][2]+=a2*w2; acc[2][3]+=a2*w3;
      acc[3][0]+=a3*w0; acc[3][1]+=a3*w1; acc[3][2]+=a3*w2; acc[3][3]+=a3*w3;
    }
    __syncthreads();
  }
  #pragma unroll
  for (int i=0;i<4;i++){
    const int row = bm + tm0 + i;
    if (row >= M) continue;
    #pragma unroll
    for (int j=0;j<4;j++){
      const int col = bn + tn0 + j;
      if (col >= N) continue;
      float v = acc[i][j];
      if (bias) v += bias[col];
      if (RES)  v += Rres[(size_t)row*ldc + col];
      if (ACT == 1) v = softplus_(v);
      C[(size_t)row*ldc + col] = v;
    }
  }
}

// ---------------- vectorized triple-split conversion ----------------
template<int C, int KP, int MODEA>
__global__ void cvt3t_k(const float* __restrict__ X, int ldx, short* __restrict__ Y,
                        int realR, int total4)
{
  const int i4 = blockIdx.x*256 + threadIdx.x;
  if (i4 >= total4) return;
  const int idx = i4 << 2;
  const int c3 = idx % KP;
  const int r  = idx / KP;
  short4v out = {0,0,0,0};
  if (r < realR && c3 < 3*C) {
    const int part = c3 / C;
    const int c = c3 - part*C;
    const bool lo = MODEA ? (part == 2) : (part == 1);
    const float4 v = *(const float4*)(X + (size_t)r*ldx + c);
    out.x = bf_split(v.x, lo); out.y = bf_split(v.y, lo);
    out.z = bf_split(v.z, lo); out.w = bf_split(v.w, lo);
  }
  *(short4v*)(Y + (size_t)r*KP + c3) = out;
}

// ---------------- bf16 MFMA GEMM (pipelined loads): C = act(A3 @ W3^T + bias [+ R]) ----------------
template<int ACT, int RES, int BIAS>
__global__ __launch_bounds__(256)
void gemm3b_k(const short* __restrict__ A3, const short* __restrict__ W3,
              const float* __restrict__ bias, const float* __restrict__ Rres,
              float* __restrict__ C, int ldc, int NOUT, int M, int N, int K3)
{
  __shared__ short As[128][40];
  __shared__ short Ws[128][40];
  const int bm = blockIdx.x << 7;
  const int bn = blockIdx.y << 7;
  const int tid = threadIdx.x;
  const int lane = tid & 63;
  const int wv = tid >> 6;
  const int wr = (wv >> 1) << 6;
  const int wc = (wv & 1) << 6;
  const int frow = lane & 15;
  const int fk   = lane >> 4;
  const int srow = tid >> 1;
  const int shalf = (tid & 1) << 4;

  floatx4 acc[4][4] = {};
  const short* gA = A3 + (size_t)(bm + srow)*K3 + shalf;
  const short* gW = W3 + (size_t)(bn + srow)*K3 + shalf;

  short8v va0 = *(const short8v*)(gA);
  short8v va1 = *(const short8v*)(gA + 8);
  short8v vw0 = *(const short8v*)(gW);
  short8v vw1 = *(const short8v*)(gW + 8);

  for (int k0 = 0; k0 < K3; k0 += 32) {
    __syncthreads();
    *(short8v*)&As[srow][shalf]     = va0;
    *(short8v*)&As[srow][shalf + 8] = va1;
    *(short8v*)&Ws[srow][shalf]     = vw0;
    *(short8v*)&Ws[srow][shalf + 8] = vw1;
    __syncthreads();
    const int kn = k0 + 32;
    if (kn < K3) {           // issue next-tile loads; overlap with frag reads + MFMA
      va0 = *(const short8v*)(gA + kn);
      va1 = *(const short8v*)(gA + kn + 8);
      vw0 = *(const short8v*)(gW + kn);
      vw1 = *(const short8v*)(gW + kn + 8);
    }
    short8v af[4], bfv[4];
    #pragma unroll
    for (int mf = 0; mf < 4; ++mf)
      af[mf] = *(const short8v*)&As[wr + mf*16 + frow][fk*8];
    #pragma unroll
    for (int nf = 0; nf < 4; ++nf)
      bfv[nf] = *(const short8v*)&Ws[wc + nf*16 + frow][fk*8];
    #pragma unroll
    for (int mf = 0; mf < 4; ++mf)
      #pragma unroll
      for (int nf = 0; nf < 4; ++nf)
        acc[mf][nf] = __builtin_amdgcn_mfma_f32_16x16x32_bf16(af[mf], bfv[nf], acc[mf][nf], 0, 0, 0);
  }

  #pragma unroll
  for (int mf = 0; mf < 4; ++mf) {
    #pragma unroll
    for (int nf = 0; nf < 4; ++nf) {
      const int col = bn + wc + nf*16 + (lane & 15);
      if (col >= NOUT) continue;
      #pragma unroll
      for (int r = 0; r < 4; ++r) {
        const int row = bm + wr + mf*16 + (lane >> 4)*4 + r;
        float v = acc[mf][nf][r];
        if (BIAS) v += bias[col];
        if (RES)  v += Rres[(size_t)row*ldc + col];
        if (ACT == 1) v = softplus_(v);
        C[(size_t)row*ldc + col] = v;
      }
    }
  }
}

// ---------------- split-K variant: partial planes Cpart[z][M][ldc], no bias/act ----------------
__global__ __launch_bounds__(256)
void gemm3bz_k(const short* __restrict__ A3, const short* __restrict__ W3,
               float* __restrict__ C, int ldc, int NOUT, int M, int K3, int KC)
{
  __shared__ short As[128][40];
  __shared__ short Ws[128][40];
  const int bm = blockIdx.x << 7;
  const int bn = blockIdx.y << 7;
  const int kbeg = blockIdx.z * KC;
  float* Cpart = C + (size_t)blockIdx.z * M * ldc;
  const int tid = threadIdx.x;
  const int lane = tid & 63;
  const int wv = tid >> 6;
  const int wr = (wv >> 1) << 6;
  const int wc = (wv & 1) << 6;
  const int frow = lane & 15;
  const int fk   = lane >> 4;
  const int srow = tid >> 1;
  const int shalf = (tid & 1) << 4;

  floatx4 acc[4][4] = {};
  const short* gA = A3 + (size_t)(bm + srow)*K3 + shalf + kbeg;
  const short* gW = W3 + (size_t)(bn + srow)*K3 + shalf + kbeg;

  short8v va0 = *(const short8v*)(gA);
  short8v va1 = *(const short8v*)(gA + 8);
  short8v vw0 = *(const short8v*)(gW);
  short8v vw1 = *(const short8v*)(gW + 8);

  for (int k0 = 0; k0 < KC; k0 += 32) {
    __syncthreads();
    *(short8v*)&As[srow][shalf]     = va0;
    *(short8v*)&As[srow][shalf + 8] = va1;
    *(short8v*)&Ws[srow][shalf]     = vw0;
    *(short8v*)&Ws[srow][shalf + 8] = vw1;
    __syncthreads();
    const int kn = k0 + 32;
    if (kn < KC) {
      va0 = *(const short8v*)(gA + kn);
      va1 = *(const short8v*)(gA + kn + 8);
      vw0 = *(const short8v*)(gW + kn);
      vw1 = *(const short8v*)(gW + kn + 8);
    }
    short8v af[4], bfv[4];
    #pragma unroll
    for (int mf = 0; mf < 4; ++mf)
      af[mf] = *(const short8v*)&As[wr + mf*16 + frow][fk*8];
    #pragma unroll
    for (int nf = 0; nf < 4; ++nf)
      bfv[nf] = *(const short8v*)&Ws[wc + nf*16 + frow][fk*8];
    #pragma unroll
    for (int mf = 0; mf < 4; ++mf)
      #pragma unroll
      for (int nf = 0; nf < 4; ++nf)
        acc[mf][nf] = __builtin_amdgcn_mfma_f32_16x16x32_bf16(af[mf], bfv[nf], acc[mf][nf], 0, 0, 0);
  }

  #pragma unroll
  for (int mf = 0; mf < 4; ++mf) {
    #pragma unroll
    for (int nf = 0; nf < 4; ++nf) {
      const int col = bn + wc + nf*16 + (lane & 15);
      if (col >= NOUT) continue;
      #pragma unroll
      for (int r = 0; r < 4; ++r) {
        const int row = bm + wr + mf*16 + (lane >> 4)*4 + r;
        Cpart[(size_t)row*ldc + col] = acc[mf][nf][r];
      }
    }
  }
}

// ---------------- split-K reduce kernels ----------------
__global__ void reduce_xp_k(const float* __restrict__ part, float* __restrict__ out)
{
  const int i = blockIdx.x*256 + threadIdx.x;   // 2048*80
  if (i >= 163840) return;
  float s = 0.f;
  #pragma unroll
  for (int z = 0; z < 8; ++z) s += part[(size_t)z*163840 + i];
  out[i] = s;
}
__global__ void reduce_feat_k(const float* __restrict__ part, const float* __restrict__ bias,
                              float* __restrict__ out /* x_projb base */)
{
  const int i = blockIdx.x*256 + threadIdx.x;   // 1024*128
  if (i >= 131072) return;
  const int r = i >> 7, c = i & 127;
  float s = bias[c];
  #pragma unroll
  for (int z = 0; z < 8; ++z) s += part[(size_t)z*131072 + i];
  out[(size_t)r*256 + 128 + c] = s;
}
__global__ void reduce_out_k(const float* __restrict__ part, float* __restrict__ m1x)
{
  const int i = blockIdx.x*256 + threadIdx.x;   // 2048*768
  if (i >= 1572864) return;
  float s = m1x[i];
  #pragma unroll
  for (int z = 0; z < 4; ++z) s += part[(size_t)z*1572864 + i];
  m1x[i] = s;
}

// ---------------- m1 delta projection: streaming K=48 dot + softplus ----------------
// grid (256, 6); block: rows r0..r0+8, cols d = by*256+tid; dt_w row kept in 48 VGPRs
__global__ __launch_bounds__(256)
void dt1_k(const float* __restrict__ dbl, const float* __restrict__ dt_w,
           const float* __restrict__ dt_b, float* __restrict__ delta)
{
  const int d = blockIdx.y*256 + threadIdx.x;
  const int r0 = blockIdx.x*8;
  float w[48];
  #pragma unroll
  for (int q = 0; q < 12; ++q)
    *(float4*)&w[q*4] = *(const float4*)(dt_w + (size_t)d*48 + q*4);
  __shared__ float sdbl[8][48];
  if (threadIdx.x < 96) {
    const int rr = threadIdx.x / 12, q = threadIdx.x % 12;
    *(float4*)&sdbl[rr][q*4] = *(const float4*)(dbl + (size_t)(r0+rr)*80 + q*4);
  }
  __syncthreads();
  const float bv = dt_b[d];
  #pragma unroll
  for (int rr = 0; rr < 8; ++rr) {
    float acc = bv;
    #pragma unroll
    for (int k = 0; k < 48; ++k) acc += sdbl[rr][k]*w[k];
    delta[(size_t)(r0+rr)*1536 + d] = softplus_(acc);
  }
}

// ---------------- patch conv as MFMA over im2col LDS tiles ----------------
__global__ __launch_bounds__(256)
void patch_mfma_k(const float* __restrict__ x, const float* __restrict__ w,
                  float* __restrict__ partial)
{
  const int bb = blockIdx.x >> 2;
  const int cs = blockIdx.x & 3;
  __shared__ short Ah[64][264], Al[64][264];
  __shared__ short Wh[32][264], Wl[32][264];
  const int tid = threadIdx.x;
  const int lane = tid & 63, wv = tid >> 6;
  const int frow = lane & 15, fk = lane >> 4;
  floatx4 acc[2] = {};
  for (int ci = 0; ci < 8; ++ci) {
    const int c = cs*8 + ci;
    __syncthreads();
    const float4* xs = (const float4*)(x + ((size_t)bb*32 + c)*16384);
    #pragma unroll
    for (int q = 0; q < 16; ++q) {
      const int f4 = q*256 + tid;
      const float4 v = xs[f4];
      const int o4 = f4 << 2;
      const int h = o4 >> 7, ww = o4 & 127;
      const int patch = ((h >> 4) << 3) + (ww >> 4);
      const int pos = ((h & 15) << 4) + (ww & 15);
      short4v hv, lv;
      hv.x = bf_split(v.x,false); lv.x = bf_split(v.x,true);
      hv.y = bf_split(v.y,false); lv.y = bf_split(v.y,true);
      hv.z = bf_split(v.z,false); lv.z = bf_split(v.z,true);
      hv.w = bf_split(v.w,false); lv.w = bf_split(v.w,true);
      *(short4v*)&Ah[patch][pos] = hv;
      *(short4v*)&Al[patch][pos] = lv;
    }
    #pragma unroll
    for (int q = 0; q < 8; ++q) {
      const int f4 = q*256 + tid;
      const int o = f4 >> 6, pos = (f4 & 63) << 2;
      const float4 v = *(const float4*)(w + ((size_t)o*32 + c)*256 + pos);
      short4v hv, lv;
      hv.x = bf_split(v.x,false); lv.x = bf_split(v.x,true);
      hv.y = bf_split(v.y,false); lv.y = bf_split(v.y,true);
      hv.z = bf_split(v.z,false); lv.z = bf_split(v.z,true);
      hv.w = bf_split(v.w,false); lv.w = bf_split(v.w,true);
      *(short4v*)&Wh[o][pos] = hv;
      *(short4v*)&Wl[o][pos] = lv;
    }
    __syncthreads();
    #pragma unroll
    for (int part = 0; part < 3; ++part) {
      const short (*Asrc)[264] = (part == 2) ? Al : Ah;
      const short (*Wsrc)[264] = (part == 1) ? Wl : Wh;
      #pragma unroll
      for (int kc = 0; kc < 8; ++kc) {
        const short8v a  = *(const short8v*)&Asrc[wv*16 + frow][kc*32 + fk*8];
        const short8v b0 = *(const short8v*)&Wsrc[frow][kc*32 + fk*8];
        const short8v b1 = *(const short8v*)&Wsrc[16 + frow][kc*32 + fk*8];
        acc[0] = __builtin_amdgcn_mfma_f32_16x16x32_bf16(a, b0, acc[0], 0, 0, 0);
        acc[1] = __builtin_amdgcn_mfma_f32_16x16x32_bf16(a, b1, acc[1], 0, 0, 0);
      }
    }
  }
  #pragma unroll
  for (int nf = 0; nf < 2; ++nf) {
    const int o = nf*16 + (lane & 15);
    #pragma unroll
    for (int r = 0; r < 4; ++r) {
      const int patch = wv*16 + (lane >> 4)*4 + r;
      partial[(((size_t)cs*32 + bb)*32 + o)*64 + patch] = acc[nf][r];
    }
  }
}

__global__ void reduce_patch_k(const float* __restrict__ partial, const float* __restrict__ bias,
                               float* __restrict__ xp)
{
  const int idx = blockIdx.x*256 + threadIdx.x;
  if (idx >= 65536) return;
  const int o = (idx >> 6) & 31;
  float s = bias[o];
  #pragma unroll
  for (int cs = 0; cs < 4; ++cs) s += partial[(size_t)cs*65536 + idx];
  xp[idx] = s;
}

// ---------------- fused: x_proj assemble + gelu fuse + concat + layernorm ----------------
__global__ __launch_bounds__(256)
void fuse_ln_k(const float* __restrict__ xpat, const float* __restrict__ xprojbuf,
               const float* __restrict__ xfeat, const float* __restrict__ lnw,
               const float* __restrict__ lnb, const float* __restrict__ focusp,
               float* __restrict__ cat)
{
  const int row = blockIdx.x;
  const int t = threadIdx.x;
  const float focus = focusp[0];
  const float xp = xpat[(size_t)row*256 + t];
  const float pr = (t < 128) ? xfeat[(size_t)row*1280 + t] : xprojbuf[(size_t)row*256 + t];
  const float xf = gelu_(focus*pr + (2.f - focus)*xp);
  float s  = xp + xf + pr;
  float sq = xp*xp + xf*xf + pr*pr;
  __shared__ float rs[4], rq[4];
  const int lane = t & 63, wv = t >> 6;
  #pragma unroll
  for (int off = 32; off > 0; off >>= 1) {
    s  += __shfl_down(s,  off, 64);
    sq += __shfl_down(sq, off, 64);
  }
  if (lane == 0) { rs[wv] = s; rq[wv] = sq; }
  __syncthreads();
  const float S = rs[0]+rs[1]+rs[2]+rs[3];
  const float Q = rq[0]+rq[1]+rq[2]+rq[3];
  const float mu = S * (1.f/768.f);
  const float var = Q*(1.f/768.f) - mu*mu;
  const float rstd = rsqrtf(var + 1e-5f);
  const size_t ob = (size_t)row*768;
  cat[ob +        t] = (xp - mu)*rstd*lnw[      t] + lnb[      t];
  cat[ob + 256 +  t] = (xf - mu)*rstd*lnw[256 + t] + lnb[256 + t];
  cat[ob + 512 +  t] = (pr - mu)*rstd*lnw[512 + t] + lnb[512 + t];
}

// ---------------- prep: duplicate + flip ----------------
__global__ void prep_m1_k(const float* __restrict__ cat, float* __restrict__ X)
{
  const int idx = blockIdx.x*256 + threadIdx.x;
  if (idx >= 64*32*768) return;
  const int d = idx % 768;
  const int sl = idx / 768;
  const int l = sl & 31;
  const int s = sl >> 5;
  const int b = s & 31;
  const int ll = (s < 32) ? l : 31 - l;
  X[idx] = cat[((size_t)b*32 + ll)*768 + d];
}
__global__ void prep_m2_k(const float* __restrict__ cat, float* __restrict__ X)
{
  const int idx = blockIdx.x*256 + threadIdx.x;
  if (idx >= 64*768*32) return;
  const int c = idx & 31;
  const int sj = idx >> 5;
  const int j = sj % 768;
  const int s = sj / 768;
  const int b = (s < 32) ? s : s - 32;
  const int jj = (s < 32) ? j : 767 - j;
  X[idx] = cat[((size_t)b*32 + c)*768 + jj];
}

// ---------------- depthwise causal conv (k=4) + silu ----------------
__global__ void dwconv_silu_k(const float* __restrict__ xz, int ldxz,
                              const float* __restrict__ w, const float* __restrict__ b,
                              float* __restrict__ xc, int di, int L, int total)
{
  const int idx = blockIdx.x*256 + threadIdx.x;
  if (idx >= total) return;
  const int d = idx % di;
  const int sl = idx / di;
  const int l = sl % L;
  float acc = b[d];
  const float* wd = w + d*4;
  #pragma unroll
  for (int k = 0; k < 4; ++k) {
    const int ll = l - 3 + k;
    if (ll >= 0) acc += xz[(size_t)(sl - 3 + k)*ldxz + d] * wd[k];
  }
  xc[idx] = silu_(acc);
}

// ---------------- m2 dt projection (K=2) + softplus ----------------
__global__ void dt2_k(const float* __restrict__ dbl, const float* __restrict__ dt_w,
                      const float* __restrict__ dt_b, float* __restrict__ delta)
{
  const int idx = blockIdx.x*256 + threadIdx.x;
  if (idx >= 49152*64) return;
  const int d = idx & 63;
  const int r = idx >> 6;
  const float a0 = dbl[(size_t)r*34 + 0], a1 = dbl[(size_t)r*34 + 1];
  delta[idx] = softplus_(a0*dt_w[d*2] + a1*dt_w[d*2+1] + dt_b[d]);
}

// ---------------- m1 selective scan (L=32) ----------------
__global__ void scan_k(const float* __restrict__ delta, const float* __restrict__ xc,
                       const float* __restrict__ dbl, int lddbl, int droff,
                       const float* __restrict__ z, int ldz,
                       const float* __restrict__ A_log, const float* __restrict__ Dp,
                       float* __restrict__ Y, int di, int L, int total)
{
  const int idx = blockIdx.x*256 + threadIdx.x;
  if (idx >= total) return;
  const int d = idx % di;
  const int s = idx / di;
  float A[16], h[16];
  #pragma unroll
  for (int n = 0; n < 16; ++n) { A[n] = -__expf(A_log[d*16 + n]); h[n] = 0.f; }
  const float Dv = Dp[d];
  const size_t base = (size_t)s*L;
  for (int l = 0; l < L; ++l) {
    const size_t row = base + l;
    const float de  = delta[row*di + d];
    const float xcv = xc[row*di + d];
    const float du  = de * xcv;
    const float* bl = dbl + row*lddbl + droff;
    float y = 0.f;
    #pragma unroll
    for (int n = 0; n < 16; ++n) {
      const float dA = __expf(de * A[n]);
      h[n] = dA*h[n] + du*bl[n];
      y += h[n]*bl[16 + n];
    }
    const float zv = z[row*ldz + d];
    Y[row*di + d] = (y + xcv*Dv) * silu_(zv);
  }
}

// ---------------- m2 chunked scan: 12 chunks of 64 ----------------
#define NC2 12
#define LC2 64

__global__ __launch_bounds__(256)
void scan2_partA(const float* __restrict__ delta, const float* __restrict__ xc,
                 const float* __restrict__ dbl, const float* __restrict__ A_log,
                 float* __restrict__ Hend, unsigned short* __restrict__ sde_buf)
{
  const int t = blockIdx.x*256 + threadIdx.x;
  if (t >= 64*64*NC2) return;
  const int d = t & 63;
  const int c = (t >> 6) % NC2;
  const int s = t / (64*NC2);
  float A[16], h[16];
  #pragma unroll
  for (int n = 0; n < 16; ++n) { A[n] = -__expf(A_log[d*16 + n]); h[n] = 0.f; }
  float sde = 0.f;
  const size_t row0 = (size_t)s*768 + c*LC2;
  for (int l = 0; l < LC2; ++l) {
    const size_t row = row0 + l;
    const float de  = delta[row*64 + d];
    const float xcv = xc[row*64 + d];
    const float du  = de * xcv;
    const float* bl = dbl + row*34 + 2;
    sde += de;
    #pragma unroll
    for (int n = 0; n < 16; ++n)
      h[n] = __expf(de*A[n])*h[n] + du*bl[n];
  }
  float* hp = Hend + (size_t)t*16;
  #pragma unroll
  for (int n = 0; n < 16; ++n) hp[n] = h[n];
  const unsigned u = __float_as_uint(sde);
  sde_buf[t] = (unsigned short)((u + 0x7FFFu + ((u >> 16) & 1u)) >> 16);
}

__global__ void scan2_carry(const float* __restrict__ A_log,
                            float* __restrict__ Hend, const unsigned short* __restrict__ sde_buf)
{
  const int t = blockIdx.x*256 + threadIdx.x;
  if (t >= 4096) return;
  const int d = t & 63;
  const int s = t >> 6;
  float A[16], H[16];
  #pragma unroll
  for (int n = 0; n < 16; ++n) { A[n] = -__expf(A_log[d*16 + n]); H[n] = 0.f; }
  for (int c = 0; c < NC2; ++c) {
    const size_t off = ((size_t)(s*NC2 + c)*64 + d)*16;
    const float sde = __uint_as_float(((unsigned)sde_buf[(s*NC2 + c)*64 + d]) << 16);
    #pragma unroll
    for (int n = 0; n < 16; ++n) {
      const float he = Hend[off + n];
      Hend[off + n] = H[n];
      H[n] = __expf(sde*A[n])*H[n] + he;
    }
  }
}

__global__ __launch_bounds__(256)
void scan2_partC(const float* __restrict__ delta, const float* __restrict__ xc,
                 const float* __restrict__ dbl, const float* __restrict__ z,
                 const float* __restrict__ A_log, const float* __restrict__ Dp,
                 const float* __restrict__ Hin, float* __restrict__ Y)
{
  const int t = blockIdx.x*256 + threadIdx.x;
  if (t >= 64*64*NC2) return;
  const int d = t & 63;
  const int c = (t >> 6) % NC2;
  const int s = t / (64*NC2);
  float A[16], h[16];
  #pragma unroll
  for (int n = 0; n < 16; ++n) {
    A[n] = -__expf(A_log[d*16 + n]);
    h[n] = Hin[(size_t)t*16 + n];
  }
  const float Dv = Dp[d];
  const size_t row0 = (size_t)s*768 + c*LC2;
  for (int l = 0; l < LC2; ++l) {
    const size_t row = row0 + l;
    const float de  = delta[row*64 + d];
    const float xcv = xc[row*64 + d];
    const float du  = de * xcv;
    const float* bl = dbl + row*34 + 2;
    float y = 0.f;
    #pragma unroll
    for (int n = 0; n < 16; ++n) {
      const float dA = __expf(de*A[n]);
      h[n] = dA*h[n] + du*bl[n];
      y += h[n]*bl[16 + n];
    }
    const float zv = z[row*128 + d];
    Y[row*64 + d] = (y + xcv*Dv) * silu_(zv);
  }
}

// ---------------- combine + mean over l ----------------
__global__ __launch_bounds__(256)
void x3_k(const float* __restrict__ x1p, const float* __restrict__ x2p, float* __restrict__ x3)
{
  const int b = blockIdx.x;
  for (int j = threadIdx.x; j < 768; j += 256) {
    float s = 0.f;
    for (int i = 0; i < 32; ++i) {
      s += x1p[((size_t)b*32 + i)*768 + j] + x1p[((size_t)(b+32)*32 + i)*768 + j];
      s += x2p[((size_t)b*768 + j)*32 + i] + x2p[((size_t)(b+32)*768 + j)*32 + i];
    }
    x3[(size_t)b*768 + j] = s * (1.f/32.f);
  }
}

// ---------------- regression head ----------------
__global__ __launch_bounds__(512)
void head_k(const float* __restrict__ x3, const float* __restrict__ w1, const float* __restrict__ b1,
            const float* __restrict__ w2, const float* __restrict__ b2, float* __restrict__ out)
{
  const int b = blockIdx.x;
  const int t = threadIdx.x;
  __shared__ float xrow[768];
  for (int i = t; i < 768; i += 512) xrow[i] = x3[(size_t)b*768 + i];
  __syncthreads();
  float hv = 0.f;
  if (t < 384) {
    const float* wr = w1 + (size_t)t*768;
    float acc = b1[t];
    for (int d = 0; d < 768; ++d) acc += xrow[d]*wr[d];
    hv = acc * w2[t];
  }
  __shared__ float red[8];
  const int lane = t & 63, wv = t >> 6;
  #pragma unroll
  for (int off = 32; off > 0; off >>= 1) hv += __shfl_down(hv, off, 64);
  if (lane == 0) red[wv] = hv;
  __syncthreads();
  if (t == 0) {
    float s = b2[0];
    #pragma unroll
    for (int i = 0; i < 8; ++i) s += red[i];
    out[b] = s;
  }
}

extern "C" void kernel_launch(void* const* d_in, const int* in_sizes, int n_in,
                              void* d_out, int out_size, void* d_ws, size_t ws_size,
                              hipStream_t stream)
{
  (void)in_sizes; (void)n_in; (void)out_size;
  const float* x_cwt        = (const float*)d_in[0];
  const float* x_features   = (const float*)d_in[1];
  const float* patch_conv_w = (const float*)d_in[2];
  const float* patch_conv_b = (const float*)d_in[3];
  const float* patch_proj_w = (const float*)d_in[4];
  const float* patch_proj_b = (const float*)d_in[5];
  const float* feat_proj_w  = (const float*)d_in[6];
  const float* feat_proj_b  = (const float*)d_in[7];
  const float* ln_w         = (const float*)d_in[8];
  const float* ln_b         = (const float*)d_in[9];
  const float* focus        = (const float*)d_in[10];
  const float* reg_w1       = (const float*)d_in[11];
  const float* reg_b1       = (const float*)d_in[12];
  const float* reg_w2       = (const float*)d_in[13];
  const float* reg_b2       = (const float*)d_in[14];
  const float* m1w[9]; for (int i=0;i<9;i++) m1w[i] = (const float*)d_in[15+i];
  const float* m2w[9]; for (int i=0;i<9;i++) m2w[i] = (const float*)d_in[24+i];

  // ---- arena (floats) ----
  float* p = (float*)d_ws;
  size_t need = 0;
  auto alloc = [&](size_t n){ float* r = p; p += n; need += n; return r; };
  float* cat    = alloc(786432);    // front: cat | m2 loop: Hend
  float* m1x    = alloc(1572864);
  float* m2x    = alloc(1572864);   // m1 loop: xp split-K partials (1.31M) — written by prep_m2 later
  float* x3     = alloc(24576);     // m2 loop: sde | end: x3
  float* bxz    = alloc(6291456);
  float* bxc    = alloc(3145728);
  float* bdbl   = alloc(1671168);
  float* bdelta = alloc(3145728);
  float* by     = alloc(3145728);
  if (ws_size < need * sizeof(float)) return;

  // front-end overlays (inside bxz; bdelta holds feat split-K partials)
  float* xp_buf    = bxz;             // 65,536
  float* x_patched = bxz + 65536;     // 262,144
  float* x_projb   = bxz + 327680;    // 262,144
  float* pc_part   = bxz + 589824;    // 262,144
  short* A3f = (short*)bxc;                    // 1024x3072 sh
  short* W3f = (short*)(bxc + 1600000);        // 128x3072 sh
  short* A3p = (short*)(bxc + 1900000);        // 1024x192 sh
  short* W3p = (short*)(bxc + 2100000);        // 256x192 sh
  float* featpart = bdelta;                    // 8 x 1024x128 = 1,048,576 fl
  // m1 overlays (liveness traced)
  short* A3i  = (short*)bxc;                   // 2048x2304 sh = 2.36M fl
  short* W3i  = (short*)bdelta;                // 3072x2304 sh = 3.54M fl (spills into by head — dead)
  short* A3x  = (short*)bdelta;                // 2048x4608 sh = 4.72M fl (bdelta + by[0..1.57M])
  short* W3x  = (short*)(by + 1600000);        // 128x4608 sh = 0.29M fl
  float* xppart = m2x;                         // 8 x 2048x80 = 1,310,720 fl (m2x dead in m1 loop)
  short* A3o  = (short*)bxz;                   // 2048x4608 sh (xz/z dead after scan)
  short* W3o  = (short*)bxc;                   // 768x4608 sh (xc dead after scan)
  float* outpart = bdelta;                     // 4 x 2048x768 = 6,291,456 fl = bdelta+by exactly
  // m2 scan overlays
  float* sHend = cat;
  unsigned short* sSde = (unsigned short*)x3;

  // ---- front-end ----
  patch_mfma_k<<<128, 256, 0, stream>>>(x_cwt, patch_conv_w, pc_part);
  reduce_patch_k<<<256, 256, 0, stream>>>(pc_part, patch_conv_b, xp_buf);
  cvt3t_k<64,192,1><<<192, 256, 0, stream>>>(xp_buf, 64, A3p, 1024, 49152);
  cvt3t_k<64,192,0><<<48, 256, 0, stream>>>(patch_proj_w, 64, W3p, 256, 12288);
  gemm3b_k<0,0,1><<<dim3(8,2), 256, 0, stream>>>(A3p, W3p, patch_proj_b, nullptr,
                                                 x_patched, 256, 256, 1024, 256, 192);
  cvt3t_k<1024,3072,1><<<3072, 256, 0, stream>>>(x_features + 256, 1280, A3f, 1024, 786432);
  cvt3t_k<1024,3072,0><<<384, 256, 0, stream>>>(feat_proj_w, 1024, W3f, 128, 98304);
  gemm3bz_k<<<dim3(8,1,8), 256, 0, stream>>>(A3f, W3f, featpart, 128, 128, 1024, 3072, 384);
  reduce_feat_k<<<512, 256, 0, stream>>>(featpart, feat_proj_b, x_projb);
  fuse_ln_k<<<1024, 256, 0, stream>>>(x_patched, x_projb, x_features, ln_w, ln_b, focus, cat);
  prep_m1_k<<<6144, 256, 0, stream>>>(cat, m1x);

  // ---- m1: 2 layers on batched (64,32,768); di=1536, dr=48 ----
  for (int im = 0; im < 2; ++im) {
    const float* in_w   = m1w[0] + (size_t)im*3072*768;
    const float* conv_w = m1w[1] + (size_t)im*1536*4;
    const float* conv_b = m1w[2] + (size_t)im*1536;
    const float* xp_w   = m1w[3] + (size_t)im*80*1536;
    const float* dt_w   = m1w[4] + (size_t)im*1536*48;
    const float* dt_b   = m1w[5] + (size_t)im*1536;
    const float* A_log  = m1w[6] + (size_t)im*1536*16;
    const float* Dp     = m1w[7] + (size_t)im*1536;
    const float* out_w  = m1w[8] + (size_t)im*768*1536;
    // in-proj
    cvt3t_k<768,2304,1><<<4608, 256, 0, stream>>>(m1x, 768, A3i, 2048, 1179648);
    cvt3t_k<768,2304,0><<<6912, 256, 0, stream>>>(in_w, 768, W3i, 3072, 1769472);
    gemm3b_k<0,0,0><<<dim3(16,24), 256, 0, stream>>>(A3i, W3i, nullptr, nullptr,
                                                     bxz, 3072, 3072, 2048, 3072, 2304);
    dwconv_silu_k<<<12288, 256, 0, stream>>>(bxz, 3072, conv_w, conv_b, bxc, 1536, 32, 2048*1536);
    // xp: split-K x8 -> partials in m2x -> reduce into bdbl
    cvt3t_k<1536,4608,1><<<9216, 256, 0, stream>>>(bxc, 1536, A3x, 2048, 2359296);
    cvt3t_k<1536,4608,0><<<576, 256, 0, stream>>>(xp_w, 1536, W3x, 80, 147456);
    gemm3bz_k<<<dim3(16,1,8), 256, 0, stream>>>(A3x, W3x, xppart, 80, 80, 2048, 4608, 576);
    reduce_xp_k<<<640, 256, 0, stream>>>(xppart, bdbl);
    // delta: streaming K=48 (overwrites A3x head — dead)
    dt1_k<<<dim3(256,6), 256, 0, stream>>>(bdbl, dt_w, dt_b, bdelta);
    scan_k<<<384, 256, 0, stream>>>(bdelta, bxc, bdbl, 80, 48, bxz + 1536, 3072,
                                    A_log, Dp, by, 1536, 32, 98304);
    // out-proj: split-K x4 -> partials bdelta+by -> reduce (+residual) into m1x
    cvt3t_k<1536,4608,1><<<9216, 256, 0, stream>>>(by, 1536, A3o, 2048, 2359296);
    cvt3t_k<1536,4608,0><<<3456, 256, 0, stream>>>(out_w, 1536, W3o, 768, 884736);
    gemm3bz_k<<<dim3(16,6,4), 256, 0, stream>>>(A3o, W3o, outpart, 768, 768, 2048, 4608, 1152);
    reduce_out_k<<<6144, 256, 0, stream>>>(outpart, m1x);
  }

  // ---- m2 prep (cat still alive; becomes Hend afterwards) ----
  prep_m2_k<<<6144, 256, 0, stream>>>(cat, m2x);

  // ---- m2: 2 layers on batched (64,768,32); di=64, dr=2 ----
  for (int im = 0; im < 2; ++im) {
    const float* in_w   = m2w[0] + (size_t)im*128*32;
    const float* conv_w = m2w[1] + (size_t)im*64*4;
    const float* conv_b = m2w[2] + (size_t)im*64;
    const float* xp_w   = m2w[3] + (size_t)im*34*64;
    const float* dt_w   = m2w[4] + (size_t)im*64*2;
    const float* dt_b   = m2w[5] + (size_t)im*64;
    const float* A_log  = m2w[6] + (size_t)im*64*16;
    const float* Dp     = m2w[7] + (size_t)im*64;
    const float* out_w  = m2w[8] + (size_t)im*32*64;
    gemm_k<0,0><<<dim3(768,2), 256, 0, stream>>>(m2x, 32, in_w, nullptr, nullptr,
                                                 bxz, 128, 49152, 128, 32);
    dwconv_silu_k<<<12288, 256, 0, stream>>>(bxz, 128, conv_w, conv_b, bxc, 64, 768, 49152*64);
    gemm_k<0,0><<<dim3(768,1), 256, 0, stream>>>(bxc, 64, xp_w, nullptr, nullptr,
                                                 bdbl, 34, 49152, 34, 64);
    dt2_k<<<12288, 256, 0, stream>>>(bdbl, dt_w, dt_b, bdelta);
    scan2_partA<<<192, 256, 0, stream>>>(bdelta, bxc, bdbl, A_log, sHend, sSde);
    scan2_carry<<<16, 256, 0, stream>>>(A_log, sHend, sSde);
    scan2_partC<<<192, 256, 0, stream>>>(bdelta, bxc, bdbl, bxz + 64, A_log, Dp, sHend, by);
    gemm_k<0,1><<<dim3(768,1), 256, 0, stream>>>(by, 64, out_w, nullptr, m2x,
                                                 m2x, 32, 49152, 32, 64);
  }

  // ---- head ----
  x3_k<<<32, 256, 0, stream>>>(m1x, m2x, x3);
  head_k<<<32, 512, 0, stream>>>(x3, reg_w1, reg_b1, reg_w2, reg_b2, (float*)d_out);
}

// Round 7
// 1016.402 us; speedup vs baseline: 2.4836x; 1.0050x over previous
//
#include <hip/hip_runtime.h>
#include <math.h>

#define DEV __device__ __forceinline__

DEV float sigmoid_(float x){ return 1.f/(1.f+__expf(-x)); }
DEV float silu_(float x){ return x * sigmoid_(x); }
DEV float softplus_(float x){ return (x > 20.f) ? x : log1pf(__expf(x)); }
DEV float gelu_(float x){ return 0.5f*x*(1.f + erff(x*0.70710678118654752440f)); }

typedef __attribute__((ext_vector_type(8))) short short8v;
typedef __attribute__((ext_vector_type(4))) short short4v;
typedef __attribute__((ext_vector_type(4))) float floatx4;

DEV short bf_split(float x, bool want_lo){
  unsigned u = __float_as_uint(x);
  unsigned hb = (u + 0x7FFFu + ((u >> 16) & 1u)) >> 16;
  if (!want_lo) return (short)hb;
  float lo = x - __uint_as_float(hb << 16);
  unsigned ul = __float_as_uint(lo);
  return (short)((ul + 0x7FFFu + ((ul >> 16) & 1u)) >> 16);
}

// ---------------- fp32 GEMM (m2's K<=64 streaming shapes) ----------------
template<int ACT, int RES>
__global__ __launch_bounds__(256)
void gemm_k(const float* __restrict__ A, int lda,
            const float* __restrict__ W,
            const float* __restrict__ bias,
            const float* __restrict__ Rres,
            float* __restrict__ C, int ldc,
            int M, int N, int K)
{
  __shared__ float As[16][68];
  __shared__ float Ws[16][68];
  const int bm = blockIdx.x << 6;
  const int bn = blockIdx.y << 6;
  const int tid = threadIdx.x;
  const int tm0 = (tid >> 4) << 2;
  const int tn0 = (tid & 15) << 2;
  const int r   = tid >> 2;
  const int kk4 = (tid & 3) << 2;
  float acc[4][4] = {};
  for (int k0 = 0; k0 < K; k0 += 16) {
    const int gk = k0 + kk4;
    float4 va = make_float4(0.f,0.f,0.f,0.f);
    const int gr = bm + r;
    if (gr < M && gk < K) va = *(const float4*)(A + (size_t)gr*lda + gk);
    As[kk4+0][r]=va.x; As[kk4+1][r]=va.y; As[kk4+2][r]=va.z; As[kk4+3][r]=va.w;
    float4 vw = make_float4(0.f,0.f,0.f,0.f);
    const int gc = bn + r;
    if (gc < N && gk < K) vw = *(const float4*)(W + (size_t)gc*K + gk);
    Ws[kk4+0][r]=vw.x; Ws[kk4+1][r]=vw.y; Ws[kk4+2][r]=vw.z; Ws[kk4+3][r]=vw.w;
    __syncthreads();
    #pragma unroll
    for (int kk = 0; kk < 16; ++kk) {
      const float a0=As[kk][tm0+0], a1=As[kk][tm0+1], a2=As[kk][tm0+2], a3=As[kk][tm0+3];
      const float w0=Ws[kk][tn0+0], w1=Ws[kk][tn0+1], w2=Ws[kk][tn0+2], w3=Ws[kk][tn0+3];
      acc[0][0]+=a0*w0; acc[0][1]+=a0*w1; acc[0][2]+=a0*w2; acc[0][3]+=a0*w3;
      acc[1][0]+=a1*w0; acc[1][1]+=a1*w1; acc[1][2]+=a1*w2; acc[1][3]+=a1*w3;
      acc[2][0]+=a2*w0; acc[2][1]+=a2*w1; acc[2][2]+=a2*w2; acc[2][3]+=a2*w3;
      acc[3][0]+=a3*w0; acc[3][1]+=a3*w1; acc[3][2]+=a3*w2; acc[3][3]+=a3*w3;
    }
    __syncthreads();
  }
  #pragma unroll
  for (int i=0;i<4;i++){
    const int row = bm + tm0 + i;
    if (row >= M) continue;
    #pragma unroll
    for (int j=0;j<4;j++){
      const int col = bn + tn0 + j;
      if (col >= N) continue;
      float v = acc[i][j];
      if (bias) v += bias[col];
      if (RES)  v += Rres[(size_t)row*ldc + col];
      if (ACT == 1) v = softplus_(v);
      C[(size_t)row*ldc + col] = v;
    }
  }
}

// ---------------- vectorized split conversion ----------------
// MODE 0: [hi|lo|hi] (W triple), 1: [hi|hi|lo] (A triple), 2: [hi|lo] (duo)
template<int C, int KP, int MODE>
__global__ void cvt3t_k(const float* __restrict__ X, int ldx, short* __restrict__ Y,
                        int realR, int total4)
{
  const int i4 = blockIdx.x*256 + threadIdx.x;
  if (i4 >= total4) return;
  const int idx = i4 << 2;
  const int c3 = idx % KP;
  const int r  = idx / KP;
  short4v out = {0,0,0,0};
  const int nparts = (MODE == 2) ? 2 : 3;
  if (r < realR && c3 < nparts*C) {
    const int part = c3 / C;
    const int c = c3 - part*C;
    const bool lo = (MODE == 1) ? (part == 2) : (part == 1);
    const float4 v = *(const float4*)(X + (size_t)r*ldx + c);
    out.x = bf_split(v.x, lo); out.y = bf_split(v.y, lo);
    out.z = bf_split(v.z, lo); out.w = bf_split(v.w, lo);
  }
  *(short4v*)(Y + (size_t)r*KP + c3) = out;
}

// ---------------- bf16 MFMA GEMM (pipelined): C = act(A3 @ W3^T + bias [+ R]) ----------------
template<int ACT, int RES, int BIAS>
__global__ __launch_bounds__(256)
void gemm3b_k(const short* __restrict__ A3, const short* __restrict__ W3,
              const float* __restrict__ bias, const float* __restrict__ Rres,
              float* __restrict__ C, int ldc, int NOUT, int M, int N, int K3)
{
  __shared__ short As[128][40];
  __shared__ short Ws[128][40];
  const int bm = blockIdx.x << 7;
  const int bn = blockIdx.y << 7;
  const int tid = threadIdx.x;
  const int lane = tid & 63;
  const int wv = tid >> 6;
  const int wr = (wv >> 1) << 6;
  const int wc = (wv & 1) << 6;
  const int frow = lane & 15;
  const int fk   = lane >> 4;
  const int srow = tid >> 1;
  const int shalf = (tid & 1) << 4;

  floatx4 acc[4][4] = {};
  const short* gA = A3 + (size_t)(bm + srow)*K3 + shalf;
  const short* gW = W3 + (size_t)(bn + srow)*K3 + shalf;

  short8v va0 = *(const short8v*)(gA);
  short8v va1 = *(const short8v*)(gA + 8);
  short8v vw0 = *(const short8v*)(gW);
  short8v vw1 = *(const short8v*)(gW + 8);

  for (int k0 = 0; k0 < K3; k0 += 32) {
    __syncthreads();
    *(short8v*)&As[srow][shalf]     = va0;
    *(short8v*)&As[srow][shalf + 8] = va1;
    *(short8v*)&Ws[srow][shalf]     = vw0;
    *(short8v*)&Ws[srow][shalf + 8] = vw1;
    __syncthreads();
    const int kn = k0 + 32;
    if (kn < K3) {
      va0 = *(const short8v*)(gA + kn);
      va1 = *(const short8v*)(gA + kn + 8);
      vw0 = *(const short8v*)(gW + kn);
      vw1 = *(const short8v*)(gW + kn + 8);
    }
    short8v af[4], bfv[4];
    #pragma unroll
    for (int mf = 0; mf < 4; ++mf)
      af[mf] = *(const short8v*)&As[wr + mf*16 + frow][fk*8];
    #pragma unroll
    for (int nf = 0; nf < 4; ++nf)
      bfv[nf] = *(const short8v*)&Ws[wc + nf*16 + frow][fk*8];
    #pragma unroll
    for (int mf = 0; mf < 4; ++mf)
      #pragma unroll
      for (int nf = 0; nf < 4; ++nf)
        acc[mf][nf] = __builtin_amdgcn_mfma_f32_16x16x32_bf16(af[mf], bfv[nf], acc[mf][nf], 0, 0, 0);
  }

  #pragma unroll
  for (int mf = 0; mf < 4; ++mf) {
    #pragma unroll
    for (int nf = 0; nf < 4; ++nf) {
      const int col = bn + wc + nf*16 + (lane & 15);
      if (col >= NOUT) continue;
      #pragma unroll
      for (int r = 0; r < 4; ++r) {
        const int row = bm + wr + mf*16 + (lane >> 4)*4 + r;
        float v = acc[mf][nf][r];
        if (BIAS) v += bias[col];
        if (RES)  v += Rres[(size_t)row*ldc + col];
        if (ACT == 1) v = softplus_(v);
        C[(size_t)row*ldc + col] = v;
      }
    }
  }
}

// ---------------- split-K partial-plane GEMM ----------------
__global__ __launch_bounds__(256)
void gemm3bz_k(const short* __restrict__ A3, const short* __restrict__ W3,
               float* __restrict__ C, int ldc, int NOUT, int M, int K3, int KC)
{
  __shared__ short As[128][40];
  __shared__ short Ws[128][40];
  const int bm = blockIdx.x << 7;
  const int bn = blockIdx.y << 7;
  const int kbeg = blockIdx.z * KC;
  float* Cpart = C + (size_t)blockIdx.z * M * ldc;
  const int tid = threadIdx.x;
  const int lane = tid & 63;
  const int wv = tid >> 6;
  const int wr = (wv >> 1) << 6;
  const int wc = (wv & 1) << 6;
  const int frow = lane & 15;
  const int fk   = lane >> 4;
  const int srow = tid >> 1;
  const int shalf = (tid & 1) << 4;

  floatx4 acc[4][4] = {};
  const short* gA = A3 + (size_t)(bm + srow)*K3 + shalf + kbeg;
  const short* gW = W3 + (size_t)(bn + srow)*K3 + shalf + kbeg;

  short8v va0 = *(const short8v*)(gA);
  short8v va1 = *(const short8v*)(gA + 8);
  short8v vw0 = *(const short8v*)(gW);
  short8v vw1 = *(const short8v*)(gW + 8);

  for (int k0 = 0; k0 < KC; k0 += 32) {
    __syncthreads();
    *(short8v*)&As[srow][shalf]     = va0;
    *(short8v*)&As[srow][shalf + 8] = va1;
    *(short8v*)&Ws[srow][shalf]     = vw0;
    *(short8v*)&Ws[srow][shalf + 8] = vw1;
    __syncthreads();
    const int kn = k0 + 32;
    if (kn < KC) {
      va0 = *(const short8v*)(gA + kn);
      va1 = *(const short8v*)(gA + kn + 8);
      vw0 = *(const short8v*)(gW + kn);
      vw1 = *(const short8v*)(gW + kn + 8);
    }
    short8v af[4], bfv[4];
    #pragma unroll
    for (int mf = 0; mf < 4; ++mf)
      af[mf] = *(const short8v*)&As[wr + mf*16 + frow][fk*8];
    #pragma unroll
    for (int nf = 0; nf < 4; ++nf)
      bfv[nf] = *(const short8v*)&Ws[wc + nf*16 + frow][fk*8];
    #pragma unroll
    for (int mf = 0; mf < 4; ++mf)
      #pragma unroll
      for (int nf = 0; nf < 4; ++nf)
        acc[mf][nf] = __builtin_amdgcn_mfma_f32_16x16x32_bf16(af[mf], bfv[nf], acc[mf][nf], 0, 0, 0);
  }

  #pragma unroll
  for (int mf = 0; mf < 4; ++mf) {
    #pragma unroll
    for (int nf = 0; nf < 4; ++nf) {
      const int col = bn + wc + nf*16 + (lane & 15);
      if (col >= NOUT) continue;
      #pragma unroll
      for (int r = 0; r < 4; ++r) {
        const int row = bm + wr + mf*16 + (lane >> 4)*4 + r;
        Cpart[(size_t)row*ldc + col] = acc[mf][nf][r];
      }
    }
  }
}

// ---------------- duo-split 3-product GEMM: A,W stored [hi|lo] (row stride 2K) ----------------
// z=0: Ahi*Whi, z=1: Ahi*Wlo, z=2: Alo*Whi -> partial planes
__global__ __launch_bounds__(256)
void gemm3bz2_k(const short* __restrict__ A2, const short* __restrict__ W2,
                float* __restrict__ C, int ldc, int NOUT, int M, int K)
{
  __shared__ short As[128][40];
  __shared__ short Ws[128][40];
  const int bm = blockIdx.x << 7;
  const int bn = blockIdx.y << 7;
  const int z = blockIdx.z;
  const int kA = (z == 2) ? K : 0;
  const int kW = (z == 1) ? K : 0;
  float* Cpart = C + (size_t)z * M * ldc;
  const int tid = threadIdx.x;
  const int lane = tid & 63;
  const int wv = tid >> 6;
  const int wr = (wv >> 1) << 6;
  const int wc = (wv & 1) << 6;
  const int frow = lane & 15;
  const int fk   = lane >> 4;
  const int srow = tid >> 1;
  const int shalf = (tid & 1) << 4;

  floatx4 acc[4][4] = {};
  const short* gA = A2 + (size_t)(bm + srow)*(2*K) + shalf + kA;
  const short* gW = W2 + (size_t)(bn + srow)*(2*K) + shalf + kW;

  short8v va0 = *(const short8v*)(gA);
  short8v va1 = *(const short8v*)(gA + 8);
  short8v vw0 = *(const short8v*)(gW);
  short8v vw1 = *(const short8v*)(gW + 8);

  for (int k0 = 0; k0 < K; k0 += 32) {
    __syncthreads();
    *(short8v*)&As[srow][shalf]     = va0;
    *(short8v*)&As[srow][shalf + 8] = va1;
    *(short8v*)&Ws[srow][shalf]     = vw0;
    *(short8v*)&Ws[srow][shalf + 8] = vw1;
    __syncthreads();
    const int kn = k0 + 32;
    if (kn < K) {
      va0 = *(const short8v*)(gA + kn);
      va1 = *(const short8v*)(gA + kn + 8);
      vw0 = *(const short8v*)(gW + kn);
      vw1 = *(const short8v*)(gW + kn + 8);
    }
    short8v af[4], bfv[4];
    #pragma unroll
    for (int mf = 0; mf < 4; ++mf)
      af[mf] = *(const short8v*)&As[wr + mf*16 + frow][fk*8];
    #pragma unroll
    for (int nf = 0; nf < 4; ++nf)
      bfv[nf] = *(const short8v*)&Ws[wc + nf*16 + frow][fk*8];
    #pragma unroll
    for (int mf = 0; mf < 4; ++mf)
      #pragma unroll
      for (int nf = 0; nf < 4; ++nf)
        acc[mf][nf] = __builtin_amdgcn_mfma_f32_16x16x32_bf16(af[mf], bfv[nf], acc[mf][nf], 0, 0, 0);
  }

  #pragma unroll
  for (int mf = 0; mf < 4; ++mf) {
    #pragma unroll
    for (int nf = 0; nf < 4; ++nf) {
      const int col = bn + wc + nf*16 + (lane & 15);
      if (col >= NOUT) continue;
      #pragma unroll
      for (int r = 0; r < 4; ++r) {
        const int row = bm + wr + mf*16 + (lane >> 4)*4 + r;
        Cpart[(size_t)row*ldc + col] = acc[mf][nf][r];
      }
    }
  }
}

// ---------------- split-K reduce kernels ----------------
__global__ void reduce_xp_k(const float* __restrict__ part, float* __restrict__ out)
{
  const int i = blockIdx.x*256 + threadIdx.x;   // 2048*80
  if (i >= 163840) return;
  float s = 0.f;
  #pragma unroll
  for (int z = 0; z < 8; ++z) s += part[(size_t)z*163840 + i];
  out[i] = s;
}
__global__ void reduce_feat_k(const float* __restrict__ part, const float* __restrict__ bias,
                              float* __restrict__ out)
{
  const int i = blockIdx.x*256 + threadIdx.x;   // 1024*128
  if (i >= 131072) return;
  const int r = i >> 7, c = i & 127;
  float s = bias[c];
  #pragma unroll
  for (int z = 0; z < 8; ++z) s += part[(size_t)z*131072 + i];
  out[(size_t)r*256 + 128 + c] = s;
}
__global__ void reduce_out_k(const float* __restrict__ part, float* __restrict__ m1x)
{
  const int i = blockIdx.x*256 + threadIdx.x;   // 2048*768
  if (i >= 1572864) return;
  float s = m1x[i];
  #pragma unroll
  for (int z = 0; z < 3; ++z) s += part[(size_t)z*1572864 + i];
  m1x[i] = s;
}

// ---------------- m1 delta projection: streaming K=48 ----------------
__global__ __launch_bounds__(256)
void dt1_k(const float* __restrict__ dbl, const float* __restrict__ dt_w,
           const float* __restrict__ dt_b, float* __restrict__ delta)
{
  const int d = blockIdx.y*256 + threadIdx.x;
  const int r0 = blockIdx.x*8;
  float w[48];
  #pragma unroll
  for (int q = 0; q < 12; ++q)
    *(float4*)&w[q*4] = *(const float4*)(dt_w + (size_t)d*48 + q*4);
  __shared__ float sdbl[8][48];
  if (threadIdx.x < 96) {
    const int rr = threadIdx.x / 12, q = threadIdx.x % 12;
    *(float4*)&sdbl[rr][q*4] = *(const float4*)(dbl + (size_t)(r0+rr)*80 + q*4);
  }
  __syncthreads();
  const float bv = dt_b[d];
  #pragma unroll
  for (int rr = 0; rr < 8; ++rr) {
    float acc = bv;
    #pragma unroll
    for (int k = 0; k < 48; ++k) acc += sdbl[rr][k]*w[k];
    delta[(size_t)(r0+rr)*1536 + d] = softplus_(acc);
  }
}

// ---------------- patch conv im2col (one 16-channel half) -> triple-split bf16 ----------------
// A3[row = b*64+patch][K3=12288], k = c*256 + (h&15)*16 + (w&15), layout [hi|hi|lo]
__global__ void im2col3_k(const float* __restrict__ x, int c0, short* __restrict__ A3)
{
  const int t = blockIdx.x*256 + threadIdx.x;   // 2,097,152 float4s
  if (t >= 2097152) return;
  const int b = t >> 16;
  const int r = t & 65535;
  const int c = r >> 12;
  const int f = r & 4095;
  const float4 v = *(const float4*)(x + (((size_t)b*32 + c0 + c) << 14) + (f << 2));
  const int o4 = f << 2;
  const int h = o4 >> 7, w = o4 & 127;
  const int patch = ((h >> 4) << 3) + (w >> 4);
  const int pos = ((h & 15) << 4) + (w & 15);
  const int row = (b << 6) + patch;
  const int k = (c << 8) + pos;
  short4v hv, lv;
  hv.x = bf_split(v.x,false); lv.x = bf_split(v.x,true);
  hv.y = bf_split(v.y,false); lv.y = bf_split(v.y,true);
  hv.z = bf_split(v.z,false); lv.z = bf_split(v.z,true);
  hv.w = bf_split(v.w,false); lv.w = bf_split(v.w,true);
  short* base = A3 + (size_t)row*12288 + k;
  *(short4v*)(base)        = hv;
  *(short4v*)(base + 4096) = hv;
  *(short4v*)(base + 8192) = lv;
}

// reduce 16 partial planes + bias -> A3p (patch_proj A operand, [hi|hi|lo], K=64->192)
__global__ void reduce_patch16_k(const float* __restrict__ part, const float* __restrict__ bias,
                                 short* __restrict__ A3p)
{
  const int idx = blockIdx.x*256 + threadIdx.x;   // 65536 = (b*32+o)*64+patch
  if (idx >= 65536) return;
  const int patch = idx & 63;
  const int o = (idx >> 6) & 31;
  const int b = idx >> 11;
  const int row = (b << 6) + patch;
  float s = bias[o];
  #pragma unroll
  for (int z = 0; z < 16; ++z) s += part[(size_t)z*65536 + row*32 + o];
  const short hi = bf_split(s,false), lo = bf_split(s,true);
  short* p = A3p + (size_t)((b << 5) + o)*192 + patch;
  p[0] = hi; p[64] = hi; p[128] = lo;
}

// ---------------- fused: x_proj assemble + gelu fuse + concat + layernorm ----------------
__global__ __launch_bounds__(256)
void fuse_ln_k(const float* __restrict__ xpat, const float* __restrict__ xprojbuf,
               const float* __restrict__ xfeat, const float* __restrict__ lnw,
               const float* __restrict__ lnb, const float* __restrict__ focusp,
               float* __restrict__ cat)
{
  const int row = blockIdx.x;
  const int t = threadIdx.x;
  const float focus = focusp[0];
  const float xp = xpat[(size_t)row*256 + t];
  const float pr = (t < 128) ? xfeat[(size_t)row*1280 + t] : xprojbuf[(size_t)row*256 + t];
  const float xf = gelu_(focus*pr + (2.f - focus)*xp);
  float s  = xp + xf + pr;
  float sq = xp*xp + xf*xf + pr*pr;
  __shared__ float rs[4], rq[4];
  const int lane = t & 63, wv = t >> 6;
  #pragma unroll
  for (int off = 32; off > 0; off >>= 1) {
    s  += __shfl_down(s,  off, 64);
    sq += __shfl_down(sq, off, 64);
  }
  if (lane == 0) { rs[wv] = s; rq[wv] = sq; }
  __syncthreads();
  const float S = rs[0]+rs[1]+rs[2]+rs[3];
  const float Q = rq[0]+rq[1]+rq[2]+rq[3];
  const float mu = S * (1.f/768.f);
  const float var = Q*(1.f/768.f) - mu*mu;
  const float rstd = rsqrtf(var + 1e-5f);
  const size_t ob = (size_t)row*768;
  cat[ob +        t] = (xp - mu)*rstd*lnw[      t] + lnb[      t];
  cat[ob + 256 +  t] = (xf - mu)*rstd*lnw[256 + t] + lnb[256 + t];
  cat[ob + 512 +  t] = (pr - mu)*rstd*lnw[512 + t] + lnb[512 + t];
}

// ---------------- prep: duplicate + flip ----------------
__global__ void prep_m1_k(const float* __restrict__ cat, float* __restrict__ X)
{
  const int idx = blockIdx.x*256 + threadIdx.x;
  if (idx >= 64*32*768) return;
  const int d = idx % 768;
  const int sl = idx / 768;
  const int l = sl & 31;
  const int s = sl >> 5;
  const int b = s & 31;
  const int ll = (s < 32) ? l : 31 - l;
  X[idx] = cat[((size_t)b*32 + ll)*768 + d];
}
__global__ void prep_m2_k(const float* __restrict__ cat, float* __restrict__ X)
{
  const int idx = blockIdx.x*256 + threadIdx.x;
  if (idx >= 64*768*32) return;
  const int c = idx & 31;
  const int sj = idx >> 5;
  const int j = sj % 768;
  const int s = sj / 768;
  const int b = (s < 32) ? s : s - 32;
  const int jj = (s < 32) ? j : 767 - j;
  X[idx] = cat[((size_t)b*32 + c)*768 + jj];
}

// ---------------- m2 depthwise causal conv (k=4) + silu ----------------
__global__ void dwconv_silu_k(const float* __restrict__ xz, int ldxz,
                              const float* __restrict__ w, const float* __restrict__ b,
                              float* __restrict__ xc, int di, int L, int total)
{
  const int idx = blockIdx.x*256 + threadIdx.x;
  if (idx >= total) return;
  const int d = idx % di;
  const int sl = idx / di;
  const int l = sl % L;
  float acc = b[d];
  const float* wd = w + d*4;
  #pragma unroll
  for (int k = 0; k < 4; ++k) {
    const int ll = l - 3 + k;
    if (ll >= 0) acc += xz[(size_t)(sl - 3 + k)*ldxz + d] * wd[k];
  }
  xc[idx] = silu_(acc);
}

// ---------------- m1 dwconv + silu, fused with A3x triple-split emit ----------------
__global__ void dwconv3_m1_k(const float* __restrict__ xz,
                             const float* __restrict__ w, const float* __restrict__ b,
                             float* __restrict__ xc, short* __restrict__ A3x)
{
  const int idx = blockIdx.x*256 + threadIdx.x;   // 2048*1536
  if (idx >= 3145728) return;
  const int d = idx % 1536;
  const int sl = idx / 1536;
  const int l = sl & 31;
  float acc = b[d];
  const float* wd = w + d*4;
  #pragma unroll
  for (int k = 0; k < 4; ++k) {
    const int ll = l - 3 + k;
    if (ll >= 0) acc += xz[(size_t)(sl - 3 + k)*3072 + d] * wd[k];
  }
  const float v = silu_(acc);
  xc[idx] = v;
  const short hi = bf_split(v,false), lo = bf_split(v,true);
  short* p = A3x + (size_t)sl*4608 + d;
  p[0] = hi; p[1536] = hi; p[3072] = lo;
}

// ---------------- m2 dt projection (K=2) + softplus ----------------
__global__ void dt2_k(const float* __restrict__ dbl, const float* __restrict__ dt_w,
                      const float* __restrict__ dt_b, float* __restrict__ delta)
{
  const int idx = blockIdx.x*256 + threadIdx.x;
  if (idx >= 49152*64) return;
  const int d = idx & 63;
  const int r = idx >> 6;
  const float a0 = dbl[(size_t)r*34 + 0], a1 = dbl[(size_t)r*34 + 1];
  delta[idx] = softplus_(a0*dt_w[d*2] + a1*dt_w[d*2+1] + dt_b[d]);
}

// ---------------- m1 selective scan (L=32), fused with A3o duo-split emit ----------------
__global__ void scan3_m1_k(const float* __restrict__ delta, const float* __restrict__ xc,
                           const float* __restrict__ dbl, const float* __restrict__ z,
                           const float* __restrict__ A_log, const float* __restrict__ Dp,
                           short* __restrict__ A3o)
{
  const int idx = blockIdx.x*256 + threadIdx.x;   // 98304 = 64seq*1536d
  if (idx >= 98304) return;
  const int d = idx % 1536;
  const int s = idx / 1536;
  float A[16], h[16];
  #pragma unroll
  for (int n = 0; n < 16; ++n) { A[n] = -__expf(A_log[d*16 + n]); h[n] = 0.f; }
  const float Dv = Dp[d];
  for (int l = 0; l < 32; ++l) {
    const size_t row = (size_t)s*32 + l;
    const float de  = delta[row*1536 + d];
    const float xcv = xc[row*1536 + d];
    const float du  = de * xcv;
    const float* bl = dbl + row*80 + 48;
    float y = 0.f;
    #pragma unroll
    for (int n = 0; n < 16; ++n) {
      const float dA = __expf(de * A[n]);
      h[n] = dA*h[n] + du*bl[n];
      y += h[n]*bl[16 + n];
    }
    const float zv = z[row*3072 + d];
    const float out = (y + xcv*Dv) * silu_(zv);
    short* p = A3o + row*3072 + d;
    p[0] = bf_split(out,false);
    p[1536] = bf_split(out,true);
  }
}

// ---------------- m2 chunked scan: 12 chunks of 64 ----------------
#define NC2 12
#define LC2 64

__global__ __launch_bounds__(256)
void scan2_partA(const float* __restrict__ delta, const float* __restrict__ xc,
                 const float* __restrict__ dbl, const float* __restrict__ A_log,
                 float* __restrict__ Hend, unsigned short* __restrict__ sde_buf)
{
  const int t = blockIdx.x*256 + threadIdx.x;
  if (t >= 64*64*NC2) return;
  const int d = t & 63;
  const int c = (t >> 6) % NC2;
  const int s = t / (64*NC2);
  float A[16], h[16];
  #pragma unroll
  for (int n = 0; n < 16; ++n) { A[n] = -__expf(A_log[d*16 + n]); h[n] = 0.f; }
  float sde = 0.f;
  const size_t row0 = (size_t)s*768 + c*LC2;
  for (int l = 0; l < LC2; ++l) {
    const size_t row = row0 + l;
    const float de  = delta[row*64 + d];
    const float xcv = xc[row*64 + d];
    const float du  = de * xcv;
    const float* bl = dbl + row*34 + 2;
    sde += de;
    #pragma unroll
    for (int n = 0; n < 16; ++n)
      h[n] = __expf(de*A[n])*h[n] + du*bl[n];
  }
  float* hp = Hend + (size_t)t*16;
  #pragma unroll
  for (int n = 0; n < 16; ++n) hp[n] = h[n];
  const unsigned u = __float_as_uint(sde);
  sde_buf[t] = (unsigned short)((u + 0x7FFFu + ((u >> 16) & 1u)) >> 16);
}

__global__ void scan2_carry(const float* __restrict__ A_log,
                            float* __restrict__ Hend, const unsigned short* __restrict__ sde_buf)
{
  const int t = blockIdx.x*256 + threadIdx.x;
  if (t >= 4096) return;
  const int d = t & 63;
  const int s = t >> 6;
  float A[16], H[16];
  #pragma unroll
  for (int n = 0; n < 16; ++n) { A[n] = -__expf(A_log[d*16 + n]); H[n] = 0.f; }
  for (int c = 0; c < NC2; ++c) {
    const size_t off = ((size_t)(s*NC2 + c)*64 + d)*16;
    const float sde = __uint_as_float(((unsigned)sde_buf[(s*NC2 + c)*64 + d]) << 16);
    #pragma unroll
    for (int n = 0; n < 16; ++n) {
      const float he = Hend[off + n];
      Hend[off + n] = H[n];
      H[n] = __expf(sde*A[n])*H[n] + he;
    }
  }
}

__global__ __launch_bounds__(256)
void scan2_partC(const float* __restrict__ delta, const float* __restrict__ xc,
                 const float* __restrict__ dbl, const float* __restrict__ z,
                 const float* __restrict__ A_log, const float* __restrict__ Dp,
                 const float* __restrict__ Hin, float* __restrict__ Y)
{
  const int t = blockIdx.x*256 + threadIdx.x;
  if (t >= 64*64*NC2) return;
  const int d = t & 63;
  const int c = (t >> 6) % NC2;
  const int s = t / (64*NC2);
  float A[16], h[16];
  #pragma unroll
  for (int n = 0; n < 16; ++n) {
    A[n] = -__expf(A_log[d*16 + n]);
    h[n] = Hin[(size_t)t*16 + n];
  }
  const float Dv = Dp[d];
  const size_t row0 = (size_t)s*768 + c*LC2;
  for (int l = 0; l < LC2; ++l) {
    const size_t row = row0 + l;
    const float de  = delta[row*64 + d];
    const float xcv = xc[row*64 + d];
    const float du  = de * xcv;
    const float* bl = dbl + row*34 + 2;
    float y = 0.f;
    #pragma unroll
    for (int n = 0; n < 16; ++n) {
      const float dA = __expf(de*A[n]);
      h[n] = dA*h[n] + du*bl[n];
      y += h[n]*bl[16 + n];
    }
    const float zv = z[row*128 + d];
    Y[row*64 + d] = (y + xcv*Dv) * silu_(zv);
  }
}

// ---------------- combine + mean over l ----------------
__global__ __launch_bounds__(256)
void x3_k(const float* __restrict__ x1p, const float* __restrict__ x2p, float* __restrict__ x3)
{
  const int b = blockIdx.x;
  for (int j = threadIdx.x; j < 768; j += 256) {
    float s = 0.f;
    for (int i = 0; i < 32; ++i) {
      s += x1p[((size_t)b*32 + i)*768 + j] + x1p[((size_t)(b+32)*32 + i)*768 + j];
      s += x2p[((size_t)b*768 + j)*32 + i] + x2p[((size_t)(b+32)*768 + j)*32 + i];
    }
    x3[(size_t)b*768 + j] = s * (1.f/32.f);
  }
}

// ---------------- regression head ----------------
__global__ __launch_bounds__(512)
void head_k(const float* __restrict__ x3, const float* __restrict__ w1, const float* __restrict__ b1,
            const float* __restrict__ w2, const float* __restrict__ b2, float* __restrict__ out)
{
  const int b = blockIdx.x;
  const int t = threadIdx.x;
  __shared__ float xrow[768];
  for (int i = t; i < 768; i += 512) xrow[i] = x3[(size_t)b*768 + i];
  __syncthreads();
  float hv = 0.f;
  if (t < 384) {
    const float* wr = w1 + (size_t)t*768;
    float acc = b1[t];
    for (int d = 0; d < 768; ++d) acc += xrow[d]*wr[d];
    hv = acc * w2[t];
  }
  __shared__ float red[8];
  const int lane = t & 63, wv = t >> 6;
  #pragma unroll
  for (int off = 32; off > 0; off >>= 1) hv += __shfl_down(hv, off, 64);
  if (lane == 0) red[wv] = hv;
  __syncthreads();
  if (t == 0) {
    float s = b2[0];
    #pragma unroll
    for (int i = 0; i < 8; ++i) s += red[i];
    out[b] = s;
  }
}

extern "C" void kernel_launch(void* const* d_in, const int* in_sizes, int n_in,
                              void* d_out, int out_size, void* d_ws, size_t ws_size,
                              hipStream_t stream)
{
  (void)in_sizes; (void)n_in; (void)out_size;
  const float* x_cwt        = (const float*)d_in[0];
  const float* x_features   = (const float*)d_in[1];
  const float* patch_conv_w = (const float*)d_in[2];
  const float* patch_conv_b = (const float*)d_in[3];
  const float* patch_proj_w = (const float*)d_in[4];
  const float* patch_proj_b = (const float*)d_in[5];
  const float* feat_proj_w  = (const float*)d_in[6];
  const float* feat_proj_b  = (const float*)d_in[7];
  const float* ln_w         = (const float*)d_in[8];
  const float* ln_b         = (const float*)d_in[9];
  const float* focus        = (const float*)d_in[10];
  const float* reg_w1       = (const float*)d_in[11];
  const float* reg_b1       = (const float*)d_in[12];
  const float* reg_w2       = (const float*)d_in[13];
  const float* reg_b2       = (const float*)d_in[14];
  const float* m1w[9]; for (int i=0;i<9;i++) m1w[i] = (const float*)d_in[15+i];
  const float* m2w[9]; for (int i=0;i<9;i++) m2w[i] = (const float*)d_in[24+i];

  // ---- arena (floats), 21,356,544 fl ----
  float* p = (float*)d_ws;
  size_t need = 0;
  auto alloc = [&](size_t n){ float* r = p; p += n; need += n; return r; };
  float* cat    = alloc(786432);    // front/m1: cat | m2 loop: Hend
  float* m1x    = alloc(1572864);
  float* m2x    = alloc(1572864);   // m1 loop: xp split-K partials; front: featpart
  float* x3     = alloc(24576);     // m2 loop: sde | end: x3
  float* bxz    = alloc(6291456);
  float* bxc    = alloc(3145728);
  float* bdbl   = alloc(1671168);
  float* bdelta = alloc(3145728);
  float* by     = alloc(3145728);
  if (ws_size < need * sizeof(float)) return;

  // ---- overlays (liveness traced per stage) ----
  // patch stage: A3pc spans bxz..bdelta head; W3pc/pcpart in by
  short* A3pc  = (short*)bxz;            // 2048x12288 sh = 12,582,912 fl
  short* W3pc  = (short*)by;             // 128x12288 sh = 786,432 fl... (393,216 fl used x2B)
  float* pcpart = by + 800000;           // 16 x 65536 = 1,048,576 fl
  // front smalls live in m1x (dead until prep_m1)
  float* x_patched = m1x;                // 262,144
  float* x_projb   = m1x + 262144;       // 262,144
  short* A3p = (short*)(m1x + 524288);   // 1024x192 sh = 98,304 fl
  short* W3p = (short*)(m1x + 630016);   // 256x192 sh = 24,576 fl
  // feat stage (after patch GEMMs): bxz free again
  short* A3f = (short*)bxz;              // 1024x3072 sh = 1,572,864 fl
  short* W3f = (short*)(bxz + 1600000);  // 128x3072 sh = 196,608 fl
  float* featpart = m2x;                 // 8 x 131072 = 1,048,576 fl
  // m1 loop
  short* A3i  = (short*)bxc;             // 2048x2304 sh = 2,359,296 fl
  short* W3i  = (short*)bdbl;            // 3072x2304 sh = 3,538,944 fl (bdbl+bdelta head)
  short* A3x  = (short*)bdbl;            // 2048x4608 sh = 4,718,592 fl (bdbl+bdelta span)
  short* W3x  = (short*)by;              // 128x4608 sh = 294,912 fl
  float* xppart = m2x;                   // 8 x 163840 = 1,310,720 fl
  short* A3o  = (short*)by;              // 2048x3072 sh = 3,145,728 fl = by exactly ([hi|lo])
  short* W3o  = (short*)bxc;             // 768x3072 sh = 1,179,648 fl ([hi|lo])
  float* outpart = bdbl;                 // 3 x 1,572,864 = 4,718,592 fl (bdbl+bdelta span)
  // m2 scan overlays
  float* sHend = cat;
  unsigned short* sSde = (unsigned short*)x3;

  // ---- patch conv: 2 halves of im2col + split-K MFMA ----
  im2col3_k<<<8192, 256, 0, stream>>>(x_cwt, 0, A3pc);
  cvt3t_k<4096,12288,0><<<1536, 256, 0, stream>>>(patch_conv_w, 8192, W3pc, 32, 393216);
  gemm3bz_k<<<dim3(16,1,8), 256, 0, stream>>>(A3pc, W3pc, pcpart, 32, 32, 2048, 12288, 1536);
  im2col3_k<<<8192, 256, 0, stream>>>(x_cwt, 16, A3pc);
  cvt3t_k<4096,12288,0><<<1536, 256, 0, stream>>>(patch_conv_w + 4096, 8192, W3pc, 32, 393216);
  gemm3bz_k<<<dim3(16,1,8), 256, 0, stream>>>(A3pc, W3pc, pcpart + 8*65536, 32, 32, 2048, 12288, 1536);
  reduce_patch16_k<<<256, 256, 0, stream>>>(pcpart, patch_conv_b, A3p);
  // patch_proj: (1024x64)@(256x64)^T + b
  cvt3t_k<64,192,0><<<48, 256, 0, stream>>>(patch_proj_w, 64, W3p, 256, 12288);
  gemm3b_k<0,0,1><<<dim3(8,2), 256, 0, stream>>>(A3p, W3p, patch_proj_b, nullptr,
                                                 x_patched, 256, 256, 1024, 256, 192);
  // feat_proj
  cvt3t_k<1024,3072,1><<<3072, 256, 0, stream>>>(x_features + 256, 1280, A3f, 1024, 786432);
  cvt3t_k<1024,3072,0><<<384, 256, 0, stream>>>(feat_proj_w, 1024, W3f, 128, 98304);
  gemm3bz_k<<<dim3(8,1,8), 256, 0, stream>>>(A3f, W3f, featpart, 128, 128, 1024, 3072, 384);
  reduce_feat_k<<<512, 256, 0, stream>>>(featpart, feat_proj_b, x_projb);
  fuse_ln_k<<<1024, 256, 0, stream>>>(x_patched, x_projb, x_features, ln_w, ln_b, focus, cat);
  prep_m1_k<<<6144, 256, 0, stream>>>(cat, m1x);

  // ---- m1: 2 layers on batched (64,32,768); di=1536, dr=48 ----
  for (int im = 0; im < 2; ++im) {
    const float* in_w   = m1w[0] + (size_t)im*3072*768;
    const float* conv_w = m1w[1] + (size_t)im*1536*4;
    const float* conv_b = m1w[2] + (size_t)im*1536;
    const float* xp_w   = m1w[3] + (size_t)im*80*1536;
    const float* dt_w   = m1w[4] + (size_t)im*1536*48;
    const float* dt_b   = m1w[5] + (size_t)im*1536;
    const float* A_log  = m1w[6] + (size_t)im*1536*16;
    const float* Dp     = m1w[7] + (size_t)im*1536;
    const float* out_w  = m1w[8] + (size_t)im*768*1536;
    // in-proj -> bxz (xi cols 0..1535, z cols 1536..3071)
    cvt3t_k<768,2304,1><<<4608, 256, 0, stream>>>(m1x, 768, A3i, 2048, 1179648);
    cvt3t_k<768,2304,0><<<6912, 256, 0, stream>>>(in_w, 768, W3i, 3072, 1769472);
    gemm3b_k<0,0,0><<<dim3(16,24), 256, 0, stream>>>(A3i, W3i, nullptr, nullptr,
                                                     bxz, 3072, 3072, 2048, 3072, 2304);
    // dwconv + silu, fused A3x emit
    dwconv3_m1_k<<<12288, 256, 0, stream>>>(bxz, conv_w, conv_b, bxc, A3x);
    // xp: split-K x8 -> partials @m2x -> reduce into bdbl
    cvt3t_k<1536,4608,0><<<576, 256, 0, stream>>>(xp_w, 1536, W3x, 80, 147456);
    gemm3bz_k<<<dim3(16,1,8), 256, 0, stream>>>(A3x, W3x, xppart, 80, 80, 2048, 4608, 576);
    reduce_xp_k<<<640, 256, 0, stream>>>(xppart, bdbl);
    // delta: streaming K=48
    dt1_k<<<dim3(256,6), 256, 0, stream>>>(bdbl, dt_w, dt_b, bdelta);
    // scan, fused A3o duo-split emit
    scan3_m1_k<<<384, 256, 0, stream>>>(bdelta, bxc, bdbl, bxz + 1536, A_log, Dp, A3o);
    // out-proj: duo-split 3-product split-K -> partials -> reduce (+residual) into m1x
    cvt3t_k<1536,3072,2><<<2304, 256, 0, stream>>>(out_w, 1536, W3o, 768, 589824);
    gemm3bz2_k<<<dim3(16,6,3), 256, 0, stream>>>(A3o, W3o, outpart, 768, 768, 2048, 1536);
    reduce_out_k<<<6144, 256, 0, stream>>>(outpart, m1x);
  }

  // ---- m2 prep (cat still alive; becomes Hend afterwards) ----
  prep_m2_k<<<6144, 256, 0, stream>>>(cat, m2x);

  // ---- m2: 2 layers on batched (64,768,32); di=64, dr=2 ----
  for (int im = 0; im < 2; ++im) {
    const float* in_w   = m2w[0] + (size_t)im*128*32;
    const float* conv_w = m2w[1] + (size_t)im*64*4;
    const float* conv_b = m2w[2] + (size_t)im*64;
    const float* xp_w   = m2w[3] + (size_t)im*34*64;
    const float* dt_w   = m2w[4] + (size_t)im*64*2;
    const float* dt_b   = m2w[5] + (size_t)im*64;
    const float* A_log  = m2w[6] + (size_t)im*64*16;
    const float* Dp     = m2w[7] + (size_t)im*64;
    const float* out_w  = m2w[8] + (size_t)im*32*64;
    gemm_k<0,0><<<dim3(768,2), 256, 0, stream>>>(m2x, 32, in_w, nullptr, nullptr,
                                                 bxz, 128, 49152, 128, 32);
    dwconv_silu_k<<<12288, 256, 0, stream>>>(bxz, 128, conv_w, conv_b, bxc, 64, 768, 49152*64);
    gemm_k<0,0><<<dim3(768,1), 256, 0, stream>>>(bxc, 64, xp_w, nullptr, nullptr,
                                                 bdbl, 34, 49152, 34, 64);
    dt2_k<<<12288, 256, 0, stream>>>(bdbl, dt_w, dt_b, bdelta);
    scan2_partA<<<192, 256, 0, stream>>>(bdelta, bxc, bdbl, A_log, sHend, sSde);
    scan2_carry<<<16, 256, 0, stream>>>(A_log, sHend, sSde);
    scan2_partC<<<192, 256, 0, stream>>>(bdelta, bxc, bdbl, bxz + 64, A_log, Dp, sHend, by);
    gemm_k<0,1><<<dim3(768,1), 256, 0, stream>>>(by, 64, out_w, nullptr, m2x,
                                                 m2x, 32, 49152, 32, 64);
  }

  // ---- head ----
  x3_k<<<32, 256, 0, stream>>>(m1x, m2x, x3);
  head_k<<<32, 512, 0, stream>>>(x3, reg_w1, reg_b1, reg_w2, reg_b2, (float*)d_out);
}

// Round 8
// 943.489 us; speedup vs baseline: 2.6755x; 1.0773x over previous
//
#include <hip/hip_runtime.h>
#include <math.h>

#define DEV __device__ __forceinline__

DEV float sigmoid_(float x){ return 1.f/(1.f+__expf(-x)); }
DEV float silu_(float x){ return x * sigmoid_(x); }
DEV float softplus_(float x){ return (x > 20.f) ? x : log1pf(__expf(x)); }
DEV float gelu_(float x){ return 0.5f*x*(1.f + erff(x*0.70710678118654752440f)); }

typedef __attribute__((ext_vector_type(8))) short short8v;
typedef __attribute__((ext_vector_type(4))) short short4v;
typedef __attribute__((ext_vector_type(4))) float floatx4;

DEV short bf_split(float x, bool want_lo){
  unsigned u = __float_as_uint(x);
  unsigned hb = (u + 0x7FFFu + ((u >> 16) & 1u)) >> 16;
  if (!want_lo) return (short)hb;
  float lo = x - __uint_as_float(hb << 16);
  unsigned ul = __float_as_uint(lo);
  return (short)((ul + 0x7FFFu + ((ul >> 16) & 1u)) >> 16);
}

// ---------------- fp32 GEMM (m2's K<=64 streaming shapes) ----------------
template<int ACT, int RES>
__global__ __launch_bounds__(256)
void gemm_k(const float* __restrict__ A, int lda,
            const float* __restrict__ W,
            const float* __restrict__ bias,
            const float* __restrict__ Rres,
            float* __restrict__ C, int ldc,
            int M, int N, int K)
{
  __shared__ float As[16][68];
  __shared__ float Ws[16][68];
  const int bm = blockIdx.x << 6;
  const int bn = blockIdx.y << 6;
  const int tid = threadIdx.x;
  const int tm0 = (tid >> 4) << 2;
  const int tn0 = (tid & 15) << 2;
  const int r   = tid >> 2;
  const int kk4 = (tid & 3) << 2;
  float acc[4][4] = {};
  for (int k0 = 0; k0 < K; k0 += 16) {
    const int gk = k0 + kk4;
    float4 va = make_float4(0.f,0.f,0.f,0.f);
    const int gr = bm + r;
    if (gr < M && gk < K) va = *(const float4*)(A + (size_t)gr*lda + gk);
    As[kk4+0][r]=va.x; As[kk4+1][r]=va.y; As[kk4+2][r]=va.z; As[kk4+3][r]=va.w;
    float4 vw = make_float4(0.f,0.f,0.f,0.f);
    const int gc = bn + r;
    if (gc < N && gk < K) vw = *(const float4*)(W + (size_t)gc*K + gk);
    Ws[kk4+0][r]=vw.x; Ws[kk4+1][r]=vw.y; Ws[kk4+2][r]=vw.z; Ws[kk4+3][r]=vw.w;
    __syncthreads();
    #pragma unroll
    for (int kk = 0; kk < 16; ++kk) {
      const float a0=As[kk][tm0+0], a1=As[kk][tm0+1], a2=As[kk][tm0+2], a3=As[kk][tm0+3];
      const float w0=Ws[kk][tn0+0], w1=Ws[kk][tn0+1], w2=Ws[kk][tn0+2], w3=Ws[kk][tn0+3];
      acc[0][0]+=a0*w0; acc[0][1]+=a0*w1; acc[0][2]+=a0*w2; acc[0][3]+=a0*w3;
      acc[1][0]+=a1*w0; acc[1][1]+=a1*w1; acc[1][2]+=a1*w2; acc[1][3]+=a1*w3;
      acc[2][0]+=a2*w0; acc[2][1]+=a2*w1; acc[2][2]+=a2*w2; acc[2][3]+=a2*w3;
      acc[3][0]+=a3*w0; acc[3][1]+=a3*w1; acc[3][2]+=a3*w2; acc[3][3]+=a3*w3;
    }
    __syncthreads();
  }
  #pragma unroll
  for (int i=0;i<4;i++){
    const int row = bm + tm0 + i;
    if (row >= M) continue;
    #pragma unroll
    for (int j=0;j<4;j++){
      const int col = bn + tn0 + j;
      if (col >= N) continue;
      float v = acc[i][j];
      if (bias) v += bias[col];
      if (RES)  v += Rres[(size_t)row*ldc + col];
      if (ACT == 1) v = softplus_(v);
      C[(size_t)row*ldc + col] = v;
    }
  }
}

// ---------------- vectorized split conversion ----------------
// MODE 0: [hi|lo|hi] (W triple), 1: [hi|hi|lo] (A triple), 2: [hi|lo] (duo)
template<int C, int KP, int MODE>
__global__ void cvt3t_k(const float* __restrict__ X, int ldx, short* __restrict__ Y,
                        int realR, int total4)
{
  const int i4 = blockIdx.x*256 + threadIdx.x;
  if (i4 >= total4) return;
  const int idx = i4 << 2;
  const int c3 = idx % KP;
  const int r  = idx / KP;
  short4v out = {0,0,0,0};
  const int nparts = (MODE == 2) ? 2 : 3;
  if (r < realR && c3 < nparts*C) {
    const int part = c3 / C;
    const int c = c3 - part*C;
    const bool lo = (MODE == 1) ? (part == 2) : (part == 1);
    const float4 v = *(const float4*)(X + (size_t)r*ldx + c);
    out.x = bf_split(v.x, lo); out.y = bf_split(v.y, lo);
    out.z = bf_split(v.z, lo); out.w = bf_split(v.w, lo);
  }
  *(short4v*)(Y + (size_t)r*KP + c3) = out;
}

// ---------------- bf16 MFMA GEMM (pipelined): C = act(A3 @ W3^T + bias [+ R]) ----------------
template<int ACT, int RES, int BIAS>
__global__ __launch_bounds__(256)
void gemm3b_k(const short* __restrict__ A3, const short* __restrict__ W3,
              const float* __restrict__ bias, const float* __restrict__ Rres,
              float* __restrict__ C, int ldc, int NOUT, int M, int N, int K3)
{
  __shared__ short As[128][40];
  __shared__ short Ws[128][40];
  const int bm = blockIdx.x << 7;
  const int bn = blockIdx.y << 7;
  const int tid = threadIdx.x;
  const int lane = tid & 63;
  const int wv = tid >> 6;
  const int wr = (wv >> 1) << 6;
  const int wc = (wv & 1) << 6;
  const int frow = lane & 15;
  const int fk   = lane >> 4;
  const int srow = tid >> 1;
  const int shalf = (tid & 1) << 4;

  floatx4 acc[4][4] = {};
  const short* gA = A3 + (size_t)(bm + srow)*K3 + shalf;
  const short* gW = W3 + (size_t)(bn + srow)*K3 + shalf;

  short8v va0 = *(const short8v*)(gA);
  short8v va1 = *(const short8v*)(gA + 8);
  short8v vw0 = *(const short8v*)(gW);
  short8v vw1 = *(const short8v*)(gW + 8);

  for (int k0 = 0; k0 < K3; k0 += 32) {
    __syncthreads();
    *(short8v*)&As[srow][shalf]     = va0;
    *(short8v*)&As[srow][shalf + 8] = va1;
    *(short8v*)&Ws[srow][shalf]     = vw0;
    *(short8v*)&Ws[srow][shalf + 8] = vw1;
    __syncthreads();
    const int kn = k0 + 32;
    if (kn < K3) {
      va0 = *(const short8v*)(gA + kn);
      va1 = *(const short8v*)(gA + kn + 8);
      vw0 = *(const short8v*)(gW + kn);
      vw1 = *(const short8v*)(gW + kn + 8);
    }
    short8v af[4], bfv[4];
    #pragma unroll
    for (int mf = 0; mf < 4; ++mf)
      af[mf] = *(const short8v*)&As[wr + mf*16 + frow][fk*8];
    #pragma unroll
    for (int nf = 0; nf < 4; ++nf)
      bfv[nf] = *(const short8v*)&Ws[wc + nf*16 + frow][fk*8];
    #pragma unroll
    for (int mf = 0; mf < 4; ++mf)
      #pragma unroll
      for (int nf = 0; nf < 4; ++nf)
        acc[mf][nf] = __builtin_amdgcn_mfma_f32_16x16x32_bf16(af[mf], bfv[nf], acc[mf][nf], 0, 0, 0);
  }

  #pragma unroll
  for (int mf = 0; mf < 4; ++mf) {
    #pragma unroll
    for (int nf = 0; nf < 4; ++nf) {
      const int col = bn + wc + nf*16 + (lane & 15);
      if (col >= NOUT) continue;
      #pragma unroll
      for (int r = 0; r < 4; ++r) {
        const int row = bm + wr + mf*16 + (lane >> 4)*4 + r;
        float v = acc[mf][nf][r];
        if (BIAS) v += bias[col];
        if (RES)  v += Rres[(size_t)row*ldc + col];
        if (ACT == 1) v = softplus_(v);
        C[(size_t)row*ldc + col] = v;
      }
    }
  }
}

// ---------------- split-K partial-plane GEMM ----------------
__global__ __launch_bounds__(256)
void gemm3bz_k(const short* __restrict__ A3, const short* __restrict__ W3,
               float* __restrict__ C, int ldc, int NOUT, int M, int K3, int KC)
{
  __shared__ short As[128][40];
  __shared__ short Ws[128][40];
  const int bm = blockIdx.x << 7;
  const int bn = blockIdx.y << 7;
  const int kbeg = blockIdx.z * KC;
  float* Cpart = C + (size_t)blockIdx.z * M * ldc;
  const int tid = threadIdx.x;
  const int lane = tid & 63;
  const int wv = tid >> 6;
  const int wr = (wv >> 1) << 6;
  const int wc = (wv & 1) << 6;
  const int frow = lane & 15;
  const int fk   = lane >> 4;
  const int srow = tid >> 1;
  const int shalf = (tid & 1) << 4;

  floatx4 acc[4][4] = {};
  const short* gA = A3 + (size_t)(bm + srow)*K3 + shalf + kbeg;
  const short* gW = W3 + (size_t)(bn + srow)*K3 + shalf + kbeg;

  short8v va0 = *(const short8v*)(gA);
  short8v va1 = *(const short8v*)(gA + 8);
  short8v vw0 = *(const short8v*)(gW);
  short8v vw1 = *(const short8v*)(gW + 8);

  for (int k0 = 0; k0 < KC; k0 += 32) {
    __syncthreads();
    *(short8v*)&As[srow][shalf]     = va0;
    *(short8v*)&As[srow][shalf + 8] = va1;
    *(short8v*)&Ws[srow][shalf]     = vw0;
    *(short8v*)&Ws[srow][shalf + 8] = vw1;
    __syncthreads();
    const int kn = k0 + 32;
    if (kn < KC) {
      va0 = *(const short8v*)(gA + kn);
      va1 = *(const short8v*)(gA + kn + 8);
      vw0 = *(const short8v*)(gW + kn);
      vw1 = *(const short8v*)(gW + kn + 8);
    }
    short8v af[4], bfv[4];
    #pragma unroll
    for (int mf = 0; mf < 4; ++mf)
      af[mf] = *(const short8v*)&As[wr + mf*16 + frow][fk*8];
    #pragma unroll
    for (int nf = 0; nf < 4; ++nf)
      bfv[nf] = *(const short8v*)&Ws[wc + nf*16 + frow][fk*8];
    #pragma unroll
    for (int mf = 0; mf < 4; ++mf)
      #pragma unroll
      for (int nf = 0; nf < 4; ++nf)
        acc[mf][nf] = __builtin_amdgcn_mfma_f32_16x16x32_bf16(af[mf], bfv[nf], acc[mf][nf], 0, 0, 0);
  }

  #pragma unroll
  for (int mf = 0; mf < 4; ++mf) {
    #pragma unroll
    for (int nf = 0; nf < 4; ++nf) {
      const int col = bn + wc + nf*16 + (lane & 15);
      if (col >= NOUT) continue;
      #pragma unroll
      for (int r = 0; r < 4; ++r) {
        const int row = bm + wr + mf*16 + (lane >> 4)*4 + r;
        Cpart[(size_t)row*ldc + col] = acc[mf][nf][r];
      }
    }
  }
}

// ---------------- duo-split 3-product GEMM: A,W stored [hi|lo] (row stride 2K) ----------------
__global__ __launch_bounds__(256)
void gemm3bz2_k(const short* __restrict__ A2, const short* __restrict__ W2,
                float* __restrict__ C, int ldc, int NOUT, int M, int K)
{
  __shared__ short As[128][40];
  __shared__ short Ws[128][40];
  const int bm = blockIdx.x << 7;
  const int bn = blockIdx.y << 7;
  const int z = blockIdx.z;
  const int kA = (z == 2) ? K : 0;
  const int kW = (z == 1) ? K : 0;
  float* Cpart = C + (size_t)z * M * ldc;
  const int tid = threadIdx.x;
  const int lane = tid & 63;
  const int wv = tid >> 6;
  const int wr = (wv >> 1) << 6;
  const int wc = (wv & 1) << 6;
  const int frow = lane & 15;
  const int fk   = lane >> 4;
  const int srow = tid >> 1;
  const int shalf = (tid & 1) << 4;

  floatx4 acc[4][4] = {};
  const short* gA = A2 + (size_t)(bm + srow)*(2*K) + shalf + kA;
  const short* gW = W2 + (size_t)(bn + srow)*(2*K) + shalf + kW;

  short8v va0 = *(const short8v*)(gA);
  short8v va1 = *(const short8v*)(gA + 8);
  short8v vw0 = *(const short8v*)(gW);
  short8v vw1 = *(const short8v*)(gW + 8);

  for (int k0 = 0; k0 < K; k0 += 32) {
    __syncthreads();
    *(short8v*)&As[srow][shalf]     = va0;
    *(short8v*)&As[srow][shalf + 8] = va1;
    *(short8v*)&Ws[srow][shalf]     = vw0;
    *(short8v*)&Ws[srow][shalf + 8] = vw1;
    __syncthreads();
    const int kn = k0 + 32;
    if (kn < K) {
      va0 = *(const short8v*)(gA + kn);
      va1 = *(const short8v*)(gA + kn + 8);
      vw0 = *(const short8v*)(gW + kn);
      vw1 = *(const short8v*)(gW + kn + 8);
    }
    short8v af[4], bfv[4];
    #pragma unroll
    for (int mf = 0; mf < 4; ++mf)
      af[mf] = *(const short8v*)&As[wr + mf*16 + frow][fk*8];
    #pragma unroll
    for (int nf = 0; nf < 4; ++nf)
      bfv[nf] = *(const short8v*)&Ws[wc + nf*16 + frow][fk*8];
    #pragma unroll
    for (int mf = 0; mf < 4; ++mf)
      #pragma unroll
      for (int nf = 0; nf < 4; ++nf)
        acc[mf][nf] = __builtin_amdgcn_mfma_f32_16x16x32_bf16(af[mf], bfv[nf], acc[mf][nf], 0, 0, 0);
  }

  #pragma unroll
  for (int mf = 0; mf < 4; ++mf) {
    #pragma unroll
    for (int nf = 0; nf < 4; ++nf) {
      const int col = bn + wc + nf*16 + (lane & 15);
      if (col >= NOUT) continue;
      #pragma unroll
      for (int r = 0; r < 4; ++r) {
        const int row = bm + wr + mf*16 + (lane >> 4)*4 + r;
        Cpart[(size_t)row*ldc + col] = acc[mf][nf][r];
      }
    }
  }
}

// ---------------- split-K reduce kernels ----------------
__global__ void reduce_xp_k(const float* __restrict__ part, float* __restrict__ out)
{
  const int i = blockIdx.x*256 + threadIdx.x;   // 2048*80
  if (i >= 163840) return;
  float s = 0.f;
  #pragma unroll
  for (int z = 0; z < 8; ++z) s += part[(size_t)z*163840 + i];
  out[i] = s;
}
__global__ void reduce_feat_k(const float* __restrict__ part, const float* __restrict__ bias,
                              float* __restrict__ out)
{
  const int i = blockIdx.x*256 + threadIdx.x;   // 1024*128
  if (i >= 131072) return;
  const int r = i >> 7, c = i & 127;
  float s = bias[c];
  #pragma unroll
  for (int z = 0; z < 8; ++z) s += part[(size_t)z*131072 + i];
  out[(size_t)r*256 + 128 + c] = s;
}
__global__ void reduce_out_k(const float* __restrict__ part, float* __restrict__ m1x)
{
  const int i = blockIdx.x*256 + threadIdx.x;   // 2048*768
  if (i >= 1572864) return;
  float s = m1x[i];
  #pragma unroll
  for (int z = 0; z < 3; ++z) s += part[(size_t)z*1572864 + i];
  m1x[i] = s;
}

// ---------------- m1 delta projection: streaming K=48 ----------------
__global__ __launch_bounds__(256)
void dt1_k(const float* __restrict__ dbl, const float* __restrict__ dt_w,
           const float* __restrict__ dt_b, float* __restrict__ delta)
{
  const int d = blockIdx.y*256 + threadIdx.x;
  const int r0 = blockIdx.x*8;
  float w[48];
  #pragma unroll
  for (int q = 0; q < 12; ++q)
    *(float4*)&w[q*4] = *(const float4*)(dt_w + (size_t)d*48 + q*4);
  __shared__ float sdbl[8][48];
  if (threadIdx.x < 96) {
    const int rr = threadIdx.x / 12, q = threadIdx.x % 12;
    *(float4*)&sdbl[rr][q*4] = *(const float4*)(dbl + (size_t)(r0+rr)*80 + q*4);
  }
  __syncthreads();
  const float bv = dt_b[d];
  #pragma unroll
  for (int rr = 0; rr < 8; ++rr) {
    float acc = bv;
    #pragma unroll
    for (int k = 0; k < 48; ++k) acc += sdbl[rr][k]*w[k];
    delta[(size_t)(r0+rr)*1536 + d] = softplus_(acc);
  }
}

// ---------------- patch conv im2col -> triple-split bf16 ----------------
__global__ void im2col3_k(const float* __restrict__ x, int c0, short* __restrict__ A3)
{
  const int t = blockIdx.x*256 + threadIdx.x;
  if (t >= 2097152) return;
  const int b = t >> 16;
  const int r = t & 65535;
  const int c = r >> 12;
  const int f = r & 4095;
  const float4 v = *(const float4*)(x + (((size_t)b*32 + c0 + c) << 14) + (f << 2));
  const int o4 = f << 2;
  const int h = o4 >> 7, w = o4 & 127;
  const int patch = ((h >> 4) << 3) + (w >> 4);
  const int pos = ((h & 15) << 4) + (w & 15);
  const int row = (b << 6) + patch;
  const int k = (c << 8) + pos;
  short4v hv, lv;
  hv.x = bf_split(v.x,false); lv.x = bf_split(v.x,true);
  hv.y = bf_split(v.y,false); lv.y = bf_split(v.y,true);
  hv.z = bf_split(v.z,false); lv.z = bf_split(v.z,true);
  hv.w = bf_split(v.w,false); lv.w = bf_split(v.w,true);
  short* base = A3 + (size_t)row*12288 + k;
  *(short4v*)(base)        = hv;
  *(short4v*)(base + 4096) = hv;
  *(short4v*)(base + 8192) = lv;
}

__global__ void reduce_patch16_k(const float* __restrict__ part, const float* __restrict__ bias,
                                 short* __restrict__ A3p)
{
  const int idx = blockIdx.x*256 + threadIdx.x;
  if (idx >= 65536) return;
  const int patch = idx & 63;
  const int o = (idx >> 6) & 31;
  const int b = idx >> 11;
  const int row = (b << 6) + patch;
  float s = bias[o];
  #pragma unroll
  for (int z = 0; z < 16; ++z) s += part[(size_t)z*65536 + row*32 + o];
  const short hi = bf_split(s,false), lo = bf_split(s,true);
  short* p = A3p + (size_t)((b << 5) + o)*192 + patch;
  p[0] = hi; p[64] = hi; p[128] = lo;
}

// ---------------- fused: x_proj assemble + gelu fuse + concat + layernorm ----------------
__global__ __launch_bounds__(256)
void fuse_ln_k(const float* __restrict__ xpat, const float* __restrict__ xprojbuf,
               const float* __restrict__ xfeat, const float* __restrict__ lnw,
               const float* __restrict__ lnb, const float* __restrict__ focusp,
               float* __restrict__ cat)
{
  const int row = blockIdx.x;
  const int t = threadIdx.x;
  const float focus = focusp[0];
  const float xp = xpat[(size_t)row*256 + t];
  const float pr = (t < 128) ? xfeat[(size_t)row*1280 + t] : xprojbuf[(size_t)row*256 + t];
  const float xf = gelu_(focus*pr + (2.f - focus)*xp);
  float s  = xp + xf + pr;
  float sq = xp*xp + xf*xf + pr*pr;
  __shared__ float rs[4], rq[4];
  const int lane = t & 63, wv = t >> 6;
  #pragma unroll
  for (int off = 32; off > 0; off >>= 1) {
    s  += __shfl_down(s,  off, 64);
    sq += __shfl_down(sq, off, 64);
  }
  if (lane == 0) { rs[wv] = s; rq[wv] = sq; }
  __syncthreads();
  const float S = rs[0]+rs[1]+rs[2]+rs[3];
  const float Q = rq[0]+rq[1]+rq[2]+rq[3];
  const float mu = S * (1.f/768.f);
  const float var = Q*(1.f/768.f) - mu*mu;
  const float rstd = rsqrtf(var + 1e-5f);
  const size_t ob = (size_t)row*768;
  cat[ob +        t] = (xp - mu)*rstd*lnw[      t] + lnb[      t];
  cat[ob + 256 +  t] = (xf - mu)*rstd*lnw[256 + t] + lnb[256 + t];
  cat[ob + 512 +  t] = (pr - mu)*rstd*lnw[512 + t] + lnb[512 + t];
}

// ---------------- prep: duplicate + flip ----------------
__global__ void prep_m1_k(const float* __restrict__ cat, float* __restrict__ X)
{
  const int idx = blockIdx.x*256 + threadIdx.x;
  if (idx >= 64*32*768) return;
  const int d = idx % 768;
  const int sl = idx / 768;
  const int l = sl & 31;
  const int s = sl >> 5;
  const int b = s & 31;
  const int ll = (s < 32) ? l : 31 - l;
  X[idx] = cat[((size_t)b*32 + ll)*768 + d];
}
__global__ void prep_m2_k(const float* __restrict__ cat, float* __restrict__ X)
{
  const int idx = blockIdx.x*256 + threadIdx.x;
  if (idx >= 64*768*32) return;
  const int c = idx & 31;
  const int sj = idx >> 5;
  const int j = sj % 768;
  const int s = sj / 768;
  const int b = (s < 32) ? s : s - 32;
  const int jj = (s < 32) ? j : 767 - j;
  X[idx] = cat[((size_t)b*32 + c)*768 + jj];
}

// ---------------- m2 depthwise causal conv (k=4) + silu ----------------
__global__ void dwconv_silu_k(const float* __restrict__ xz, int ldxz,
                              const float* __restrict__ w, const float* __restrict__ b,
                              float* __restrict__ xc, int di, int L, int total)
{
  const int idx = blockIdx.x*256 + threadIdx.x;
  if (idx >= total) return;
  const int d = idx % di;
  const int sl = idx / di;
  const int l = sl % L;
  float acc = b[d];
  const float* wd = w + d*4;
  #pragma unroll
  for (int k = 0; k < 4; ++k) {
    const int ll = l - 3 + k;
    if (ll >= 0) acc += xz[(size_t)(sl - 3 + k)*ldxz + d] * wd[k];
  }
  xc[idx] = silu_(acc);
}

// ---------------- m1 dwconv + silu, fused with A3x triple-split emit ----------------
__global__ void dwconv3_m1_k(const float* __restrict__ xz,
                             const float* __restrict__ w, const float* __restrict__ b,
                             float* __restrict__ xc, short* __restrict__ A3x)
{
  const int idx = blockIdx.x*256 + threadIdx.x;
  if (idx >= 3145728) return;
  const int d = idx % 1536;
  const int sl = idx / 1536;
  const int l = sl & 31;
  float acc = b[d];
  const float* wd = w + d*4;
  #pragma unroll
  for (int k = 0; k < 4; ++k) {
    const int ll = l - 3 + k;
    if (ll >= 0) acc += xz[(size_t)(sl - 3 + k)*3072 + d] * wd[k];
  }
  const float v = silu_(acc);
  xc[idx] = v;
  const short hi = bf_split(v,false), lo = bf_split(v,true);
  short* p = A3x + (size_t)sl*4608 + d;
  p[0] = hi; p[1536] = hi; p[3072] = lo;
}

// ---------------- m2 dt projection (K=2) + softplus ----------------
__global__ void dt2_k(const float* __restrict__ dbl, const float* __restrict__ dt_w,
                      const float* __restrict__ dt_b, float* __restrict__ delta)
{
  const int idx = blockIdx.x*256 + threadIdx.x;
  if (idx >= 49152*64) return;
  const int d = idx & 63;
  const int r = idx >> 6;
  const float a0 = dbl[(size_t)r*34 + 0], a1 = dbl[(size_t)r*34 + 1];
  delta[idx] = softplus_(a0*dt_w[d*2] + a1*dt_w[d*2+1] + dt_b[d]);
}

// ---------------- m1 selective scan (L=32), fused with A3o duo-split emit ----------------
__global__ void scan3_m1_k(const float* __restrict__ delta, const float* __restrict__ xc,
                           const float* __restrict__ dbl, const float* __restrict__ z,
                           const float* __restrict__ A_log, const float* __restrict__ Dp,
                           short* __restrict__ A3o)
{
  const int idx = blockIdx.x*256 + threadIdx.x;
  if (idx >= 98304) return;
  const int d = idx % 1536;
  const int s = idx / 1536;
  float A[16], h[16];
  #pragma unroll
  for (int n = 0; n < 16; ++n) { A[n] = -__expf(A_log[d*16 + n]); h[n] = 0.f; }
  const float Dv = Dp[d];
  for (int l = 0; l < 32; ++l) {
    const size_t row = (size_t)s*32 + l;
    const float de  = delta[row*1536 + d];
    const float xcv = xc[row*1536 + d];
    const float du  = de * xcv;
    const float* bl = dbl + row*80 + 48;
    float y = 0.f;
    #pragma unroll
    for (int n = 0; n < 16; ++n) {
      const float dA = __expf(de * A[n]);
      h[n] = dA*h[n] + du*bl[n];
      y += h[n]*bl[16 + n];
    }
    const float zv = z[row*3072 + d];
    const float out = (y + xcv*Dv) * silu_(zv);
    short* p = A3o + row*3072 + d;
    p[0] = bf_split(out,false);
    p[1536] = bf_split(out,true);
  }
}

// ---------------- m2 chunked scan: 12 chunks of 64, 4-way state-split ----------------
#define NC2 12
#define LC2 64

// grid 768 = 64 seq * 12 chunks; block 256: wave wv -> d = wv*16 + (lane&15), hf = lane>>4
__global__ __launch_bounds__(256)
void scan2_partA(const float* __restrict__ delta, const float* __restrict__ xc,
                 const float* __restrict__ dbl, const float* __restrict__ A_log,
                 float* __restrict__ Hend, unsigned short* __restrict__ sde_buf)
{
  const int s = blockIdx.x / NC2;
  const int c = blockIdx.x % NC2;
  const int lane = threadIdx.x & 63;
  const int wv = threadIdx.x >> 6;
  const int d = wv*16 + (lane & 15);
  const int hf = lane >> 4;
  const int n0 = hf*4;
  float A[4], h[4];
  #pragma unroll
  for (int n = 0; n < 4; ++n) { A[n] = -__expf(A_log[d*16 + n0 + n]); h[n] = 0.f; }
  float sde = 0.f;
  const size_t row0 = (size_t)s*768 + c*LC2;
  for (int l = 0; l < LC2; ++l) {
    const size_t row = row0 + l;
    const float de  = delta[row*64 + d];
    const float xcv = xc[row*64 + d];
    const float du  = de * xcv;
    const float* bl = dbl + row*34 + 2 + n0;
    sde += de;
    #pragma unroll
    for (int n = 0; n < 4; ++n)
      h[n] = __expf(de*A[n])*h[n] + du*bl[n];
  }
  float* hp = Hend + ((size_t)((s*NC2 + c)*64 + d))*16 + n0;
  #pragma unroll
  for (int n = 0; n < 4; ++n) hp[n] = h[n];
  if (hf == 0) {
    const unsigned u = __float_as_uint(sde);
    sde_buf[(s*NC2 + c)*64 + d] = (unsigned short)((u + 0x7FFFu + ((u >> 16) & 1u)) >> 16);
  }
}

__global__ void scan2_carry(const float* __restrict__ A_log,
                            float* __restrict__ Hend, const unsigned short* __restrict__ sde_buf)
{
  const int t = blockIdx.x*256 + threadIdx.x;
  if (t >= 4096) return;
  const int d = t & 63;
  const int s = t >> 6;
  float A[16], H[16];
  #pragma unroll
  for (int n = 0; n < 16; ++n) { A[n] = -__expf(A_log[d*16 + n]); H[n] = 0.f; }
  for (int c = 0; c < NC2; ++c) {
    const size_t off = ((size_t)(s*NC2 + c)*64 + d)*16;
    const float sde = __uint_as_float(((unsigned)sde_buf[(s*NC2 + c)*64 + d]) << 16);
    #pragma unroll
    for (int n = 0; n < 16; ++n) {
      const float he = Hend[off + n];
      Hend[off + n] = H[n];
      H[n] = __expf(sde*A[n])*H[n] + he;
    }
  }
}

__global__ __launch_bounds__(256)
void scan2_partC(const float* __restrict__ delta, const float* __restrict__ xc,
                 const float* __restrict__ dbl, const float* __restrict__ z,
                 const float* __restrict__ A_log, const float* __restrict__ Dp,
                 const float* __restrict__ Hin, float* __restrict__ Y)
{
  const int s = blockIdx.x / NC2;
  const int c = blockIdx.x % NC2;
  const int lane = threadIdx.x & 63;
  const int wv = threadIdx.x >> 6;
  const int d = wv*16 + (lane & 15);
  const int hf = lane >> 4;
  const int n0 = hf*4;
  float A[4], h[4];
  const float* hp = Hin + ((size_t)((s*NC2 + c)*64 + d))*16 + n0;
  #pragma unroll
  for (int n = 0; n < 4; ++n) {
    A[n] = -__expf(A_log[d*16 + n0 + n]);
    h[n] = hp[n];
  }
  const float Dv = Dp[d];
  const size_t row0 = (size_t)s*768 + c*LC2;
  for (int l = 0; l < LC2; ++l) {
    const size_t row = row0 + l;
    const float de  = delta[row*64 + d];
    const float xcv = xc[row*64 + d];
    const float du  = de * xcv;
    const float* bl = dbl + row*34 + 2 + n0;
    float y = 0.f;
    #pragma unroll
    for (int n = 0; n < 4; ++n) {
      const float dA = __expf(de*A[n]);
      h[n] = dA*h[n] + du*bl[n];
      y += h[n]*bl[16 + n];
    }
    y += __shfl_xor(y, 16);
    y += __shfl_xor(y, 32);
    if (hf == 0) {
      const float zv = z[row*128 + d];
      Y[row*64 + d] = (y + xcv*Dv) * silu_(zv);
    }
  }
}

// ---------------- combine + mean over l ----------------
__global__ __launch_bounds__(256)
void x3_k(const float* __restrict__ x1p, const float* __restrict__ x2p, float* __restrict__ x3)
{
  const int b = blockIdx.x;
  for (int j = threadIdx.x; j < 768; j += 256) {
    float s = 0.f;
    for (int i = 0; i < 32; ++i) {
      s += x1p[((size_t)b*32 + i)*768 + j] + x1p[((size_t)(b+32)*32 + i)*768 + j];
      s += x2p[((size_t)b*768 + j)*32 + i] + x2p[((size_t)(b+32)*768 + j)*32 + i];
    }
    x3[(size_t)b*768 + j] = s * (1.f/32.f);
  }
}

// ---------------- regression head ----------------
__global__ __launch_bounds__(512)
void head_k(const float* __restrict__ x3, const float* __restrict__ w1, const float* __restrict__ b1,
            const float* __restrict__ w2, const float* __restrict__ b2, float* __restrict__ out)
{
  const int b = blockIdx.x;
  const int t = threadIdx.x;
  __shared__ float xrow[768];
  for (int i = t; i < 768; i += 512) xrow[i] = x3[(size_t)b*768 + i];
  __syncthreads();
  float hv = 0.f;
  if (t < 384) {
    const float* wr = w1 + (size_t)t*768;
    float acc = b1[t];
    for (int d = 0; d < 768; ++d) acc += xrow[d]*wr[d];
    hv = acc * w2[t];
  }
  __shared__ float red[8];
  const int lane = t & 63, wv = t >> 6;
  #pragma unroll
  for (int off = 32; off > 0; off >>= 1) hv += __shfl_down(hv, off, 64);
  if (lane == 0) red[wv] = hv;
  __syncthreads();
  if (t == 0) {
    float s = b2[0];
    #pragma unroll
    for (int i = 0; i < 8; ++i) s += red[i];
    out[b] = s;
  }
}

extern "C" void kernel_launch(void* const* d_in, const int* in_sizes, int n_in,
                              void* d_out, int out_size, void* d_ws, size_t ws_size,
                              hipStream_t stream)
{
  (void)in_sizes; (void)n_in; (void)out_size;
  const float* x_cwt        = (const float*)d_in[0];
  const float* x_features   = (const float*)d_in[1];
  const float* patch_conv_w = (const float*)d_in[2];
  const float* patch_conv_b = (const float*)d_in[3];
  const float* patch_proj_w = (const float*)d_in[4];
  const float* patch_proj_b = (const float*)d_in[5];
  const float* feat_proj_w  = (const float*)d_in[6];
  const float* feat_proj_b  = (const float*)d_in[7];
  const float* ln_w         = (const float*)d_in[8];
  const float* ln_b         = (const float*)d_in[9];
  const float* focus        = (const float*)d_in[10];
  const float* reg_w1       = (const float*)d_in[11];
  const float* reg_b1       = (const float*)d_in[12];
  const float* reg_w2       = (const float*)d_in[13];
  const float* reg_b2       = (const float*)d_in[14];
  const float* m1w[9]; for (int i=0;i<9;i++) m1w[i] = (const float*)d_in[15+i];
  const float* m2w[9]; for (int i=0;i<9;i++) m2w[i] = (const float*)d_in[24+i];

  // ---- arena (floats), 21,356,544 fl ----
  float* p = (float*)d_ws;
  size_t need = 0;
  auto alloc = [&](size_t n){ float* r = p; p += n; need += n; return r; };
  float* cat    = alloc(786432);    // front/m1: cat | m2 loop: Hend
  float* m1x    = alloc(1572864);
  float* m2x    = alloc(1572864);
  float* x3     = alloc(24576);     // m2 loop: sde | end: x3
  float* bxz    = alloc(6291456);
  float* bxc    = alloc(3145728);
  float* bdbl   = alloc(1671168);
  float* bdelta = alloc(3145728);
  float* by     = alloc(3145728);
  if (ws_size < need * sizeof(float)) return;

  // ---- overlays (liveness traced per stage) ----
  short* A3pc  = (short*)bxz;            // 2048x12288 sh
  short* W3pc  = (short*)by;             // 32x12288 sh x2 halves
  float* pcpart = by + 800000;           // 16 x 65536 fl
  float* x_patched = m1x;                // 262,144
  float* x_projb   = m1x + 262144;       // 262,144
  short* A3p = (short*)(m1x + 524288);   // 1024x192 sh
  short* W3p = (short*)(m1x + 630016);   // 256x192 sh
  short* A3f = (short*)bxz;              // 1024x3072 sh
  short* W3f = (short*)(bxz + 1600000);  // 128x3072 sh
  float* featpart = m2x;                 // 8 x 131072 fl
  short* A3i  = (short*)bxc;             // 2048x2304 sh
  short* W3i  = (short*)bdbl;            // 3072x2304 sh
  short* A3x  = (short*)bdbl;            // 2048x4608 sh
  short* W3x  = (short*)by;              // 128x4608 sh
  float* xppart = m2x;                   // 8 x 163840 fl
  short* A3o  = (short*)by;              // 2048x3072 sh ([hi|lo])
  short* W3o  = (short*)bxc;             // 768x3072 sh ([hi|lo])
  float* outpart = bdbl;                 // 3 x 1,572,864 fl
  float* sHend = cat;
  unsigned short* sSde = (unsigned short*)x3;

  // ---- patch conv: 2 halves of im2col + split-K MFMA ----
  im2col3_k<<<8192, 256, 0, stream>>>(x_cwt, 0, A3pc);
  cvt3t_k<4096,12288,0><<<1536, 256, 0, stream>>>(patch_conv_w, 8192, W3pc, 32, 393216);
  gemm3bz_k<<<dim3(16,1,8), 256, 0, stream>>>(A3pc, W3pc, pcpart, 32, 32, 2048, 12288, 1536);
  im2col3_k<<<8192, 256, 0, stream>>>(x_cwt, 16, A3pc);
  cvt3t_k<4096,12288,0><<<1536, 256, 0, stream>>>(patch_conv_w + 4096, 8192, W3pc, 32, 393216);
  gemm3bz_k<<<dim3(16,1,8), 256, 0, stream>>>(A3pc, W3pc, pcpart + 8*65536, 32, 32, 2048, 12288, 1536);
  reduce_patch16_k<<<256, 256, 0, stream>>>(pcpart, patch_conv_b, A3p);
  cvt3t_k<64,192,0><<<48, 256, 0, stream>>>(patch_proj_w, 64, W3p, 256, 12288);
  gemm3b_k<0,0,1><<<dim3(8,2), 256, 0, stream>>>(A3p, W3p, patch_proj_b, nullptr,
                                                 x_patched, 256, 256, 1024, 256, 192);
  cvt3t_k<1024,3072,1><<<3072, 256, 0, stream>>>(x_features + 256, 1280, A3f, 1024, 786432);
  cvt3t_k<1024,3072,0><<<384, 256, 0, stream>>>(feat_proj_w, 1024, W3f, 128, 98304);
  gemm3bz_k<<<dim3(8,1,8), 256, 0, stream>>>(A3f, W3f, featpart, 128, 128, 1024, 3072, 384);
  reduce_feat_k<<<512, 256, 0, stream>>>(featpart, feat_proj_b, x_projb);
  fuse_ln_k<<<1024, 256, 0, stream>>>(x_patched, x_projb, x_features, ln_w, ln_b, focus, cat);
  prep_m1_k<<<6144, 256, 0, stream>>>(cat, m1x);

  // ---- m1: 2 layers on batched (64,32,768); di=1536, dr=48 ----
  for (int im = 0; im < 2; ++im) {
    const float* in_w   = m1w[0] + (size_t)im*3072*768;
    const float* conv_w = m1w[1] + (size_t)im*1536*4;
    const float* conv_b = m1w[2] + (size_t)im*1536;
    const float* xp_w   = m1w[3] + (size_t)im*80*1536;
    const float* dt_w   = m1w[4] + (size_t)im*1536*48;
    const float* dt_b   = m1w[5] + (size_t)im*1536;
    const float* A_log  = m1w[6] + (size_t)im*1536*16;
    const float* Dp     = m1w[7] + (size_t)im*1536;
    const float* out_w  = m1w[8] + (size_t)im*768*1536;
    cvt3t_k<768,2304,1><<<4608, 256, 0, stream>>>(m1x, 768, A3i, 2048, 1179648);
    cvt3t_k<768,2304,0><<<6912, 256, 0, stream>>>(in_w, 768, W3i, 3072, 1769472);
    gemm3b_k<0,0,0><<<dim3(16,24), 256, 0, stream>>>(A3i, W3i, nullptr, nullptr,
                                                     bxz, 3072, 3072, 2048, 3072, 2304);
    dwconv3_m1_k<<<12288, 256, 0, stream>>>(bxz, conv_w, conv_b, bxc, A3x);
    cvt3t_k<1536,4608,0><<<576, 256, 0, stream>>>(xp_w, 1536, W3x, 80, 147456);
    gemm3bz_k<<<dim3(16,1,8), 256, 0, stream>>>(A3x, W3x, xppart, 80, 80, 2048, 4608, 576);
    reduce_xp_k<<<640, 256, 0, stream>>>(xppart, bdbl);
    dt1_k<<<dim3(256,6), 256, 0, stream>>>(bdbl, dt_w, dt_b, bdelta);
    scan3_m1_k<<<384, 256, 0, stream>>>(bdelta, bxc, bdbl, bxz + 1536, A_log, Dp, A3o);
    cvt3t_k<1536,3072,2><<<2304, 256, 0, stream>>>(out_w, 1536, W3o, 768, 589824);
    gemm3bz2_k<<<dim3(16,6,3), 256, 0, stream>>>(A3o, W3o, outpart, 768, 768, 2048, 1536);
    reduce_out_k<<<6144, 256, 0, stream>>>(outpart, m1x);
  }

  // ---- m2 prep (cat still alive; becomes Hend afterwards) ----
  prep_m2_k<<<6144, 256, 0, stream>>>(cat, m2x);

  // ---- m2: 2 layers on batched (64,768,32); di=64, dr=2 ----
  for (int im = 0; im < 2; ++im) {
    const float* in_w   = m2w[0] + (size_t)im*128*32;
    const float* conv_w = m2w[1] + (size_t)im*64*4;
    const float* conv_b = m2w[2] + (size_t)im*64;
    const float* xp_w   = m2w[3] + (size_t)im*34*64;
    const float* dt_w   = m2w[4] + (size_t)im*64*2;
    const float* dt_b   = m2w[5] + (size_t)im*64;
    const float* A_log  = m2w[6] + (size_t)im*64*16;
    const float* Dp     = m2w[7] + (size_t)im*64;
    const float* out_w  = m2w[8] + (size_t)im*32*64;
    gemm_k<0,0><<<dim3(768,2), 256, 0, stream>>>(m2x, 32, in_w, nullptr, nullptr,
                                                 bxz, 128, 49152, 128, 32);
    dwconv_silu_k<<<12288, 256, 0, stream>>>(bxz, 128, conv_w, conv_b, bxc, 64, 768, 49152*64);
    gemm_k<0,0><<<dim3(768,1), 256, 0, stream>>>(bxc, 64, xp_w, nullptr, nullptr,
                                                 bdbl, 34, 49152, 34, 64);
    dt2_k<<<12288, 256, 0, stream>>>(bdbl, dt_w, dt_b, bdelta);
    scan2_partA<<<768, 256, 0, stream>>>(bdelta, bxc, bdbl, A_log, sHend, sSde);
    scan2_carry<<<16, 256, 0, stream>>>(A_log, sHend, sSde);
    scan2_partC<<<768, 256, 0, stream>>>(bdelta, bxc, bdbl, bxz + 64, A_log, Dp, sHend, by);
    gemm_k<0,1><<<dim3(768,1), 256, 0, stream>>>(by, 64, out_w, nullptr, m2x,
                                                 m2x, 32, 49152, 32, 64);
  }

  // ---- head ----
  x3_k<<<32, 256, 0, stream>>>(m1x, m2x, x3);
  head_k<<<32, 512, 0, stream>>>(x3, reg_w1, reg_b1, reg_w2, reg_b2, (float*)d_out);
}

// Round 9
// 884.137 us; speedup vs baseline: 2.8551x; 1.0671x over previous
//
#include <hip/hip_runtime.h>
#include <math.h>

#define DEV __device__ __forceinline__

DEV float sigmoid_(float x){ return 1.f/(1.f+__expf(-x)); }
DEV float silu_(float x){ return x * sigmoid_(x); }
DEV float softplus_(float x){ return (x > 20.f) ? x : log1pf(__expf(x)); }
DEV float gelu_(float x){ return 0.5f*x*(1.f + erff(x*0.70710678118654752440f)); }

typedef __attribute__((ext_vector_type(8))) short short8v;
typedef __attribute__((ext_vector_type(4))) short short4v;
typedef __attribute__((ext_vector_type(4))) float floatx4;

DEV float bfu_(unsigned short u){ return __uint_as_float(((unsigned)u) << 16); }
DEV unsigned short bfr_(float x){
  unsigned u = __float_as_uint(x);
  return (unsigned short)((u + 0x7FFFu + ((u >> 16) & 1u)) >> 16);
}
DEV short bf_split(float x, bool want_lo){
  unsigned u = __float_as_uint(x);
  unsigned hb = (u + 0x7FFFu + ((u >> 16) & 1u)) >> 16;
  if (!want_lo) return (short)hb;
  float lo = x - __uint_as_float(hb << 16);
  unsigned ul = __float_as_uint(lo);
  return (short)((ul + 0x7FFFu + ((ul >> 16) & 1u)) >> 16);
}

// ---------------- fp32 GEMM (m2's K<=64 streaming shapes) ----------------
template<int ACT, int RES>
__global__ __launch_bounds__(256)
void gemm_k(const float* __restrict__ A, int lda,
            const float* __restrict__ W,
            const float* __restrict__ bias,
            const float* __restrict__ Rres,
            float* __restrict__ C, int ldc,
            int M, int N, int K)
{
  __shared__ float As[16][68];
  __shared__ float Ws[16][68];
  const int bm = blockIdx.x << 6;
  const int bn = blockIdx.y << 6;
  const int tid = threadIdx.x;
  const int tm0 = (tid >> 4) << 2;
  const int tn0 = (tid & 15) << 2;
  const int r   = tid >> 2;
  const int kk4 = (tid & 3) << 2;
  float acc[4][4] = {};
  for (int k0 = 0; k0 < K; k0 += 16) {
    const int gk = k0 + kk4;
    float4 va = make_float4(0.f,0.f,0.f,0.f);
    const int gr = bm + r;
    if (gr < M && gk < K) va = *(const float4*)(A + (size_t)gr*lda + gk);
    As[kk4+0][r]=va.x; As[kk4+1][r]=va.y; As[kk4+2][r]=va.z; As[kk4+3][r]=va.w;
    float4 vw = make_float4(0.f,0.f,0.f,0.f);
    const int gc = bn + r;
    if (gc < N && gk < K) vw = *(const float4*)(W + (size_t)gc*K + gk);
    Ws[kk4+0][r]=vw.x; Ws[kk4+1][r]=vw.y; Ws[kk4+2][r]=vw.z; Ws[kk4+3][r]=vw.w;
    __syncthreads();
    #pragma unroll
    for (int kk = 0; kk < 16; ++kk) {
      const float a0=As[kk][tm0+0], a1=As[kk][tm0+1], a2=As[kk][tm0+2], a3=As[kk][tm0+3];
      const float w0=Ws[kk][tn0+0], w1=Ws[kk][tn0+1], w2=Ws[kk][tn0+2], w3=Ws[kk][tn0+3];
      acc[0][0]+=a0*w0; acc[0][1]+=a0*w1; acc[0][2]+=a0*w2; acc[0][3]+=a0*w3;
      acc[1][0]+=a1*w0; acc[1][1]+=a1*w1; acc[1][2]+=a1*w2; acc[1][3]+=a1*w3;
      acc[2][0]+=a2*w0; acc[2][1]+=a2*w1; acc[2][2]+=a2*w2; acc[2][3]+=a2*w3;
      acc[3][0]+=a3*w0; acc[3][1]+=a3*w1; acc[3][2]+=a3*w2; acc[3][3]+=a3*w3;
    }
    __syncthreads();
  }
  #pragma unroll
  for (int i=0;i<4;i++){
    const int row = bm + tm0 + i;
    if (row >= M) continue;
    #pragma unroll
    for (int j=0;j<4;j++){
      const int col = bn + tn0 + j;
      if (col >= N) continue;
      float v = acc[i][j];
      if (bias) v += bias[col];
      if (RES)  v += Rres[(size_t)row*ldc + col];
      if (ACT == 1) v = softplus_(v);
      C[(size_t)row*ldc + col] = v;
    }
  }
}

// ---------------- vectorized split conversion ----------------
// MODE 0: [hi|lo|hi] (W triple), 1: [hi|hi|lo] (A triple), 2: [hi|lo] (duo)
template<int C, int KP, int MODE>
__global__ void cvt3t_k(const float* __restrict__ X, int ldx, short* __restrict__ Y,
                        int realR, int total4)
{
  const int i4 = blockIdx.x*256 + threadIdx.x;
  if (i4 >= total4) return;
  const int idx = i4 << 2;
  const int c3 = idx % KP;
  const int r  = idx / KP;
  short4v out = {0,0,0,0};
  const int nparts = (MODE == 2) ? 2 : 3;
  if (r < realR && c3 < nparts*C) {
    const int part = c3 / C;
    const int c = c3 - part*C;
    const bool lo = (MODE == 1) ? (part == 2) : (part == 1);
    const float4 v = *(const float4*)(X + (size_t)r*ldx + c);
    out.x = bf_split(v.x, lo); out.y = bf_split(v.y, lo);
    out.z = bf_split(v.z, lo); out.w = bf_split(v.w, lo);
  }
  *(short4v*)(Y + (size_t)r*KP + c3) = out;
}

// ---------------- bf16 MFMA GEMM 128x128 (pad-36, pipelined) ----------------
template<int ACT, int RES, int BIAS>
__global__ __launch_bounds__(256)
void gemm3b_k(const short* __restrict__ A3, const short* __restrict__ W3,
              const float* __restrict__ bias, const float* __restrict__ Rres,
              float* __restrict__ C, int ldc, int NOUT, int M, int N, int K3)
{
  __shared__ short As[128][36];
  __shared__ short Ws[128][36];
  const int bm = blockIdx.x << 7;
  const int bn = blockIdx.y << 7;
  const int tid = threadIdx.x;
  const int lane = tid & 63;
  const int wv = tid >> 6;
  const int wr = (wv >> 1) << 6;
  const int wc = (wv & 1) << 6;
  const int frow = lane & 15;
  const int fk   = lane >> 4;
  const int srow = tid >> 1;
  const int shalf = (tid & 1) << 4;

  floatx4 acc[4][4] = {};
  const short* gA = A3 + (size_t)(bm + srow)*K3 + shalf;
  const short* gW = W3 + (size_t)(bn + srow)*K3 + shalf;

  short8v va0 = *(const short8v*)(gA);
  short8v va1 = *(const short8v*)(gA + 8);
  short8v vw0 = *(const short8v*)(gW);
  short8v vw1 = *(const short8v*)(gW + 8);

  for (int k0 = 0; k0 < K3; k0 += 32) {
    __syncthreads();
    *(short8v*)&As[srow][shalf]     = va0;
    *(short8v*)&As[srow][shalf + 8] = va1;
    *(short8v*)&Ws[srow][shalf]     = vw0;
    *(short8v*)&Ws[srow][shalf + 8] = vw1;
    __syncthreads();
    const int kn = k0 + 32;
    if (kn < K3) {
      va0 = *(const short8v*)(gA + kn);
      va1 = *(const short8v*)(gA + kn + 8);
      vw0 = *(const short8v*)(gW + kn);
      vw1 = *(const short8v*)(gW + kn + 8);
    }
    short8v af[4], bfv[4];
    #pragma unroll
    for (int mf = 0; mf < 4; ++mf)
      af[mf] = *(const short8v*)&As[wr + mf*16 + frow][fk*8];
    #pragma unroll
    for (int nf = 0; nf < 4; ++nf)
      bfv[nf] = *(const short8v*)&Ws[wc + nf*16 + frow][fk*8];
    #pragma unroll
    for (int mf = 0; mf < 4; ++mf)
      #pragma unroll
      for (int nf = 0; nf < 4; ++nf)
        acc[mf][nf] = __builtin_amdgcn_mfma_f32_16x16x32_bf16(af[mf], bfv[nf], acc[mf][nf], 0, 0, 0);
  }

  #pragma unroll
  for (int mf = 0; mf < 4; ++mf) {
    #pragma unroll
    for (int nf = 0; nf < 4; ++nf) {
      const int col = bn + wc + nf*16 + (lane & 15);
      if (col >= NOUT) continue;
      #pragma unroll
      for (int r = 0; r < 4; ++r) {
        const int row = bm + wr + mf*16 + (lane >> 4)*4 + r;
        float v = acc[mf][nf][r];
        if (BIAS) v += bias[col];
        if (RES)  v += Rres[(size_t)row*ldc + col];
        if (ACT == 1) v = softplus_(v);
        C[(size_t)row*ldc + col] = v;
      }
    }
  }
}

// ---------------- split-K partial-plane GEMM 128x128 (pad-36) ----------------
__global__ __launch_bounds__(256)
void gemm3bz_k(const short* __restrict__ A3, const short* __restrict__ W3,
               float* __restrict__ C, int ldc, int NOUT, int M, int K3, int KC)
{
  __shared__ short As[128][36];
  __shared__ short Ws[128][36];
  const int bm = blockIdx.x << 7;
  const int bn = blockIdx.y << 7;
  const int kbeg = blockIdx.z * KC;
  float* Cpart = C + (size_t)blockIdx.z * M * ldc;
  const int tid = threadIdx.x;
  const int lane = tid & 63;
  const int wv = tid >> 6;
  const int wr = (wv >> 1) << 6;
  const int wc = (wv & 1) << 6;
  const int frow = lane & 15;
  const int fk   = lane >> 4;
  const int srow = tid >> 1;
  const int shalf = (tid & 1) << 4;

  floatx4 acc[4][4] = {};
  const short* gA = A3 + (size_t)(bm + srow)*K3 + shalf + kbeg;
  const short* gW = W3 + (size_t)(bn + srow)*K3 + shalf + kbeg;

  short8v va0 = *(const short8v*)(gA);
  short8v va1 = *(const short8v*)(gA + 8);
  short8v vw0 = *(const short8v*)(gW);
  short8v vw1 = *(const short8v*)(gW + 8);

  for (int k0 = 0; k0 < KC; k0 += 32) {
    __syncthreads();
    *(short8v*)&As[srow][shalf]     = va0;
    *(short8v*)&As[srow][shalf + 8] = va1;
    *(short8v*)&Ws[srow][shalf]     = vw0;
    *(short8v*)&Ws[srow][shalf + 8] = vw1;
    __syncthreads();
    const int kn = k0 + 32;
    if (kn < KC) {
      va0 = *(const short8v*)(gA + kn);
      va1 = *(const short8v*)(gA + kn + 8);
      vw0 = *(const short8v*)(gW + kn);
      vw1 = *(const short8v*)(gW + kn + 8);
    }
    short8v af[4], bfv[4];
    #pragma unroll
    for (int mf = 0; mf < 4; ++mf)
      af[mf] = *(const short8v*)&As[wr + mf*16 + frow][fk*8];
    #pragma unroll
    for (int nf = 0; nf < 4; ++nf)
      bfv[nf] = *(const short8v*)&Ws[wc + nf*16 + frow][fk*8];
    #pragma unroll
    for (int mf = 0; mf < 4; ++mf)
      #pragma unroll
      for (int nf = 0; nf < 4; ++nf)
        acc[mf][nf] = __builtin_amdgcn_mfma_f32_16x16x32_bf16(af[mf], bfv[nf], acc[mf][nf], 0, 0, 0);
  }

  #pragma unroll
  for (int mf = 0; mf < 4; ++mf) {
    #pragma unroll
    for (int nf = 0; nf < 4; ++nf) {
      const int col = bn + wc + nf*16 + (lane & 15);
      if (col >= NOUT) continue;
      #pragma unroll
      for (int r = 0; r < 4; ++r) {
        const int row = bm + wr + mf*16 + (lane >> 4)*4 + r;
        Cpart[(size_t)row*ldc + col] = acc[mf][nf][r];
      }
    }
  }
}

// ---------------- 128x64-tile split-K GEMM (pad-36): high-occupancy variant ----------------
// z-plane Cpart = C + z*M*ldc; for z==1 grids this writes C directly.
__global__ __launch_bounds__(256)
void gemm3bnz_k(const short* __restrict__ A3, const short* __restrict__ W3,
                float* __restrict__ C, int ldc, int NOUT, int M, int K3, int KC)
{
  __shared__ short As[128][36];
  __shared__ short Ws[64][36];
  const int bm = blockIdx.x << 7;
  const int bn = blockIdx.y << 6;
  const int kbeg = blockIdx.z * KC;
  float* Cpart = C + (size_t)blockIdx.z * M * ldc;
  const int tid = threadIdx.x;
  const int lane = tid & 63;
  const int wv = tid >> 6;
  const int wr = (wv >> 1) << 6;     // 0 / 64
  const int wc = (wv & 1) << 5;      // 0 / 32
  const int frow = lane & 15;
  const int fk   = lane >> 4;
  const int srow = tid >> 1;
  const int shalf = (tid & 1) << 4;
  const int srw = tid >> 2;          // W row (0..63)
  const int sq  = (tid & 3) << 3;    // W col chunk (shorts)

  floatx4 acc[4][2] = {};
  const short* gA = A3 + (size_t)(bm + srow)*K3 + shalf + kbeg;
  const short* gW = W3 + (size_t)(bn + srw)*K3 + sq + kbeg;

  short8v va0 = *(const short8v*)(gA);
  short8v va1 = *(const short8v*)(gA + 8);
  short8v vw0 = *(const short8v*)(gW);

  for (int k0 = 0; k0 < KC; k0 += 32) {
    __syncthreads();
    *(short8v*)&As[srow][shalf]     = va0;
    *(short8v*)&As[srow][shalf + 8] = va1;
    *(short8v*)&Ws[srw][sq]         = vw0;
    __syncthreads();
    const int kn = k0 + 32;
    if (kn < KC) {
      va0 = *(const short8v*)(gA + kn);
      va1 = *(const short8v*)(gA + kn + 8);
      vw0 = *(const short8v*)(gW + kn);
    }
    short8v af[4], bfv[2];
    #pragma unroll
    for (int mf = 0; mf < 4; ++mf)
      af[mf] = *(const short8v*)&As[wr + mf*16 + frow][fk*8];
    #pragma unroll
    for (int nf = 0; nf < 2; ++nf)
      bfv[nf] = *(const short8v*)&Ws[wc + nf*16 + frow][fk*8];
    #pragma unroll
    for (int mf = 0; mf < 4; ++mf)
      #pragma unroll
      for (int nf = 0; nf < 2; ++nf)
        acc[mf][nf] = __builtin_amdgcn_mfma_f32_16x16x32_bf16(af[mf], bfv[nf], acc[mf][nf], 0, 0, 0);
  }

  #pragma unroll
  for (int mf = 0; mf < 4; ++mf) {
    #pragma unroll
    for (int nf = 0; nf < 2; ++nf) {
      const int col = bn + wc + nf*16 + (lane & 15);
      if (col >= NOUT) continue;
      #pragma unroll
      for (int r = 0; r < 4; ++r) {
        const int row = bm + wr + mf*16 + (lane >> 4)*4 + r;
        Cpart[(size_t)row*ldc + col] = acc[mf][nf][r];
      }
    }
  }
}

// ---------------- duo-split 3-product GEMM with K-split: 6 planes ----------------
// z: p = z/2 (0:hh 1:hl 2:lh), ks = z%2; planes 0-3 -> C0, 4-5 -> C1
__global__ __launch_bounds__(256)
void gemm3bz2s_k(const short* __restrict__ A2, const short* __restrict__ W2,
                 float* __restrict__ C0, float* __restrict__ C1,
                 int ldc, int NOUT, int M, int K, int KC)
{
  __shared__ short As[128][36];
  __shared__ short Ws[128][36];
  const int bm = blockIdx.x << 7;
  const int bn = blockIdx.y << 7;
  const int z = blockIdx.z;
  const int pp = z >> 1;
  const int ks = z & 1;
  const int kA = ((pp == 2) ? K : 0) + ks*KC;
  const int kW = ((pp == 1) ? K : 0) + ks*KC;
  float* Cpart = (z < 4) ? (C0 + (size_t)z * M * ldc) : (C1 + (size_t)(z-4) * M * ldc);
  const int tid = threadIdx.x;
  const int lane = tid & 63;
  const int wv = tid >> 6;
  const int wr = (wv >> 1) << 6;
  const int wc = (wv & 1) << 6;
  const int frow = lane & 15;
  const int fk   = lane >> 4;
  const int srow = tid >> 1;
  const int shalf = (tid & 1) << 4;

  floatx4 acc[4][4] = {};
  const short* gA = A2 + (size_t)(bm + srow)*(2*K) + shalf + kA;
  const short* gW = W2 + (size_t)(bn + srow)*(2*K) + shalf + kW;

  short8v va0 = *(const short8v*)(gA);
  short8v va1 = *(const short8v*)(gA + 8);
  short8v vw0 = *(const short8v*)(gW);
  short8v vw1 = *(const short8v*)(gW + 8);

  for (int k0 = 0; k0 < KC; k0 += 32) {
    __syncthreads();
    *(short8v*)&As[srow][shalf]     = va0;
    *(short8v*)&As[srow][shalf + 8] = va1;
    *(short8v*)&Ws[srow][shalf]     = vw0;
    *(short8v*)&Ws[srow][shalf + 8] = vw1;
    __syncthreads();
    const int kn = k0 + 32;
    if (kn < KC) {
      va0 = *(const short8v*)(gA + kn);
      va1 = *(const short8v*)(gA + kn + 8);
      vw0 = *(const short8v*)(gW + kn);
      vw1 = *(const short8v*)(gW + kn + 8);
    }
    short8v af[4], bfv[4];
    #pragma unroll
    for (int mf = 0; mf < 4; ++mf)
      af[mf] = *(const short8v*)&As[wr + mf*16 + frow][fk*8];
    #pragma unroll
    for (int nf = 0; nf < 4; ++nf)
      bfv[nf] = *(const short8v*)&Ws[wc + nf*16 + frow][fk*8];
    #pragma unroll
    for (int mf = 0; mf < 4; ++mf)
      #pragma unroll
      for (int nf = 0; nf < 4; ++nf)
        acc[mf][nf] = __builtin_amdgcn_mfma_f32_16x16x32_bf16(af[mf], bfv[nf], acc[mf][nf], 0, 0, 0);
  }

  #pragma unroll
  for (int mf = 0; mf < 4; ++mf) {
    #pragma unroll
    for (int nf = 0; nf < 4; ++nf) {
      const int col = bn + wc + nf*16 + (lane & 15);
      if (col >= NOUT) continue;
      #pragma unroll
      for (int r = 0; r < 4; ++r) {
        const int row = bm + wr + mf*16 + (lane >> 4)*4 + r;
        Cpart[(size_t)row*ldc + col] = acc[mf][nf][r];
      }
    }
  }
}

// ---------------- split-K reduce kernels ----------------
__global__ void reduce_xp_k(const float* __restrict__ part, float* __restrict__ out)
{
  const int i = blockIdx.x*256 + threadIdx.x;   // 2048*80
  if (i >= 163840) return;
  float s = 0.f;
  #pragma unroll
  for (int z = 0; z < 8; ++z) s += part[(size_t)z*163840 + i];
  out[i] = s;
}
__global__ void reduce_feat_k(const float* __restrict__ part, const float* __restrict__ bias,
                              float* __restrict__ out)
{
  const int i = blockIdx.x*256 + threadIdx.x;   // 1024*128
  if (i >= 131072) return;
  const int r = i >> 7, c = i & 127;
  float s = bias[c];
  #pragma unroll
  for (int z = 0; z < 8; ++z) s += part[(size_t)z*131072 + i];
  out[(size_t)r*256 + 128 + c] = s;
}
__global__ void reduce_out_k(const float* __restrict__ p0, const float* __restrict__ p1,
                             float* __restrict__ m1x)
{
  const int i = blockIdx.x*256 + threadIdx.x;   // 2048*768
  if (i >= 1572864) return;
  float s = m1x[i];
  #pragma unroll
  for (int z = 0; z < 4; ++z) s += p0[(size_t)z*1572864 + i];
  #pragma unroll
  for (int z = 0; z < 2; ++z) s += p1[(size_t)z*1572864 + i];
  m1x[i] = s;
}

// ---------------- m1 delta projection: streaming K=48 ----------------
__global__ __launch_bounds__(256)
void dt1_k(const float* __restrict__ dbl, const float* __restrict__ dt_w,
           const float* __restrict__ dt_b, float* __restrict__ delta)
{
  const int d = blockIdx.y*256 + threadIdx.x;
  const int r0 = blockIdx.x*8;
  float w[48];
  #pragma unroll
  for (int q = 0; q < 12; ++q)
    *(float4*)&w[q*4] = *(const float4*)(dt_w + (size_t)d*48 + q*4);
  __shared__ float sdbl[8][48];
  if (threadIdx.x < 96) {
    const int rr = threadIdx.x / 12, q = threadIdx.x % 12;
    *(float4*)&sdbl[rr][q*4] = *(const float4*)(dbl + (size_t)(r0+rr)*80 + q*4);
  }
  __syncthreads();
  const float bv = dt_b[d];
  #pragma unroll
  for (int rr = 0; rr < 8; ++rr) {
    float acc = bv;
    #pragma unroll
    for (int k = 0; k < 48; ++k) acc += sdbl[rr][k]*w[k];
    delta[(size_t)(r0+rr)*1536 + d] = softplus_(acc);
  }
}

// ---------------- patch conv im2col -> triple-split bf16 ----------------
__global__ void im2col3_k(const float* __restrict__ x, int c0, short* __restrict__ A3)
{
  const int t = blockIdx.x*256 + threadIdx.x;
  if (t >= 2097152) return;
  const int b = t >> 16;
  const int r = t & 65535;
  const int c = r >> 12;
  const int f = r & 4095;
  const float4 v = *(const float4*)(x + (((size_t)b*32 + c0 + c) << 14) + (f << 2));
  const int o4 = f << 2;
  const int h = o4 >> 7, w = o4 & 127;
  const int patch = ((h >> 4) << 3) + (w >> 4);
  const int pos = ((h & 15) << 4) + (w & 15);
  const int row = (b << 6) + patch;
  const int k = (c << 8) + pos;
  short4v hv, lv;
  hv.x = bf_split(v.x,false); lv.x = bf_split(v.x,true);
  hv.y = bf_split(v.y,false); lv.y = bf_split(v.y,true);
  hv.z = bf_split(v.z,false); lv.z = bf_split(v.z,true);
  hv.w = bf_split(v.w,false); lv.w = bf_split(v.w,true);
  short* base = A3 + (size_t)row*12288 + k;
  *(short4v*)(base)        = hv;
  *(short4v*)(base + 4096) = hv;
  *(short4v*)(base + 8192) = lv;
}

__global__ void reduce_patch16_k(const float* __restrict__ part, const float* __restrict__ bias,
                                 short* __restrict__ A3p)
{
  const int idx = blockIdx.x*256 + threadIdx.x;
  if (idx >= 65536) return;
  const int patch = idx & 63;
  const int o = (idx >> 6) & 31;
  const int b = idx >> 11;
  const int row = (b << 6) + patch;
  float s = bias[o];
  #pragma unroll
  for (int z = 0; z < 16; ++z) s += part[(size_t)z*65536 + row*32 + o];
  const short hi = bf_split(s,false), lo = bf_split(s,true);
  short* p = A3p + (size_t)((b << 5) + o)*192 + patch;
  p[0] = hi; p[64] = hi; p[128] = lo;
}

// ---------------- fused: x_proj assemble + gelu fuse + concat + layernorm ----------------
__global__ __launch_bounds__(256)
void fuse_ln_k(const float* __restrict__ xpat, const float* __restrict__ xprojbuf,
               const float* __restrict__ xfeat, const float* __restrict__ lnw,
               const float* __restrict__ lnb, const float* __restrict__ focusp,
               float* __restrict__ cat)
{
  const int row = blockIdx.x;
  const int t = threadIdx.x;
  const float focus = focusp[0];
  const float xp = xpat[(size_t)row*256 + t];
  const float pr = (t < 128) ? xfeat[(size_t)row*1280 + t] : xprojbuf[(size_t)row*256 + t];
  const float xf = gelu_(focus*pr + (2.f - focus)*xp);
  float s  = xp + xf + pr;
  float sq = xp*xp + xf*xf + pr*pr;
  __shared__ float rs[4], rq[4];
  const int lane = t & 63, wv = t >> 6;
  #pragma unroll
  for (int off = 32; off > 0; off >>= 1) {
    s  += __shfl_down(s,  off, 64);
    sq += __shfl_down(sq, off, 64);
  }
  if (lane == 0) { rs[wv] = s; rq[wv] = sq; }
  __syncthreads();
  const float S = rs[0]+rs[1]+rs[2]+rs[3];
  const float Q = rq[0]+rq[1]+rq[2]+rq[3];
  const float mu = S * (1.f/768.f);
  const float var = Q*(1.f/768.f) - mu*mu;
  const float rstd = rsqrtf(var + 1e-5f);
  const size_t ob = (size_t)row*768;
  cat[ob +        t] = (xp - mu)*rstd*lnw[      t] + lnb[      t];
  cat[ob + 256 +  t] = (xf - mu)*rstd*lnw[256 + t] + lnb[256 + t];
  cat[ob + 512 +  t] = (pr - mu)*rstd*lnw[512 + t] + lnb[512 + t];
}

// ---------------- prep: duplicate + flip ----------------
__global__ void prep_m1_k(const float* __restrict__ cat, float* __restrict__ X)
{
  const int idx = blockIdx.x*256 + threadIdx.x;
  if (idx >= 64*32*768) return;
  const int d = idx % 768;
  const int sl = idx / 768;
  const int l = sl & 31;
  const int s = sl >> 5;
  const int b = s & 31;
  const int ll = (s < 32) ? l : 31 - l;
  X[idx] = cat[((size_t)b*32 + ll)*768 + d];
}
__global__ void prep_m2_k(const float* __restrict__ cat, float* __restrict__ X)
{
  const int idx = blockIdx.x*256 + threadIdx.x;
  if (idx >= 64*768*32) return;
  const int c = idx & 31;
  const int sj = idx >> 5;
  const int j = sj % 768;
  const int s = sj / 768;
  const int b = (s < 32) ? s : s - 32;
  const int jj = (s < 32) ? j : 767 - j;
  X[idx] = cat[((size_t)b*32 + c)*768 + jj];
}

// ---------------- m2 depthwise causal conv (k=4) + silu ----------------
__global__ void dwconv_silu_k(const float* __restrict__ xz, int ldxz,
                              const float* __restrict__ w, const float* __restrict__ b,
                              float* __restrict__ xc, int di, int L, int total)
{
  const int idx = blockIdx.x*256 + threadIdx.x;
  if (idx >= total) return;
  const int d = idx % di;
  const int sl = idx / di;
  const int l = sl % L;
  float acc = b[d];
  const float* wd = w + d*4;
  #pragma unroll
  for (int k = 0; k < 4; ++k) {
    const int ll = l - 3 + k;
    if (ll >= 0) acc += xz[(size_t)(sl - 3 + k)*ldxz + d] * wd[k];
  }
  xc[idx] = silu_(acc);
}

// ---------------- m1 dwconv + silu, fused with A3x triple-split emit ----------------
__global__ void dwconv3_m1_k(const float* __restrict__ xz,
                             const float* __restrict__ w, const float* __restrict__ b,
                             float* __restrict__ xc, short* __restrict__ A3x)
{
  const int idx = blockIdx.x*256 + threadIdx.x;
  if (idx >= 3145728) return;
  const int d = idx % 1536;
  const int sl = idx / 1536;
  const int l = sl & 31;
  float acc = b[d];
  const float* wd = w + d*4;
  #pragma unroll
  for (int k = 0; k < 4; ++k) {
    const int ll = l - 3 + k;
    if (ll >= 0) acc += xz[(size_t)(sl - 3 + k)*3072 + d] * wd[k];
  }
  const float v = silu_(acc);
  xc[idx] = v;
  const short hi = bf_split(v,false), lo = bf_split(v,true);
  short* p = A3x + (size_t)sl*4608 + d;
  p[0] = hi; p[1536] = hi; p[3072] = lo;
}

// ---------------- m2 dt projection (K=2) + softplus ----------------
__global__ void dt2_k(const float* __restrict__ dbl, const float* __restrict__ dt_w,
                      const float* __restrict__ dt_b, float* __restrict__ delta)
{
  const int idx = blockIdx.x*256 + threadIdx.x;
  if (idx >= 49152*64) return;
  const int d = idx & 63;
  const int r = idx >> 6;
  const float a0 = dbl[(size_t)r*34 + 0], a1 = dbl[(size_t)r*34 + 1];
  delta[idx] = softplus_(a0*dt_w[d*2] + a1*dt_w[d*2+1] + dt_b[d]);
}

// ---------------- m1 selective scan (L=32), fused with A3o duo-split emit ----------------
__global__ void scan3_m1_k(const float* __restrict__ delta, const float* __restrict__ xc,
                           const float* __restrict__ dbl, const float* __restrict__ z,
                           const float* __restrict__ A_log, const float* __restrict__ Dp,
                           short* __restrict__ A3o)
{
  const int idx = blockIdx.x*256 + threadIdx.x;
  if (idx >= 98304) return;
  const int d = idx % 1536;
  const int s = idx / 1536;
  float A[16], h[16];
  #pragma unroll
  for (int n = 0; n < 16; ++n) { A[n] = -__expf(A_log[d*16 + n]); h[n] = 0.f; }
  const float Dv = Dp[d];
  for (int l = 0; l < 32; ++l) {
    const size_t row = (size_t)s*32 + l;
    const float de  = delta[row*1536 + d];
    const float xcv = xc[row*1536 + d];
    const float du  = de * xcv;
    const float* bl = dbl + row*80 + 48;
    float y = 0.f;
    #pragma unroll
    for (int n = 0; n < 16; ++n) {
      const float dA = __expf(de * A[n]);
      h[n] = dA*h[n] + du*bl[n];
      y += h[n]*bl[16 + n];
    }
    const float zv = z[row*3072 + d];
    const float out = (y + xcv*Dv) * silu_(zv);
    short* p = A3o + row*3072 + d;
    p[0] = bf_split(out,false);
    p[1536] = bf_split(out,true);
  }
}

// ---------------- m2 chunked scan: 24 chunks of 32, 4-way state-split, bf16 Hend ----------------
#define NC2 24
#define LC2 32

// grid 1536 = 64 seq * 24 chunks; block 256: d = wv*16 + (lane&15), hf = lane>>4
__global__ __launch_bounds__(256)
void scan2_partA(const float* __restrict__ delta, const float* __restrict__ xc,
                 const float* __restrict__ dbl, const float* __restrict__ A_log,
                 unsigned short* __restrict__ Hend, unsigned short* __restrict__ sde_buf)
{
  const int s = blockIdx.x / NC2;
  const int c = blockIdx.x % NC2;
  const int lane = threadIdx.x & 63;
  const int wv = threadIdx.x >> 6;
  const int d = wv*16 + (lane & 15);
  const int hf = lane >> 4;
  const int n0 = hf*4;
  float A[4], h[4];
  #pragma unroll
  for (int n = 0; n < 4; ++n) { A[n] = -__expf(A_log[d*16 + n0 + n]); h[n] = 0.f; }
  float sde = 0.f;
  const size_t row0 = (size_t)s*768 + c*LC2;
  for (int l = 0; l < LC2; ++l) {
    const size_t row = row0 + l;
    const float de  = delta[row*64 + d];
    const float xcv = xc[row*64 + d];
    const float du  = de * xcv;
    const float* bl = dbl + row*34 + 2 + n0;
    sde += de;
    #pragma unroll
    for (int n = 0; n < 4; ++n)
      h[n] = __expf(de*A[n])*h[n] + du*bl[n];
  }
  short4v hv;
  hv.x = (short)bfr_(h[0]); hv.y = (short)bfr_(h[1]);
  hv.z = (short)bfr_(h[2]); hv.w = (short)bfr_(h[3]);
  *(short4v*)(Hend + ((size_t)((s*NC2 + c)*64 + d))*16 + n0) = hv;
  if (hf == 0) sde_buf[(s*NC2 + c)*64 + d] = bfr_(sde);
}

__global__ void scan2_carry(const float* __restrict__ A_log,
                            unsigned short* __restrict__ Hend,
                            const unsigned short* __restrict__ sde_buf)
{
  const int t = blockIdx.x*256 + threadIdx.x;
  if (t >= 4096) return;
  const int d = t & 63;
  const int s = t >> 6;
  float A[16], H[16];
  #pragma unroll
  for (int n = 0; n < 16; ++n) { A[n] = -__expf(A_log[d*16 + n]); H[n] = 0.f; }
  for (int c = 0; c < NC2; ++c) {
    const size_t off = ((size_t)(s*NC2 + c)*64 + d)*16;
    const float sde = bfu_(sde_buf[(s*NC2 + c)*64 + d]);
    #pragma unroll
    for (int n = 0; n < 16; ++n) {
      const float he = bfu_(Hend[off + n]);
      Hend[off + n] = bfr_(H[n]);               // becomes H_in for chunk c
      H[n] = __expf(sde*A[n])*H[n] + he;
    }
  }
}

__global__ __launch_bounds__(256)
void scan2_partC(const float* __restrict__ delta, const float* __restrict__ xc,
                 const float* __restrict__ dbl, const float* __restrict__ z,
                 const float* __restrict__ A_log, const float* __restrict__ Dp,
                 const unsigned short* __restrict__ Hin, float* __restrict__ Y)
{
  const int s = blockIdx.x / NC2;
  const int c = blockIdx.x % NC2;
  const int lane = threadIdx.x & 63;
  const int wv = threadIdx.x >> 6;
  const int d = wv*16 + (lane & 15);
  const int hf = lane >> 4;
  const int n0 = hf*4;
  float A[4], h[4];
  const unsigned short* hp = Hin + ((size_t)((s*NC2 + c)*64 + d))*16 + n0;
  #pragma unroll
  for (int n = 0; n < 4; ++n) {
    A[n] = -__expf(A_log[d*16 + n0 + n]);
    h[n] = bfu_(hp[n]);
  }
  const float Dv = Dp[d];
  const size_t row0 = (size_t)s*768 + c*LC2;
  for (int l = 0; l < LC2; ++l) {
    const size_t row = row0 + l;
    const float de  = delta[row*64 + d];
    const float xcv = xc[row*64 + d];
    const float du  = de * xcv;
    const float* bl = dbl + row*34 + 2 + n0;
    float y = 0.f;
    #pragma unroll
    for (int n = 0; n < 4; ++n) {
      const float dA = __expf(de*A[n]);
      h[n] = dA*h[n] + du*bl[n];
      y += h[n]*bl[16 + n];
    }
    y += __shfl_xor(y, 16);
    y += __shfl_xor(y, 32);
    if (hf == 0) {
      const float zv = z[row*128 + d];
      Y[row*64 + d] = (y + xcv*Dv) * silu_(zv);
    }
  }
}

// ---------------- combine + mean over l ----------------
__global__ __launch_bounds__(256)
void x3_k(const float* __restrict__ x1p, const float* __restrict__ x2p, float* __restrict__ x3)
{
  const int b = blockIdx.x;
  for (int j = threadIdx.x; j < 768; j += 256) {
    float s = 0.f;
    for (int i = 0; i < 32; ++i) {
      s += x1p[((size_t)b*32 + i)*768 + j] + x1p[((size_t)(b+32)*32 + i)*768 + j];
      s += x2p[((size_t)b*768 + j)*32 + i] + x2p[((size_t)(b+32)*768 + j)*32 + i];
    }
    x3[(size_t)b*768 + j] = s * (1.f/32.f);
  }
}

// ---------------- regression head ----------------
__global__ __launch_bounds__(512)
void head_k(const float* __restrict__ x3, const float* __restrict__ w1, const float* __restrict__ b1,
            const float* __restrict__ w2, const float* __restrict__ b2, float* __restrict__ out)
{
  const int b = blockIdx.x;
  const int t = threadIdx.x;
  __shared__ float xrow[768];
  for (int i = t; i < 768; i += 512) xrow[i] = x3[(size_t)b*768 + i];
  __syncthreads();
  float hv = 0.f;
  if (t < 384) {
    const float* wr = w1 + (size_t)t*768;
    float acc = b1[t];
    for (int d = 0; d < 768; ++d) acc += xrow[d]*wr[d];
    hv = acc * w2[t];
  }
  __shared__ float red[8];
  const int lane = t & 63, wv = t >> 6;
  #pragma unroll
  for (int off = 32; off > 0; off >>= 1) hv += __shfl_down(hv, off, 64);
  if (lane == 0) red[wv] = hv;
  __syncthreads();
  if (t == 0) {
    float s = b2[0];
    #pragma unroll
    for (int i = 0; i < 8; ++i) s += red[i];
    out[b] = s;
  }
}

extern "C" void kernel_launch(void* const* d_in, const int* in_sizes, int n_in,
                              void* d_out, int out_size, void* d_ws, size_t ws_size,
                              hipStream_t stream)
{
  (void)in_sizes; (void)n_in; (void)out_size;
  const float* x_cwt        = (const float*)d_in[0];
  const float* x_features   = (const float*)d_in[1];
  const float* patch_conv_w = (const float*)d_in[2];
  const float* patch_conv_b = (const float*)d_in[3];
  const float* patch_proj_w = (const float*)d_in[4];
  const float* patch_proj_b = (const float*)d_in[5];
  const float* feat_proj_w  = (const float*)d_in[6];
  const float* feat_proj_b  = (const float*)d_in[7];
  const float* ln_w         = (const float*)d_in[8];
  const float* ln_b         = (const float*)d_in[9];
  const float* focus        = (const float*)d_in[10];
  const float* reg_w1       = (const float*)d_in[11];
  const float* reg_b1       = (const float*)d_in[12];
  const float* reg_w2       = (const float*)d_in[13];
  const float* reg_b2       = (const float*)d_in[14];
  const float* m1w[9]; for (int i=0;i<9;i++) m1w[i] = (const float*)d_in[15+i];
  const float* m2w[9]; for (int i=0;i<9;i++) m2w[i] = (const float*)d_in[24+i];

  // ---- arena (floats), 21,356,544 fl = 85.4MB (proven ws >= 87.8MB) ----
  float* p = (float*)d_ws;
  size_t need = 0;
  auto alloc = [&](size_t n){ float* r = p; p += n; need += n; return r; };
  float* cat    = alloc(786432);    // front/m1: cat | m2 loop: Hend (bf16, exact fit)
  float* m1x    = alloc(1572864);
  float* m2x    = alloc(1572864);
  float* x3     = alloc(24576);     // m2 loop: sde (ushort, exact fit) | end: x3
  float* bxz    = alloc(6291456);
  float* bxc    = alloc(3145728);
  float* bdbl   = alloc(1671168);
  float* bdelta = alloc(3145728);
  float* by     = alloc(3145728);
  if (ws_size < need * sizeof(float)) return;

  // ---- overlays (liveness traced per stage) ----
  short* A3pc  = (short*)bxz;            // 2048x12288 sh
  short* W3pc  = (short*)by;             // 32x12288 sh per half
  float* pcpart = by + 800000;           // 16 x 65536 fl
  float* x_patched = m1x;                // 262,144
  float* x_projb   = m1x + 262144;       // 262,144
  short* A3p = (short*)(m1x + 524288);   // 1024x192 sh
  short* W3p = (short*)(m1x + 630016);   // 256x192 sh
  short* A3f = (short*)bxz;              // 1024x3072 sh
  short* W3f = (short*)(bxz + 1600000);  // 128x3072 sh
  float* featpart = m2x;                 // 8 x 131072 fl
  short* A3i  = (short*)bxc;             // 2048x2304 sh
  short* W3i  = (short*)bdbl;            // 3072x2304 sh (bdbl+bdelta head)
  short* A3x  = (short*)bdbl;            // 2048x4608 sh (bdbl+bdelta span)
  short* W3x  = (short*)by;              // 128x4608 sh
  float* xppart = m2x;                   // 8 x 163840 fl
  short* A3o  = (short*)by;              // 2048x3072 sh ([hi|lo]) = by exactly
  short* W3o  = (short*)bxc;             // 768x3072 sh ([hi|lo])
  float* outp0 = bxz;                    // 4 planes x 1,572,864 fl (z dead after scan3)
  float* outp1 = bdelta;                 // 2 planes x 1,572,864 fl (delta dead after scan3)
  unsigned short* sHend = (unsigned short*)cat;  // 1,572,864 ushorts = cat exactly
  unsigned short* sSde  = (unsigned short*)x3;   // 98,304 ushorts = x3 exactly

  // ---- patch conv: 2 halves of im2col + 128x64-tile split-K MFMA ----
  im2col3_k<<<8192, 256, 0, stream>>>(x_cwt, 0, A3pc);
  cvt3t_k<4096,12288,0><<<1536, 256, 0, stream>>>(patch_conv_w, 8192, W3pc, 32, 393216);
  gemm3bnz_k<<<dim3(16,1,8), 256, 0, stream>>>(A3pc, W3pc, pcpart, 32, 32, 2048, 12288, 1536);
  im2col3_k<<<8192, 256, 0, stream>>>(x_cwt, 16, A3pc);
  cvt3t_k<4096,12288,0><<<1536, 256, 0, stream>>>(patch_conv_w + 4096, 8192, W3pc, 32, 393216);
  gemm3bnz_k<<<dim3(16,1,8), 256, 0, stream>>>(A3pc, W3pc, pcpart + 8*65536, 32, 32, 2048, 12288, 1536);
  reduce_patch16_k<<<256, 256, 0, stream>>>(pcpart, patch_conv_b, A3p);
  cvt3t_k<64,192,0><<<48, 256, 0, stream>>>(patch_proj_w, 64, W3p, 256, 12288);
  gemm3b_k<0,0,1><<<dim3(8,2), 256, 0, stream>>>(A3p, W3p, patch_proj_b, nullptr,
                                                 x_patched, 256, 256, 1024, 256, 192);
  cvt3t_k<1024,3072,1><<<3072, 256, 0, stream>>>(x_features + 256, 1280, A3f, 1024, 786432);
  cvt3t_k<1024,3072,0><<<384, 256, 0, stream>>>(feat_proj_w, 1024, W3f, 128, 98304);
  gemm3bz_k<<<dim3(8,1,8), 256, 0, stream>>>(A3f, W3f, featpart, 128, 128, 1024, 3072, 384);
  reduce_feat_k<<<512, 256, 0, stream>>>(featpart, feat_proj_b, x_projb);
  fuse_ln_k<<<1024, 256, 0, stream>>>(x_patched, x_projb, x_features, ln_w, ln_b, focus, cat);
  prep_m1_k<<<6144, 256, 0, stream>>>(cat, m1x);

  // ---- m1: 2 layers on batched (64,32,768); di=1536, dr=48 ----
  for (int im = 0; im < 2; ++im) {
    const float* in_w   = m1w[0] + (size_t)im*3072*768;
    const float* conv_w = m1w[1] + (size_t)im*1536*4;
    const float* conv_b = m1w[2] + (size_t)im*1536;
    const float* xp_w   = m1w[3] + (size_t)im*80*1536;
    const float* dt_w   = m1w[4] + (size_t)im*1536*48;
    const float* dt_b   = m1w[5] + (size_t)im*1536;
    const float* A_log  = m1w[6] + (size_t)im*1536*16;
    const float* Dp     = m1w[7] + (size_t)im*1536;
    const float* out_w  = m1w[8] + (size_t)im*768*1536;
    // in-proj -> bxz via high-occupancy 128x64 tiles (768 blocks)
    cvt3t_k<768,2304,1><<<4608, 256, 0, stream>>>(m1x, 768, A3i, 2048, 1179648);
    cvt3t_k<768,2304,0><<<6912, 256, 0, stream>>>(in_w, 768, W3i, 3072, 1769472);
    gemm3bnz_k<<<dim3(16,48,1), 256, 0, stream>>>(A3i, W3i, bxz, 3072, 3072, 2048, 2304, 2304);
    dwconv3_m1_k<<<12288, 256, 0, stream>>>(bxz, conv_w, conv_b, bxc, A3x);
    cvt3t_k<1536,4608,0><<<576, 256, 0, stream>>>(xp_w, 1536, W3x, 80, 147456);
    gemm3bz_k<<<dim3(16,1,8), 256, 0, stream>>>(A3x, W3x, xppart, 80, 80, 2048, 4608, 576);
    reduce_xp_k<<<640, 256, 0, stream>>>(xppart, bdbl);
    dt1_k<<<dim3(256,6), 256, 0, stream>>>(bdbl, dt_w, dt_b, bdelta);
    scan3_m1_k<<<384, 256, 0, stream>>>(bdelta, bxc, bdbl, bxz + 1536, A_log, Dp, A3o);
    // out-proj: duo-split 3-product x 2 K-split -> 6 planes -> reduce (+residual)
    cvt3t_k<1536,3072,2><<<2304, 256, 0, stream>>>(out_w, 1536, W3o, 768, 589824);
    gemm3bz2s_k<<<dim3(16,6,6), 256, 0, stream>>>(A3o, W3o, outp0, outp1, 768, 768, 2048, 1536, 768);
    reduce_out_k<<<6144, 256, 0, stream>>>(outp0, outp1, m1x);
  }

  // ---- m2 prep (cat still alive; becomes Hend afterwards) ----
  prep_m2_k<<<6144, 256, 0, stream>>>(cat, m2x);

  // ---- m2: 2 layers on batched (64,768,32); di=64, dr=2 ----
  for (int im = 0; im < 2; ++im) {
    const float* in_w   = m2w[0] + (size_t)im*128*32;
    const float* conv_w = m2w[1] + (size_t)im*64*4;
    const float* conv_b = m2w[2] + (size_t)im*64;
    const float* xp_w   = m2w[3] + (size_t)im*34*64;
    const float* dt_w   = m2w[4] + (size_t)im*64*2;
    const float* dt_b   = m2w[5] + (size_t)im*64;
    const float* A_log  = m2w[6] + (size_t)im*64*16;
    const float* Dp     = m2w[7] + (size_t)im*64;
    const float* out_w  = m2w[8] + (size_t)im*32*64;
    gemm_k<0,0><<<dim3(768,2), 256, 0, stream>>>(m2x, 32, in_w, nullptr, nullptr,
                                                 bxz, 128, 49152, 128, 32);
    dwconv_silu_k<<<12288, 256, 0, stream>>>(bxz, 128, conv_w, conv_b, bxc, 64, 768, 49152*64);
    gemm_k<0,0><<<dim3(768,1), 256, 0, stream>>>(bxc, 64, xp_w, nullptr, nullptr,
                                                 bdbl, 34, 49152, 34, 64);
    dt2_k<<<12288, 256, 0, stream>>>(bdbl, dt_w, dt_b, bdelta);
    scan2_partA<<<1536, 256, 0, stream>>>(bdelta, bxc, bdbl, A_log, sHend, sSde);
    scan2_carry<<<16, 256, 0, stream>>>(A_log, sHend, sSde);
    scan2_partC<<<1536, 256, 0, stream>>>(bdelta, bxc, bdbl, bxz + 64, A_log, Dp, sHend, by);
    gemm_k<0,1><<<dim3(768,1), 256, 0, stream>>>(by, 64, out_w, nullptr, m2x,
                                                 m2x, 32, 49152, 32, 64);
  }

  // ---- head ----
  x3_k<<<32, 256, 0, stream>>>(m1x, m2x, x3);
  head_k<<<32, 512, 0, stream>>>(x3, reg_w1, reg_b1, reg_w2, reg_b2, (float*)d_out);
}